// Round 1
// baseline (1169.897 us; speedup 1.0000x reference)
//
#include <hip/hip_runtime.h>
#include <math.h>

#define NTHREADS 256
#define T_STEPS 8
#define F_INC 32
#define H_DIM 128
#define O_DIM 64

// ============================ CSR build ============================
__global__ void init_cnt_kernel(int* __restrict__ cnt, int n) {
    int i = blockIdx.x * NTHREADS + threadIdx.x;
    if (i < n) cnt[i] = 0;
}

__global__ void count_kernel(const int* __restrict__ ei, int* __restrict__ cnt, int E) {
    int e = blockIdx.x * NTHREADS + threadIdx.x;
    if (e < E) atomicAdd(&cnt[ei[E + e]], 1);   // dst row of edge_index
}

// single-block chunked exclusive scan over N (~10000) — trivial cost
__global__ void scan_kernel(const int* __restrict__ cnt, int* __restrict__ rowptr,
                            int* __restrict__ wp, int n) {
    __shared__ int sd[NTHREADS];
    __shared__ int carry;
    const int tid = threadIdx.x;
    if (tid == 0) carry = 0;
    __syncthreads();
    for (int base = 0; base < n; base += NTHREADS) {
        const int i = base + tid;
        int v = (i < n) ? cnt[i] : 0;
        sd[tid] = v;
        __syncthreads();
        for (int off = 1; off < NTHREADS; off <<= 1) {
            int t = (tid >= off) ? sd[tid - off] : 0;
            __syncthreads();
            sd[tid] += t;
            __syncthreads();
        }
        const int excl = carry + sd[tid] - v;
        if (i < n) { rowptr[i] = excl; wp[i] = excl; }
        __syncthreads();
        if (tid == 0) carry += sd[NTHREADS - 1];
        __syncthreads();
    }
    if (tid == 0) rowptr[n] = carry;  // == E
}

__global__ void dis_kernel(const int* __restrict__ cnt, float* __restrict__ dis,
                           float* __restrict__ selfw, int n) {
    int i = blockIdx.x * NTHREADS + threadIdx.x;
    if (i < n) {
        float d = 1.0f + (float)cnt[i];   // deg = in-degree + 1 (self loop)
        dis[i] = rsqrtf(d);
        selfw[i] = 1.0f / d;              // dis*dis
    }
}

__global__ void fill_kernel(const int* __restrict__ ei, const float* __restrict__ dis,
                            int* __restrict__ wp, int* __restrict__ csr_src,
                            float* __restrict__ coefA, int E) {
    int e = blockIdx.x * NTHREADS + threadIdx.x;
    if (e < E) {
        int s = ei[e], d = ei[E + e];
        int p = atomicAdd(&wp[d], 1);
        csr_src[p] = s;
        coefA[p] = dis[s] * dis[d];
    }
}

// ============================ aggregation ============================
// out[n][t][C] = selfw[n]*h(n,t,:) + sum_{e in CSR[n]} coef[e]*h(src_e,t,:)
// h addressed as h[n*sn + t*st + c] (handles x layout [T][N][32] and h layout [n][t][128]).
// One block per dst node; 256 threads cover all (t,c).
template<int C>
__global__ __launch_bounds__(NTHREADS)
void agg_kernel(const float* __restrict__ h, const int* __restrict__ rowptr,
                const int* __restrict__ csrc, const float* __restrict__ coefA,
                const float* __restrict__ selfw, float* __restrict__ out,
                long sn, long st) {
    __shared__ int s_src[NTHREADS];
    __shared__ float s_w[NTHREADS];
    const int n = blockIdx.x;
    const int tid = threadIdx.x;
    const int e0 = rowptr[n], e1 = rowptr[n + 1];
    if (C == 32) {
        const int c = tid & 31, t = tid >> 5;
        const long ho = (long)t * st + c;
        float acc = selfw[n] * h[(long)n * sn + ho];
        for (int eb = e0; eb < e1; eb += NTHREADS) {
            const int m = min(NTHREADS, e1 - eb);
            __syncthreads();
            if (tid < m) { s_src[tid] = csrc[eb + tid]; s_w[tid] = coefA[eb + tid]; }
            __syncthreads();
            for (int i = 0; i < m; ++i)
                acc = fmaf(s_w[i], h[(long)s_src[i] * sn + ho], acc);
        }
        out[(long)n * (T_STEPS * 32) + t * 32 + c] = acc;
    } else {
        const int c4 = (tid & 31) * 4, t = tid >> 5;
        const long ho = (long)t * st + c4;
        const float sw = selfw[n];
        float4 a = *(const float4*)(h + (long)n * sn + ho);
        float4 acc = make_float4(sw * a.x, sw * a.y, sw * a.z, sw * a.w);
        for (int eb = e0; eb < e1; eb += NTHREADS) {
            const int m = min(NTHREADS, e1 - eb);
            __syncthreads();
            if (tid < m) { s_src[tid] = csrc[eb + tid]; s_w[tid] = coefA[eb + tid]; }
            __syncthreads();
            for (int i = 0; i < m; ++i) {
                const float w = s_w[i];
                const float4 v = *(const float4*)(h + (long)s_src[i] * sn + ho);
                acc.x = fmaf(w, v.x, acc.x);
                acc.y = fmaf(w, v.y, acc.y);
                acc.z = fmaf(w, v.z, acc.z);
                acc.w = fmaf(w, v.w, acc.w);
            }
        }
        *(float4*)(out + (long)n * (T_STEPS * 128) + t * 128 + c4) = acc;
    }
}

// ============================ GEMM + fused epilogue ============================
// C[M][ldc-slice] = A[M][K] @ B (+ epilogue).  Tile 64 rows x 128 cols, 256 threads,
// 8x4 register tile per thread, K staged in <=64 chunks to stay under 64KB LDS.
// BT=false: B is [K][ncolsB] row-major.  BT=true: B is [ncols][K] row-major (use B^T).
// EPI: 0 = +bias0+bias1 (LSTM pre-gates), 1 = +bias0,ReLU, 2 = +bias0,ReLU,BatchNorm.
template<int K, bool BT, int EPI>
__global__ __launch_bounds__(NTHREADS)
void gemm_kernel(const float* __restrict__ A, const float* __restrict__ B,
                 const float* __restrict__ bias0, const float* __restrict__ bias1,
                 const float* __restrict__ bng, const float* __restrict__ bnb,
                 const float* __restrict__ bnm, const float* __restrict__ bnv,
                 float* __restrict__ C, int ncolsB, int ldc) {
    constexpr int KC = (K < 64) ? K : 64;
    constexpr int NCH = K / KC;
    __shared__ float As[64 * KC];        // [r][k], writes contiguous, reads broadcast
    __shared__ float Bs[KC * 129];       // [k][c] padded: float4 reads conflict-free
    const int tid = threadIdx.x;
    const long row0 = (long)blockIdx.x * 64;
    const int col0 = blockIdx.y * 128;
    const int c0 = (tid & 31) * 4;
    const int r0 = (tid >> 5) * 8;
    float acc[8][4] = {};
    for (int ch = 0; ch < NCH; ++ch) {
        const int kbase = ch * KC;
        for (int p = tid; p < 64 * (KC / 4); p += NTHREADS) {
            const int r = p / (KC / 4);
            const int kv = p % (KC / 4);
            *(float4*)(&As[r * KC + 4 * kv]) =
                *(const float4*)(A + (row0 + r) * K + kbase + 4 * kv);
        }
        if (!BT) {
            for (int p = tid; p < KC * 32; p += NTHREADS) {
                const int k = p >> 5;
                const int cc = (p & 31) * 4;
                *(float4*)(&Bs[k * 129 + cc]) =
                    *(const float4*)(B + (long)(kbase + k) * ncolsB + col0 + cc);
            }
        } else {
            for (int p = tid; p < 128 * (KC / 4); p += NTHREADS) {
                const int j = p / (KC / 4);
                const int kv = p % (KC / 4);
                const float4 v = *(const float4*)(B + (long)(col0 + j) * K + kbase + 4 * kv);
                Bs[(4 * kv + 0) * 129 + j] = v.x;
                Bs[(4 * kv + 1) * 129 + j] = v.y;
                Bs[(4 * kv + 2) * 129 + j] = v.z;
                Bs[(4 * kv + 3) * 129 + j] = v.w;
            }
        }
        __syncthreads();
        #pragma unroll 8
        for (int k = 0; k < KC; ++k) {
            const float4 b4 = *(const float4*)(&Bs[k * 129 + c0]);
            #pragma unroll
            for (int i = 0; i < 8; ++i) {
                const float a = As[(r0 + i) * KC + k];
                acc[i][0] = fmaf(a, b4.x, acc[i][0]);
                acc[i][1] = fmaf(a, b4.y, acc[i][1]);
                acc[i][2] = fmaf(a, b4.z, acc[i][2]);
                acc[i][3] = fmaf(a, b4.w, acc[i][3]);
            }
        }
        __syncthreads();
    }
    // epilogue (per-column constants hoisted)
    const int colb = col0 + c0;
    float add0[4], mul[4], add1[4];
    #pragma unroll
    for (int j = 0; j < 4; ++j) {
        if (EPI == 0) {
            add0[j] = bias0[colb + j] + bias1[colb + j];
        } else if (EPI == 1) {
            add0[j] = bias0[colb + j];
        } else {
            add0[j] = bias0[colb + j];
            const float s = bng[colb + j] * rsqrtf(bnv[colb + j] + 1e-5f);
            mul[j] = s;
            add1[j] = bnb[colb + j] - bnm[colb + j] * s;
        }
    }
    #pragma unroll
    for (int i = 0; i < 8; ++i) {
        float vv[4];
        #pragma unroll
        for (int j = 0; j < 4; ++j) {
            float v = acc[i][j] + add0[j];
            if (EPI >= 1) v = fmaxf(v, 0.0f);
            if (EPI == 2) v = fmaf(v, mul[j], add1[j]);
            vv[j] = v;
        }
        *(float4*)(C + (row0 + r0 + i) * (long)ldc + colb) =
            make_float4(vv[0], vv[1], vv[2], vv[3]);
    }
}

// ============================ LSTM step (fused) ============================
// gates[32 nodes][256] = Gin[n][t][:] + h_state @ Whh^T, then elementwise LSTM update.
// Whh is [256][64] row-major.  G layout: row (n*8+t), stride 256.
__global__ __launch_bounds__(NTHREADS)
void lstm_step_kernel(const float* __restrict__ G, const float* __restrict__ Whh,
                      float* __restrict__ h_state, float* __restrict__ c_state,
                      float* __restrict__ ys, long ys_stride, int t, int Nn, int first) {
    constexpr int KC = 32;
    constexpr int GL = 260;            // gates-LDS stride (mult of 4 for float4 stores)
    __shared__ float Bs[KC * 260];     // Bs[k][j]: Whh^T chunk; later reused as gates LDS
    __shared__ float As[32 * 64];      // h_state tile
    const int tid = threadIdx.x;
    const int n0 = blockIdx.x * 32;
    const int c0 = (tid & 31) * 8;
    const int r0 = (tid >> 5) * 4;
    float acc[4][8] = {};
    if (!first) {
        for (int p = tid; p < 32 * 16; p += NTHREADS) {
            const int r = p >> 4, kv = p & 15;
            const int n = n0 + r;
            float4 v = make_float4(0.f, 0.f, 0.f, 0.f);
            if (n < Nn) v = *(const float4*)(h_state + (long)n * 64 + 4 * kv);
            *(float4*)(&As[r * 64 + 4 * kv]) = v;
        }
        for (int ch = 0; ch < 2; ++ch) {
            const int kbase = ch * KC;
            for (int p = tid; p < 256 * (KC / 4); p += NTHREADS) {
                const int j = p >> 3, kv = p & 7;
                const float4 v = *(const float4*)(Whh + (long)j * 64 + kbase + 4 * kv);
                Bs[(4 * kv + 0) * 260 + j] = v.x;
                Bs[(4 * kv + 1) * 260 + j] = v.y;
                Bs[(4 * kv + 2) * 260 + j] = v.z;
                Bs[(4 * kv + 3) * 260 + j] = v.w;
            }
            __syncthreads();
            #pragma unroll 8
            for (int k = 0; k < KC; ++k) {
                const float4 b0 = *(const float4*)(&Bs[k * 260 + c0]);
                const float4 b1 = *(const float4*)(&Bs[k * 260 + c0 + 4]);
                #pragma unroll
                for (int i = 0; i < 4; ++i) {
                    const float a = As[(r0 + i) * 64 + kbase + k];
                    acc[i][0] = fmaf(a, b0.x, acc[i][0]);
                    acc[i][1] = fmaf(a, b0.y, acc[i][1]);
                    acc[i][2] = fmaf(a, b0.z, acc[i][2]);
                    acc[i][3] = fmaf(a, b0.w, acc[i][3]);
                    acc[i][4] = fmaf(a, b1.x, acc[i][4]);
                    acc[i][5] = fmaf(a, b1.y, acc[i][5]);
                    acc[i][6] = fmaf(a, b1.z, acc[i][6]);
                    acc[i][7] = fmaf(a, b1.w, acc[i][7]);
                }
            }
            __syncthreads();
        }
    }
    // park gates in LDS (alias Bs) so each thread can grab its (i,f,g,o) quadruple
    float* gl = Bs;   // 32 rows x stride 260 = 8320 floats == sizeof(Bs)
    #pragma unroll
    for (int i = 0; i < 4; ++i) {
        *(float4*)(&gl[(r0 + i) * GL + c0]) =
            make_float4(acc[i][0], acc[i][1], acc[i][2], acc[i][3]);
        *(float4*)(&gl[(r0 + i) * GL + c0 + 4]) =
            make_float4(acc[i][4], acc[i][5], acc[i][6], acc[i][7]);
    }
    __syncthreads();
    for (int p = tid; p < 32 * 64; p += NTHREADS) {
        const int u = p & 63, r = p >> 6;
        const int n = n0 + r;
        if (n < Nn) {
            const float* Gi = G + ((long)n * T_STEPS + t) * 256;
            const float pi = gl[r * GL + u]        + Gi[u];
            const float pf = gl[r * GL + 64 + u]   + Gi[64 + u];
            const float pg = gl[r * GL + 128 + u]  + Gi[128 + u];
            const float po = gl[r * GL + 192 + u]  + Gi[192 + u];
            const float cp = first ? 0.0f : c_state[(long)n * 64 + u];
            const float si = 1.0f / (1.0f + expf(-pi));
            const float sf = 1.0f / (1.0f + expf(-pf));
            const float so = 1.0f / (1.0f + expf(-po));
            const float c = sf * cp + si * tanhf(pg);
            const float h = so * tanhf(c);
            c_state[(long)n * 64 + u] = c;
            h_state[(long)n * 64 + u] = h;
            if (ys) ys[(long)n * ys_stride + u] = h;
        }
    }
}

// ============================ launch ============================
extern "C" void kernel_launch(void* const* d_in, const int* in_sizes, int n_in,
                              void* d_out, int out_size, void* d_ws, size_t ws_size,
                              hipStream_t stream) {
    (void)n_in; (void)out_size;
    const float* x      = (const float*)d_in[0];
    const int*   ei     = (const int*)d_in[1];
    const float* w_gcn0 = (const float*)d_in[2];
    const float* b_gcn0 = (const float*)d_in[3];
    const float* w_gcn1 = (const float*)d_in[4];
    const float* b_gcn1 = (const float*)d_in[5];
    const float* w_gcn2 = (const float*)d_in[6];
    const float* b_gcn2 = (const float*)d_in[7];
    const float* bn_g0  = (const float*)d_in[8];
    const float* bn_b0  = (const float*)d_in[9];
    const float* bn_m0  = (const float*)d_in[10];
    const float* bn_v0  = (const float*)d_in[11];
    const float* bn_g1  = (const float*)d_in[12];
    const float* bn_b1  = (const float*)d_in[13];
    const float* bn_m1  = (const float*)d_in[14];
    const float* bn_v1  = (const float*)d_in[15];
    const float* w_ih_0 = (const float*)d_in[16];
    const float* w_hh_0 = (const float*)d_in[17];
    const float* b_ih_0 = (const float*)d_in[18];
    const float* b_hh_0 = (const float*)d_in[19];
    const float* w_ih_1 = (const float*)d_in[20];
    const float* w_hh_1 = (const float*)d_in[21];
    const float* b_ih_1 = (const float*)d_in[22];
    const float* b_hh_1 = (const float*)d_in[23];
    const float* w_ih_2 = (const float*)d_in[24];
    const float* w_hh_2 = (const float*)d_in[25];
    const float* b_ih_2 = (const float*)d_in[26];
    const float* b_hh_2 = (const float*)d_in[27];

    const int E = in_sizes[1] / 2;
    const int N = in_sizes[0] / (T_STEPS * F_INC);     // 10000
    const long M = (long)N * T_STEPS;                  // 80000 (divisible by 64)

    // ---- workspace carve (~130 MB total) ----
    char* ws = (char*)d_ws;
    size_t off = 0;
    auto carve = [&](size_t bytes) -> void* {
        void* p = ws + off;
        off += (bytes + 255) & ~(size_t)255;
        return p;
    };
    float* dis     = (float*)carve((size_t)N * 4);
    float* selfw   = (float*)carve((size_t)N * 4);
    float* coefA   = (float*)carve((size_t)E * 4);
    float* h_st    = (float*)carve((size_t)N * O_DIM * 4);
    float* c_st    = (float*)carve((size_t)N * O_DIM * 4);
    int*   cnt     = (int*)carve((size_t)N * 4);
    int*   rowptr  = (int*)carve((size_t)(N + 1) * 4);
    int*   wp      = (int*)carve((size_t)N * 4);
    int*   csr_src = (int*)carve((size_t)E * 4);
    float* hbuf    = (float*)carve((size_t)M * H_DIM * 4);   // 40.96 MB
    float* G       = (float*)carve((size_t)M * 256 * 4);     // 81.92 MB
    float* abuf    = G;   // agg scratch aliases G (disjoint lifetimes)
    (void)ws_size;

    const dim3 b256(NTHREADS);
    const int gN = (N + NTHREADS - 1) / NTHREADS;
    const int gE = (E + NTHREADS - 1) / NTHREADS;

    // ---- CSR + normalization ----
    init_cnt_kernel<<<gN, b256, 0, stream>>>(cnt, N);
    count_kernel<<<gE, b256, 0, stream>>>(ei, cnt, E);
    scan_kernel<<<1, b256, 0, stream>>>(cnt, rowptr, wp, N);
    dis_kernel<<<gN, b256, 0, stream>>>(cnt, dis, selfw, N);
    fill_kernel<<<gE, b256, 0, stream>>>(ei, dis, wp, csr_src, coefA, E);

    // ---- GCN (aggregate-first: gcn(h) = (A_hat h) W + b, epilogue fused in GEMM) ----
    // layer 0: x layout [T][N][32] -> a0 [n][t][32]
    agg_kernel<32><<<N, b256, 0, stream>>>(x, rowptr, csr_src, coefA, selfw, abuf,
                                           32L, (long)N * 32);
    gemm_kernel<32, false, 2><<<dim3(M / 64, 1), b256, 0, stream>>>(
        abuf, w_gcn0, b_gcn0, nullptr, bn_g0, bn_b0, bn_m0, bn_v0, hbuf, 128, 128);
    // layer 1
    agg_kernel<128><<<N, b256, 0, stream>>>(hbuf, rowptr, csr_src, coefA, selfw, abuf,
                                            (long)T_STEPS * 128, 128L);
    gemm_kernel<128, false, 2><<<dim3(M / 64, 1), b256, 0, stream>>>(
        abuf, w_gcn1, b_gcn1, nullptr, bn_g1, bn_b1, bn_m1, bn_v1, hbuf, 128, 128);
    // layer 2 (ReLU only)
    agg_kernel<128><<<N, b256, 0, stream>>>(hbuf, rowptr, csr_src, coefA, selfw, abuf,
                                            (long)T_STEPS * 128, 128L);
    gemm_kernel<128, false, 1><<<dim3(M / 64, 1), b256, 0, stream>>>(
        abuf, w_gcn2, b_gcn2, nullptr, nullptr, nullptr, nullptr, nullptr, hbuf, 128, 128);

    // ---- LSTM ----
    const int gS = (N + 31) / 32;
    float* ys0 = hbuf;                       // [n][t][64] (hbuf dead after Gin0 GEMM)
    float* ys1 = hbuf + (size_t)M * O_DIM;
    // layer 0
    gemm_kernel<128, true, 0><<<dim3(M / 64, 2), b256, 0, stream>>>(
        hbuf, w_ih_0, b_ih_0, b_hh_0, nullptr, nullptr, nullptr, nullptr, G, 256, 256);
    for (int t = 0; t < T_STEPS; ++t)
        lstm_step_kernel<<<gS, b256, 0, stream>>>(G, w_hh_0, h_st, c_st,
                                                  ys0 + (long)t * O_DIM,
                                                  (long)T_STEPS * O_DIM, t, N, t == 0);
    // layer 1
    gemm_kernel<64, true, 0><<<dim3(M / 64, 2), b256, 0, stream>>>(
        ys0, w_ih_1, b_ih_1, b_hh_1, nullptr, nullptr, nullptr, nullptr, G, 256, 256);
    for (int t = 0; t < T_STEPS; ++t)
        lstm_step_kernel<<<gS, b256, 0, stream>>>(G, w_hh_1, h_st, c_st,
                                                  ys1 + (long)t * O_DIM,
                                                  (long)T_STEPS * O_DIM, t, N, t == 0);
    // layer 2 (only final h is needed -> write straight to d_out at t==7)
    gemm_kernel<64, true, 0><<<dim3(M / 64, 2), b256, 0, stream>>>(
        ys1, w_ih_2, b_ih_2, b_hh_2, nullptr, nullptr, nullptr, nullptr, G, 256, 256);
    for (int t = 0; t < T_STEPS; ++t)
        lstm_step_kernel<<<gS, b256, 0, stream>>>(G, w_hh_2, h_st, c_st,
                                                  (t == T_STEPS - 1) ? (float*)d_out : nullptr,
                                                  64L, t, N, t == 0);
}

// Round 2
// 851.489 us; speedup vs baseline: 1.3739x; 1.3739x over previous
//
#include <hip/hip_runtime.h>
#include <hip/hip_bf16.h>
#include <math.h>

#define NTHREADS 256
#define T_STEPS 8
#define F_INC 32
#define H_DIM 128
#define O_DIM 64

typedef unsigned short u16;
typedef __attribute__((ext_vector_type(8))) short short8_t;
typedef __attribute__((ext_vector_type(4))) float float4_t;

__device__ __forceinline__ float bf2f(u16 u) {
    return __uint_as_float(((unsigned)u) << 16);
}
__device__ __forceinline__ u16 f2bf(float f) {
    __hip_bfloat16 h = __float2bfloat16(f);   // RNE
    union { __hip_bfloat16 h; u16 s; } cv; cv.h = h; return cv.s;
}
__device__ __forceinline__ float4 ld_bf4(const u16* p) {
    uint2 u = *(const uint2*)p;
    return make_float4(__uint_as_float(u.x << 16), __uint_as_float(u.x & 0xffff0000u),
                       __uint_as_float(u.y << 16), __uint_as_float(u.y & 0xffff0000u));
}
__device__ __forceinline__ void st_bf4(u16* p, float4 v) {
    ushort4 s = make_ushort4(f2bf(v.x), f2bf(v.y), f2bf(v.z), f2bf(v.w));
    *(ushort4*)p = s;
}

// ============================ CSR build ============================
__global__ void init_cnt_kernel(int* __restrict__ cnt, int n) {
    int i = blockIdx.x * NTHREADS + threadIdx.x;
    if (i < n) cnt[i] = 0;
}

__global__ void count_kernel(const int* __restrict__ ei, int* __restrict__ cnt, int E) {
    int e = blockIdx.x * NTHREADS + threadIdx.x;
    if (e < E) atomicAdd(&cnt[ei[E + e]], 1);   // dst row of edge_index
}

__global__ void scan_kernel(const int* __restrict__ cnt, int* __restrict__ rowptr,
                            int* __restrict__ wp, int n) {
    __shared__ int sd[NTHREADS];
    __shared__ int carry;
    const int tid = threadIdx.x;
    if (tid == 0) carry = 0;
    __syncthreads();
    for (int base = 0; base < n; base += NTHREADS) {
        const int i = base + tid;
        int v = (i < n) ? cnt[i] : 0;
        sd[tid] = v;
        __syncthreads();
        for (int off = 1; off < NTHREADS; off <<= 1) {
            int t = (tid >= off) ? sd[tid - off] : 0;
            __syncthreads();
            sd[tid] += t;
            __syncthreads();
        }
        const int excl = carry + sd[tid] - v;
        if (i < n) { rowptr[i] = excl; wp[i] = excl; }
        __syncthreads();
        if (tid == 0) carry += sd[NTHREADS - 1];
        __syncthreads();
    }
    if (tid == 0) rowptr[n] = carry;
}

__global__ void dis_kernel(const int* __restrict__ cnt, float* __restrict__ dis,
                           float* __restrict__ selfw, int n) {
    int i = blockIdx.x * NTHREADS + threadIdx.x;
    if (i < n) {
        float d = 1.0f + (float)cnt[i];
        dis[i] = rsqrtf(d);
        selfw[i] = 1.0f / d;
    }
}

__global__ void fill_kernel(const int* __restrict__ ei, const float* __restrict__ dis,
                            int* __restrict__ wp, int* __restrict__ csr_src,
                            float* __restrict__ coefA, int E) {
    int e = blockIdx.x * NTHREADS + threadIdx.x;
    if (e < E) {
        int s = ei[e], d = ei[E + e];
        int p = atomicAdd(&wp[d], 1);
        csr_src[p] = s;
        coefA[p] = dis[s] * dis[d];
    }
}

// ============================ input / weight prep ============================
// xb[n][t][c] (bf16) from x[t][n][c] (fp32)
__global__ void xprep_kernel(const float* __restrict__ x, u16* __restrict__ xb, int N) {
    long i = (long)blockIdx.x * NTHREADS + threadIdx.x;
    if (i < (long)N * 256) {
        int n = (int)(i >> 8), tc = (int)(i & 255);
        int t = tc >> 5, c = tc & 31;
        xb[i] = f2bf(x[((long)t * N + n) * 32 + c]);
    }
}

// Wt[n][k] = W[k][n] (bf16 from fp32), W is [K][Nc]
__global__ void wprep_t_kernel(const float* __restrict__ W, u16* __restrict__ Wt,
                               int K, int Nc) {
    int i = blockIdx.x * NTHREADS + threadIdx.x;
    if (i < K * Nc) {
        int k = i / Nc, n = i % Nc;
        Wt[n * K + k] = f2bf(W[i]);
    }
}

// straight cast
__global__ void wprep_c_kernel(const float* __restrict__ W, u16* __restrict__ Wt, int sz) {
    int i = blockIdx.x * NTHREADS + threadIdx.x;
    if (i < sz) Wt[i] = f2bf(W[i]);
}

// ============================ aggregation (bf16 in/out, fp32 acc) ============================
// out[n][t][128] = selfw[n]*h[n] + sum coef*h[src];  h layout [n][t][128] bf16
__global__ __launch_bounds__(NTHREADS)
void agg_bf128_kernel(const u16* __restrict__ h, const int* __restrict__ rowptr,
                      const int* __restrict__ csrc, const float* __restrict__ coefA,
                      const float* __restrict__ selfw, u16* __restrict__ out) {
    __shared__ int s_src[NTHREADS];
    __shared__ float s_w[NTHREADS];
    const int n = blockIdx.x, tid = threadIdx.x;
    const int e0 = rowptr[n], e1 = rowptr[n + 1];
    const int c4 = (tid & 31) * 4, t = tid >> 5;
    const long ho = (long)t * 128 + c4;
    const float sw = selfw[n];
    float4 sv = ld_bf4(h + (long)n * 1024 + ho);
    float4 acc = make_float4(sw * sv.x, sw * sv.y, sw * sv.z, sw * sv.w);
    for (int eb = e0; eb < e1; eb += NTHREADS) {
        const int m = min(NTHREADS, e1 - eb);
        __syncthreads();
        if (tid < m) { s_src[tid] = csrc[eb + tid]; s_w[tid] = coefA[eb + tid]; }
        __syncthreads();
        for (int i = 0; i < m; ++i) {
            const float w = s_w[i];
            const float4 v = ld_bf4(h + (long)s_src[i] * 1024 + ho);
            acc.x = fmaf(w, v.x, acc.x);
            acc.y = fmaf(w, v.y, acc.y);
            acc.z = fmaf(w, v.z, acc.z);
            acc.w = fmaf(w, v.w, acc.w);
        }
    }
    st_bf4(out + (long)n * 1024 + ho, acc);
}

// 32-channel variant: 4 waves split the edge list, LDS reduce at the end.
__global__ __launch_bounds__(NTHREADS)
void agg_bf32_kernel(const u16* __restrict__ h, const int* __restrict__ rowptr,
                     const int* __restrict__ csrc, const float* __restrict__ coefA,
                     const float* __restrict__ selfw, u16* __restrict__ out) {
    __shared__ float red[4 * 64 * 4];
    const int n = blockIdx.x, tid = threadIdx.x;
    const int wid = tid >> 6, lane = tid & 63;
    const int c4 = (lane & 7) * 4, t = lane >> 3;
    const long ho = (long)t * 32 + c4;
    const int e0 = rowptr[n], e1 = rowptr[n + 1];
    float4 acc = make_float4(0.f, 0.f, 0.f, 0.f);
    for (int e = e0 + wid; e < e1; e += 4) {
        const int s = csrc[e];          // wave-uniform -> broadcast
        const float w = coefA[e];
        const float4 v = ld_bf4(h + (long)s * 256 + ho);
        acc.x = fmaf(w, v.x, acc.x);
        acc.y = fmaf(w, v.y, acc.y);
        acc.z = fmaf(w, v.z, acc.z);
        acc.w = fmaf(w, v.w, acc.w);
    }
    *(float4*)(&red[(wid * 64 + lane) * 4]) = acc;
    __syncthreads();
    if (wid == 0) {
        float4 a = *(float4*)(&red[lane * 4]);
        for (int w = 1; w < 4; ++w) {
            float4 b = *(float4*)(&red[(w * 64 + lane) * 4]);
            a.x += b.x; a.y += b.y; a.z += b.z; a.w += b.w;
        }
        const float sw = selfw[n];
        const float4 sv = ld_bf4(h + (long)n * 256 + ho);
        a.x = fmaf(sw, sv.x, a.x);
        a.y = fmaf(sw, sv.y, a.y);
        a.z = fmaf(sw, sv.z, a.z);
        a.w = fmaf(sw, sv.w, a.w);
        st_bf4(out + (long)n * 256 + ho, a);
    }
}

// ============================ MFMA GEMM + fused epilogue ============================
// C[M][ldc] = A[M][K](bf16) @ Bt^T (Bt is [ncols][K] bf16, row n = column n of B).
// Block tile 128 rows x 128 cols, 4 waves, each wave 32 rows x 128 cols via
// 2x8 tiles of v_mfma_f32_16x16x32_bf16.  fp32 accumulate.
// EPI: 0 = +bias0+bias1, 1 = +bias0,ReLU, 2 = +bias0,ReLU,BN.  OUTBF: bf16 or fp32 out.
template<int K, int EPI, bool OUTBF>
__global__ __launch_bounds__(NTHREADS)
void mfma_gemm_kernel(const u16* __restrict__ A, const u16* __restrict__ Bt,
                      const float* __restrict__ bias0, const float* __restrict__ bias1,
                      const float* __restrict__ bng, const float* __restrict__ bnb,
                      const float* __restrict__ bnm, const float* __restrict__ bnv,
                      void* __restrict__ Cout, int ldc) {
    constexpr int KC = (K < 64) ? K : 64;
    constexpr int KP = KC + 8;               // pad: keeps 16B alignment, breaks pow-2 stride
    constexpr int KV = KC / 8;               // uint4 chunks per row
    __shared__ u16 As[128 * KP];
    __shared__ u16 Bs[128 * KP];
    const int tid = threadIdx.x;
    const long row0 = (long)blockIdx.x * 128;
    const int col0 = blockIdx.y * 128;
    const int wid = tid >> 6, lane = tid & 63;
    const int quad = lane >> 4, l16 = lane & 15;

    float4_t acc[2][8];
    #pragma unroll
    for (int rt = 0; rt < 2; ++rt)
        #pragma unroll
        for (int ct = 0; ct < 8; ++ct)
            acc[rt][ct] = (float4_t){0.f, 0.f, 0.f, 0.f};

    const int arow = wid * 32 + l16;
    const int koff = quad * 8;
    for (int ch = 0; ch < K / KC; ++ch) {
        const int kbase = ch * KC;
        for (int p = tid; p < 128 * KV; p += NTHREADS) {
            const int r = p / KV, kv = p % KV;
            *(uint4*)(&As[r * KP + kv * 8]) =
                *(const uint4*)(A + (row0 + r) * K + kbase + kv * 8);
        }
        for (int p = tid; p < 128 * KV; p += NTHREADS) {
            const int r = p / KV, kv = p % KV;
            *(uint4*)(&Bs[r * KP + kv * 8]) =
                *(const uint4*)(Bt + (long)(col0 + r) * K + kbase + kv * 8);
        }
        __syncthreads();
        #pragma unroll
        for (int kc = 0; kc < KC / 32; ++kc) {
            const short8_t a0 = *(const short8_t*)(&As[arow * KP + kc * 32 + koff]);
            const short8_t a1 = *(const short8_t*)(&As[(arow + 16) * KP + kc * 32 + koff]);
            #pragma unroll
            for (int ct = 0; ct < 8; ++ct) {
                const short8_t b = *(const short8_t*)(&Bs[(ct * 16 + l16) * KP + kc * 32 + koff]);
                acc[0][ct] = __builtin_amdgcn_mfma_f32_16x16x32_bf16(a0, b, acc[0][ct], 0, 0, 0);
                acc[1][ct] = __builtin_amdgcn_mfma_f32_16x16x32_bf16(a1, b, acc[1][ct], 0, 0, 0);
            }
        }
        __syncthreads();
    }

    // epilogue: lane holds D[row=quad*4+r][col=l16] per 16x16 tile
    float e_add0[8], e_mul[8], e_add1[8];
    #pragma unroll
    for (int ct = 0; ct < 8; ++ct) {
        const int c = col0 + ct * 16 + l16;
        if constexpr (EPI == 0) {
            e_add0[ct] = bias0[c] + bias1[c];
        } else if constexpr (EPI == 1) {
            e_add0[ct] = bias0[c];
        } else {
            e_add0[ct] = bias0[c];
            const float s = bng[c] * rsqrtf(bnv[c] + 1e-5f);
            e_mul[ct] = s;
            e_add1[ct] = bnb[c] - bnm[c] * s;
        }
    }
    #pragma unroll
    for (int rt = 0; rt < 2; ++rt) {
        #pragma unroll
        for (int r = 0; r < 4; ++r) {
            const long row = row0 + wid * 32 + rt * 16 + quad * 4 + r;
            #pragma unroll
            for (int ct = 0; ct < 8; ++ct) {
                float v = acc[rt][ct][r] + e_add0[ct];
                if constexpr (EPI >= 1) v = fmaxf(v, 0.f);
                if constexpr (EPI == 2) v = fmaf(v, e_mul[ct], e_add1[ct]);
                const long idx = row * (long)ldc + col0 + ct * 16 + l16;
                if constexpr (OUTBF) ((u16*)Cout)[idx] = f2bf(v);
                else ((float*)Cout)[idx] = v;
            }
        }
    }
}

// ============================ LSTM step (fused, fp32 recurrence) ============================
__global__ __launch_bounds__(NTHREADS)
void lstm_step_kernel(const float* __restrict__ G, const float* __restrict__ Whh,
                      float* __restrict__ h_state, float* __restrict__ c_state,
                      u16* __restrict__ ys, long ys_stride, float* __restrict__ out_f,
                      int t, int Nn, int first) {
    constexpr int KCr = 32;
    constexpr int GL = 260;
    __shared__ float Bs[KCr * 260];
    __shared__ float As[32 * 64];
    const int tid = threadIdx.x;
    const int n0 = blockIdx.x * 32;
    const int c0 = (tid & 31) * 8;
    const int r0 = (tid >> 5) * 4;
    float acc[4][8] = {};
    if (!first) {
        for (int p = tid; p < 32 * 16; p += NTHREADS) {
            const int r = p >> 4, kv = p & 15;
            const int n = n0 + r;
            float4 v = make_float4(0.f, 0.f, 0.f, 0.f);
            if (n < Nn) v = *(const float4*)(h_state + (long)n * 64 + 4 * kv);
            *(float4*)(&As[r * 64 + 4 * kv]) = v;
        }
        for (int ch = 0; ch < 2; ++ch) {
            const int kbase = ch * KCr;
            for (int p = tid; p < 256 * (KCr / 4); p += NTHREADS) {
                const int j = p >> 3, kv = p & 7;
                const float4 v = *(const float4*)(Whh + (long)j * 64 + kbase + 4 * kv);
                Bs[(4 * kv + 0) * 260 + j] = v.x;
                Bs[(4 * kv + 1) * 260 + j] = v.y;
                Bs[(4 * kv + 2) * 260 + j] = v.z;
                Bs[(4 * kv + 3) * 260 + j] = v.w;
            }
            __syncthreads();
            #pragma unroll 8
            for (int k = 0; k < KCr; ++k) {
                const float4 b0 = *(const float4*)(&Bs[k * 260 + c0]);
                const float4 b1 = *(const float4*)(&Bs[k * 260 + c0 + 4]);
                #pragma unroll
                for (int i = 0; i < 4; ++i) {
                    const float a = As[(r0 + i) * 64 + kbase + k];
                    acc[i][0] = fmaf(a, b0.x, acc[i][0]);
                    acc[i][1] = fmaf(a, b0.y, acc[i][1]);
                    acc[i][2] = fmaf(a, b0.z, acc[i][2]);
                    acc[i][3] = fmaf(a, b0.w, acc[i][3]);
                    acc[i][4] = fmaf(a, b1.x, acc[i][4]);
                    acc[i][5] = fmaf(a, b1.y, acc[i][5]);
                    acc[i][6] = fmaf(a, b1.z, acc[i][6]);
                    acc[i][7] = fmaf(a, b1.w, acc[i][7]);
                }
            }
            __syncthreads();
        }
    }
    float* gl = Bs;
    #pragma unroll
    for (int i = 0; i < 4; ++i) {
        *(float4*)(&gl[(r0 + i) * GL + c0]) =
            make_float4(acc[i][0], acc[i][1], acc[i][2], acc[i][3]);
        *(float4*)(&gl[(r0 + i) * GL + c0 + 4]) =
            make_float4(acc[i][4], acc[i][5], acc[i][6], acc[i][7]);
    }
    __syncthreads();
    for (int p = tid; p < 32 * 64; p += NTHREADS) {
        const int u = p & 63, r = p >> 6;
        const int n = n0 + r;
        if (n < Nn) {
            const float* Gi = G + ((long)n * T_STEPS + t) * 256;
            const float pi = gl[r * GL + u]       + Gi[u];
            const float pf = gl[r * GL + 64 + u]  + Gi[64 + u];
            const float pg = gl[r * GL + 128 + u] + Gi[128 + u];
            const float po = gl[r * GL + 192 + u] + Gi[192 + u];
            const float cp = first ? 0.0f : c_state[(long)n * 64 + u];
            const float si = 1.0f / (1.0f + expf(-pi));
            const float sf = 1.0f / (1.0f + expf(-pf));
            const float so = 1.0f / (1.0f + expf(-po));
            const float c = sf * cp + si * tanhf(pg);
            const float h = so * tanhf(c);
            c_state[(long)n * 64 + u] = c;
            h_state[(long)n * 64 + u] = h;
            if (ys) ys[(long)n * ys_stride + u] = f2bf(h);
            if (out_f) out_f[(long)n * 64 + u] = h;
        }
    }
}

// ============================ launch ============================
extern "C" void kernel_launch(void* const* d_in, const int* in_sizes, int n_in,
                              void* d_out, int out_size, void* d_ws, size_t ws_size,
                              hipStream_t stream) {
    (void)n_in; (void)out_size; (void)ws_size;
    const float* x      = (const float*)d_in[0];
    const int*   ei     = (const int*)d_in[1];
    const float* w_gcn0 = (const float*)d_in[2];
    const float* b_gcn0 = (const float*)d_in[3];
    const float* w_gcn1 = (const float*)d_in[4];
    const float* b_gcn1 = (const float*)d_in[5];
    const float* w_gcn2 = (const float*)d_in[6];
    const float* b_gcn2 = (const float*)d_in[7];
    const float* bn_g0  = (const float*)d_in[8];
    const float* bn_b0  = (const float*)d_in[9];
    const float* bn_m0  = (const float*)d_in[10];
    const float* bn_v0  = (const float*)d_in[11];
    const float* bn_g1  = (const float*)d_in[12];
    const float* bn_b1  = (const float*)d_in[13];
    const float* bn_m1  = (const float*)d_in[14];
    const float* bn_v1  = (const float*)d_in[15];
    const float* w_ih_0 = (const float*)d_in[16];
    const float* w_hh_0 = (const float*)d_in[17];
    const float* b_ih_0 = (const float*)d_in[18];
    const float* b_hh_0 = (const float*)d_in[19];
    const float* w_ih_1 = (const float*)d_in[20];
    const float* w_hh_1 = (const float*)d_in[21];
    const float* b_ih_1 = (const float*)d_in[22];
    const float* b_hh_1 = (const float*)d_in[23];
    const float* w_ih_2 = (const float*)d_in[24];
    const float* w_hh_2 = (const float*)d_in[25];
    const float* b_ih_2 = (const float*)d_in[26];
    const float* b_hh_2 = (const float*)d_in[27];

    const int E = in_sizes[1] / 2;
    const int N = in_sizes[0] / (T_STEPS * F_INC);     // 10000
    const long M = (long)N * T_STEPS;                  // 80000 = 625 * 128

    // ---- workspace carve ----
    char* ws = (char*)d_ws;
    size_t off = 0;
    auto carve = [&](size_t bytes) -> void* {
        void* p = ws + off;
        off += (bytes + 255) & ~(size_t)255;
        return p;
    };
    float* dis     = (float*)carve((size_t)N * 4);
    float* selfw   = (float*)carve((size_t)N * 4);
    float* coefA   = (float*)carve((size_t)E * 4);
    float* h_st    = (float*)carve((size_t)N * O_DIM * 4);
    float* c_st    = (float*)carve((size_t)N * O_DIM * 4);
    int*   cnt     = (int*)carve((size_t)N * 4);
    int*   rowptr  = (int*)carve((size_t)(N + 1) * 4);
    int*   wp      = (int*)carve((size_t)N * 4);
    int*   csr_src = (int*)carve((size_t)E * 4);
    u16*   xb      = (u16*)carve((size_t)N * 256 * 2);        // 5.1 MB
    u16*   hbuf    = (u16*)carve((size_t)M * H_DIM * 2);      // 20.5 MB
    u16*   wt0     = (u16*)carve((size_t)32 * 128 * 2);
    u16*   wt1     = (u16*)carve((size_t)128 * 128 * 2);
    u16*   wt2     = (u16*)carve((size_t)128 * 128 * 2);
    u16*   wtih0   = (u16*)carve((size_t)256 * 128 * 2);
    u16*   wtih1   = (u16*)carve((size_t)256 * 64 * 2);
    u16*   wtih2   = (u16*)carve((size_t)256 * 64 * 2);
    float* G       = (float*)carve((size_t)M * 256 * 4);      // 81.9 MB
    u16*   abuf    = (u16*)G;                 // agg scratch aliases G (disjoint lifetime)
    u16*   ys0     = hbuf;                    // hbuf dead after Gin0 GEMM
    u16*   ys1     = hbuf + (size_t)M * O_DIM;

    const dim3 b256(NTHREADS);
    const int gN = (N + NTHREADS - 1) / NTHREADS;
    const int gE = (E + NTHREADS - 1) / NTHREADS;

    // ---- CSR + normalization ----
    init_cnt_kernel<<<gN, b256, 0, stream>>>(cnt, N);
    count_kernel<<<gE, b256, 0, stream>>>(ei, cnt, E);
    scan_kernel<<<1, b256, 0, stream>>>(cnt, rowptr, wp, N);
    dis_kernel<<<gN, b256, 0, stream>>>(cnt, dis, selfw, N);
    fill_kernel<<<gE, b256, 0, stream>>>(ei, dis, wp, csr_src, coefA, E);

    // ---- prep: x -> bf16 [n][t][32]; weights -> bf16 [n][k] ----
    xprep_kernel<<<(int)((N * 256L + 255) / 256), b256, 0, stream>>>(x, xb, N);
    wprep_t_kernel<<<(32 * 128 + 255) / 256, b256, 0, stream>>>(w_gcn0, wt0, 32, 128);
    wprep_t_kernel<<<(128 * 128 + 255) / 256, b256, 0, stream>>>(w_gcn1, wt1, 128, 128);
    wprep_t_kernel<<<(128 * 128 + 255) / 256, b256, 0, stream>>>(w_gcn2, wt2, 128, 128);
    wprep_c_kernel<<<(256 * 128 + 255) / 256, b256, 0, stream>>>(w_ih_0, wtih0, 256 * 128);
    wprep_c_kernel<<<(256 * 64 + 255) / 256, b256, 0, stream>>>(w_ih_1, wtih1, 256 * 64);
    wprep_c_kernel<<<(256 * 64 + 255) / 256, b256, 0, stream>>>(w_ih_2, wtih2, 256 * 64);

    // ---- GCN: aggregate-first, MFMA GEMM with fused epilogue ----
    const int gBlk = (int)(M / 128);   // 625
    agg_bf32_kernel<<<N, b256, 0, stream>>>(xb, rowptr, csr_src, coefA, selfw, abuf);
    mfma_gemm_kernel<32, 2, true><<<dim3(gBlk, 1), b256, 0, stream>>>(
        abuf, wt0, b_gcn0, nullptr, bn_g0, bn_b0, bn_m0, bn_v0, hbuf, 128);
    agg_bf128_kernel<<<N, b256, 0, stream>>>(hbuf, rowptr, csr_src, coefA, selfw, abuf);
    mfma_gemm_kernel<128, 2, true><<<dim3(gBlk, 1), b256, 0, stream>>>(
        abuf, wt1, b_gcn1, nullptr, bn_g1, bn_b1, bn_m1, bn_v1, hbuf, 128);
    agg_bf128_kernel<<<N, b256, 0, stream>>>(hbuf, rowptr, csr_src, coefA, selfw, abuf);
    mfma_gemm_kernel<128, 1, true><<<dim3(gBlk, 1), b256, 0, stream>>>(
        abuf, wt2, b_gcn2, nullptr, nullptr, nullptr, nullptr, nullptr, hbuf, 128);

    // ---- LSTM ----
    const int gS = (N + 31) / 32;
    // layer 0 (reads hbuf; ys0/ys1 alias hbuf but are only written after this GEMM)
    mfma_gemm_kernel<128, 0, false><<<dim3(gBlk, 2), b256, 0, stream>>>(
        hbuf, wtih0, b_ih_0, b_hh_0, nullptr, nullptr, nullptr, nullptr, G, 256);
    for (int t = 0; t < T_STEPS; ++t)
        lstm_step_kernel<<<gS, b256, 0, stream>>>(G, w_hh_0, h_st, c_st,
                                                  ys0 + (long)t * O_DIM,
                                                  (long)T_STEPS * O_DIM, nullptr, t, N, t == 0);
    // layer 1
    mfma_gemm_kernel<64, 0, false><<<dim3(gBlk, 2), b256, 0, stream>>>(
        ys0, wtih1, b_ih_1, b_hh_1, nullptr, nullptr, nullptr, nullptr, G, 256);
    for (int t = 0; t < T_STEPS; ++t)
        lstm_step_kernel<<<gS, b256, 0, stream>>>(G, w_hh_1, h_st, c_st,
                                                  ys1 + (long)t * O_DIM,
                                                  (long)T_STEPS * O_DIM, nullptr, t, N, t == 0);
    // layer 2 (only final h needed -> d_out fp32 at t==7)
    mfma_gemm_kernel<64, 0, false><<<dim3(gBlk, 2), b256, 0, stream>>>(
        ys1, wtih2, b_ih_2, b_hh_2, nullptr, nullptr, nullptr, nullptr, G, 256);
    for (int t = 0; t < T_STEPS; ++t)
        lstm_step_kernel<<<gS, b256, 0, stream>>>(G, w_hh_2, h_st, c_st,
                                                  nullptr, 0L,
                                                  (t == T_STEPS - 1) ? (float*)d_out : nullptr,
                                                  t, N, t == 0);
}

// Round 3
// 470.318 us; speedup vs baseline: 2.4875x; 1.8105x over previous
//
#include <hip/hip_runtime.h>
#include <hip/hip_bf16.h>
#include <math.h>

#define NTHREADS 256
#define T_STEPS 8
#define F_INC 32
#define H_DIM 128
#define O_DIM 64

typedef unsigned short u16;
typedef __attribute__((ext_vector_type(8))) short short8_t;
typedef __attribute__((ext_vector_type(4))) float float4_t;

__device__ __forceinline__ float bf2f(u16 u) {
    return __uint_as_float(((unsigned)u) << 16);
}
__device__ __forceinline__ u16 f2bf(float f) {
    __hip_bfloat16 h = __float2bfloat16(f);   // RNE
    union { __hip_bfloat16 h; u16 s; } cv; cv.h = h; return cv.s;
}
__device__ __forceinline__ float4 ld_bf4(const u16* p) {
    uint2 u = *(const uint2*)p;
    return make_float4(__uint_as_float(u.x << 16), __uint_as_float(u.x & 0xffff0000u),
                       __uint_as_float(u.y << 16), __uint_as_float(u.y & 0xffff0000u));
}
__device__ __forceinline__ void st_bf4(u16* p, float4 v) {
    ushort4 s = make_ushort4(f2bf(v.x), f2bf(v.y), f2bf(v.z), f2bf(v.w));
    *(ushort4*)p = s;
}
__device__ __forceinline__ float sigmoidf(float x) {
    return 1.0f / (1.0f + expf(-x));
}

// ============================ CSR build ============================
__global__ void init_cnt_kernel(int* __restrict__ cnt, int n) {
    int i = blockIdx.x * NTHREADS + threadIdx.x;
    if (i < n) cnt[i] = 0;
}

__global__ void count_kernel(const int* __restrict__ ei, int* __restrict__ cnt, int E) {
    int e = blockIdx.x * NTHREADS + threadIdx.x;
    if (e < E) atomicAdd(&cnt[ei[E + e]], 1);   // dst row of edge_index
}

// 3-phase scan (replaces 25µs single-block version)
__global__ void scan_part1(const int* __restrict__ cnt, int* __restrict__ bsum, int n) {
    __shared__ int sd[NTHREADS];
    const int i = blockIdx.x * NTHREADS + threadIdx.x;
    sd[threadIdx.x] = (i < n) ? cnt[i] : 0;
    __syncthreads();
    for (int off = 128; off > 0; off >>= 1) {
        if (threadIdx.x < off) sd[threadIdx.x] += sd[threadIdx.x + off];
        __syncthreads();
    }
    if (threadIdx.x == 0) bsum[blockIdx.x] = sd[0];
}
__global__ void scan_part2(const int* __restrict__ bsum, int* __restrict__ boff, int nb) {
    if (threadIdx.x == 0) {
        int s = 0;
        for (int b = 0; b < nb; ++b) { boff[b] = s; s += bsum[b]; }
    }
}
__global__ void scan_part3(const int* __restrict__ cnt, const int* __restrict__ boff,
                           int* __restrict__ rowptr, int* __restrict__ wp, int n) {
    __shared__ int sd[NTHREADS];
    const int i = blockIdx.x * NTHREADS + threadIdx.x;
    const int v = (i < n) ? cnt[i] : 0;
    sd[threadIdx.x] = v;
    __syncthreads();
    for (int off = 1; off < NTHREADS; off <<= 1) {
        const int tv = (threadIdx.x >= off) ? sd[threadIdx.x - off] : 0;
        __syncthreads();
        sd[threadIdx.x] += tv;
        __syncthreads();
    }
    const int excl = boff[blockIdx.x] + sd[threadIdx.x] - v;
    if (i < n) {
        rowptr[i] = excl; wp[i] = excl;
        if (i == n - 1) rowptr[n] = excl + v;
    }
}

__global__ void dis_kernel(const int* __restrict__ cnt, float* __restrict__ dis,
                           float* __restrict__ selfw, int n) {
    int i = blockIdx.x * NTHREADS + threadIdx.x;
    if (i < n) {
        float d = 1.0f + (float)cnt[i];
        dis[i] = rsqrtf(d);
        selfw[i] = 1.0f / d;
    }
}

__global__ void fill_kernel(const int* __restrict__ ei, const float* __restrict__ dis,
                            int* __restrict__ wp, int* __restrict__ csr_src,
                            float* __restrict__ coefA, int E) {
    int e = blockIdx.x * NTHREADS + threadIdx.x;
    if (e < E) {
        int s = ei[e], d = ei[E + e];
        int p = atomicAdd(&wp[d], 1);
        csr_src[p] = s;
        coefA[p] = dis[s] * dis[d];
    }
}

// ============================ fused weight prep (one launch) ============================
// wt0:[128][32]T  wt1,wt2:[128][128]T  wtih0:[256][128]C  wtih1,wtih2:[256][64]C
// whh0,whh1,whh2:[256][64]C        (T = transpose to [col][k], C = straight cast)
__global__ void wprep_all_kernel(const float* g0, const float* g1, const float* g2,
                                 const float* i0, const float* i1, const float* i2,
                                 const float* h0, const float* h1, const float* h2,
                                 u16* o_g0, u16* o_g1, u16* o_g2,
                                 u16* o_i0, u16* o_i1, u16* o_i2,
                                 u16* o_h0, u16* o_h1, u16* o_h2) {
    const int i = blockIdx.x * NTHREADS + threadIdx.x;
    if (i < 4096)        { o_g0[i] = f2bf(g0[(i & 31) * 128 + (i >> 5)]); }
    else if (i < 20480)  { int j = i - 4096;   o_g1[j] = f2bf(g1[(j & 127) * 128 + (j >> 7)]); }
    else if (i < 36864)  { int j = i - 20480;  o_g2[j] = f2bf(g2[(j & 127) * 128 + (j >> 7)]); }
    else if (i < 69632)  { int j = i - 36864;  o_i0[j] = f2bf(i0[j]); }
    else if (i < 86016)  { int j = i - 69632;  o_i1[j] = f2bf(i1[j]); }
    else if (i < 102400) { int j = i - 86016;  o_i2[j] = f2bf(i2[j]); }
    else if (i < 118784) { int j = i - 102400; o_h0[j] = f2bf(h0[j]); }
    else if (i < 135168) { int j = i - 118784; o_h1[j] = f2bf(h1[j]); }
    else if (i < 151552) { int j = i - 135168; o_h2[j] = f2bf(h2[j]); }
}

// ============================ aggregation, t-major + XCD-pinned ============================
// blockIdx.x = t (round-robin dispatch pins each t-slice to one XCD's L2).
// layer0: gathers fp32 x [t][n][32] directly, writes bf16 [t][n][32].
__global__ __launch_bounds__(NTHREADS)
void agg32t_kernel(const float* __restrict__ x, const int* __restrict__ rowptr,
                   const int* __restrict__ csrc, const float* __restrict__ coefA,
                   const float* __restrict__ selfw, u16* __restrict__ out, int N) {
    const int t = blockIdx.x;
    const int slot = threadIdx.x >> 3, lane = threadIdx.x & 7;
    const int n = blockIdx.y * 32 + slot;
    if (n >= N) return;
    const int c4 = lane * 4;
    const float* xb = x + (long)t * N * 32;
    const int e0 = rowptr[n], e1 = rowptr[n + 1];
    const float sw = selfw[n];
    const float4 sv = *(const float4*)(xb + (long)n * 32 + c4);
    float4 acc = make_float4(sw * sv.x, sw * sv.y, sw * sv.z, sw * sv.w);
    for (int e = e0; e < e1; ++e) {
        const float wgt = coefA[e];
        const int s = csrc[e];
        const float4 v = *(const float4*)(xb + (long)s * 32 + c4);
        acc.x = fmaf(wgt, v.x, acc.x);
        acc.y = fmaf(wgt, v.y, acc.y);
        acc.z = fmaf(wgt, v.z, acc.z);
        acc.w = fmaf(wgt, v.w, acc.w);
    }
    st_bf4(out + ((long)t * N + n) * 32 + c4, acc);
}

// 128-ch: bf16 h [t][n][128] (2.56 MB per t-slice -> fits 4MB per-XCD L2)
__global__ __launch_bounds__(NTHREADS)
void agg128t_kernel(const u16* __restrict__ h, const int* __restrict__ rowptr,
                    const int* __restrict__ csrc, const float* __restrict__ coefA,
                    const float* __restrict__ selfw, u16* __restrict__ out, int N) {
    const int t = blockIdx.x;
    const int slot = threadIdx.x >> 5, lane = threadIdx.x & 31;
    const int n = blockIdx.y * 8 + slot;
    const int c4 = lane * 4;
    const u16* hb = h + (long)t * N * 128;
    const int e0 = rowptr[n], e1 = rowptr[n + 1];
    const float sw = selfw[n];
    const float4 sv = ld_bf4(hb + (long)n * 128 + c4);
    float4 acc = make_float4(sw * sv.x, sw * sv.y, sw * sv.z, sw * sv.w);
    for (int e = e0; e < e1; ++e) {
        const float wgt = coefA[e];
        const int s = csrc[e];
        const float4 v = ld_bf4(hb + (long)s * 128 + c4);
        acc.x = fmaf(wgt, v.x, acc.x);
        acc.y = fmaf(wgt, v.y, acc.y);
        acc.z = fmaf(wgt, v.z, acc.z);
        acc.w = fmaf(wgt, v.w, acc.w);
    }
    st_bf4(out + ((long)t * N + n) * 128 + c4, acc);
}

// ============================ MFMA GEMM + fused epilogue ============================
// C[M][ldc] = A[M][K](bf16) @ Bt^T (Bt is [ncols][K] bf16).  128x128 tile, 4 waves,
// 2x8 tiles of v_mfma_f32_16x16x32_bf16, fp32 accumulate.
// EPI: 0 = +bias0+bias1, 1 = +bias0,ReLU, 2 = +bias0,ReLU,BN.
template<int K, int EPI, bool OUTBF>
__global__ __launch_bounds__(NTHREADS)
void mfma_gemm_kernel(const u16* __restrict__ A, const u16* __restrict__ Bt,
                      const float* __restrict__ bias0, const float* __restrict__ bias1,
                      const float* __restrict__ bng, const float* __restrict__ bnb,
                      const float* __restrict__ bnm, const float* __restrict__ bnv,
                      void* __restrict__ Cout, int ldc) {
    constexpr int KC = (K < 64) ? K : 64;
    constexpr int KP = KC + 8;
    constexpr int KV = KC / 8;
    __shared__ __align__(16) u16 As[128 * KP];
    __shared__ __align__(16) u16 Bs[128 * KP];
    const int tid = threadIdx.x;
    const long row0 = (long)blockIdx.x * 128;
    const int col0 = blockIdx.y * 128;
    const int wid = tid >> 6, lane = tid & 63;
    const int quad = lane >> 4, l16 = lane & 15;

    float4_t acc[2][8];
    #pragma unroll
    for (int rt = 0; rt < 2; ++rt)
        #pragma unroll
        for (int ct = 0; ct < 8; ++ct)
            acc[rt][ct] = (float4_t){0.f, 0.f, 0.f, 0.f};

    const int arow = wid * 32 + l16;
    const int koff = quad * 8;
    for (int ch = 0; ch < K / KC; ++ch) {
        const int kbase = ch * KC;
        for (int p = tid; p < 128 * KV; p += NTHREADS) {
            const int r = p / KV, kv = p % KV;
            *(uint4*)(&As[r * KP + kv * 8]) =
                *(const uint4*)(A + (row0 + r) * K + kbase + kv * 8);
        }
        for (int p = tid; p < 128 * KV; p += NTHREADS) {
            const int r = p / KV, kv = p % KV;
            *(uint4*)(&Bs[r * KP + kv * 8]) =
                *(const uint4*)(Bt + (long)(col0 + r) * K + kbase + kv * 8);
        }
        __syncthreads();
        #pragma unroll
        for (int kc = 0; kc < KC / 32; ++kc) {
            const short8_t a0 = *(const short8_t*)(&As[arow * KP + kc * 32 + koff]);
            const short8_t a1 = *(const short8_t*)(&As[(arow + 16) * KP + kc * 32 + koff]);
            #pragma unroll
            for (int ct = 0; ct < 8; ++ct) {
                const short8_t b = *(const short8_t*)(&Bs[(ct * 16 + l16) * KP + kc * 32 + koff]);
                acc[0][ct] = __builtin_amdgcn_mfma_f32_16x16x32_bf16(a0, b, acc[0][ct], 0, 0, 0);
                acc[1][ct] = __builtin_amdgcn_mfma_f32_16x16x32_bf16(a1, b, acc[1][ct], 0, 0, 0);
            }
        }
        __syncthreads();
    }

    float e_add0[8], e_mul[8], e_add1[8];
    #pragma unroll
    for (int ct = 0; ct < 8; ++ct) {
        const int c = col0 + ct * 16 + l16;
        if constexpr (EPI == 0) {
            e_add0[ct] = bias0[c] + bias1[c];
        } else if constexpr (EPI == 1) {
            e_add0[ct] = bias0[c];
        } else {
            e_add0[ct] = bias0[c];
            const float s = bng[c] * rsqrtf(bnv[c] + 1e-5f);
            e_mul[ct] = s;
            e_add1[ct] = bnb[c] - bnm[c] * s;
        }
    }
    #pragma unroll
    for (int rt = 0; rt < 2; ++rt) {
        #pragma unroll
        for (int r = 0; r < 4; ++r) {
            const long row = row0 + wid * 32 + rt * 16 + quad * 4 + r;
            #pragma unroll
            for (int ct = 0; ct < 8; ++ct) {
                float v = acc[rt][ct][r] + e_add0[ct];
                if constexpr (EPI >= 1) v = fmaxf(v, 0.f);
                if constexpr (EPI == 2) v = fmaf(v, e_mul[ct], e_add1[ct]);
                const long idx = row * (long)ldc + col0 + ct * 16 + l16;
                if constexpr (OUTBF) ((u16*)Cout)[idx] = f2bf(v);
                else ((float*)Cout)[idx] = v;
            }
        }
    }
}

// ============================ fully-fused 3-layer x 8-step LSTM ============================
// Per-node-independent recurrence: one block = 16 nodes, zero inter-block comm.
// Wave w owns gate units [w*16, w*16+16): i/f/g/o for a unit live in the SAME lane
// (col-tiles w, w+4(? no): cols g*64+w*16+l16) -> c/h state stays in registers.
// Weights: per-wave MFMA B-frags in VGPRs (5 matrices x 32 regs = 160).
// h exchanged via LDS as split-bf16 (hi+lo) -> recurrent GEMM ~fp16+ precision.
__global__ __launch_bounds__(NTHREADS, 2)
void lstm_fused_kernel(const float* __restrict__ G0,
                       const u16* __restrict__ whh0, const u16* __restrict__ wih1,
                       const u16* __restrict__ whh1, const u16* __restrict__ wih2,
                       const u16* __restrict__ whh2,
                       const float* __restrict__ bi1, const float* __restrict__ bh1,
                       const float* __restrict__ bi2, const float* __restrict__ bh2,
                       float* __restrict__ out, int N) {
    const int tid = threadIdx.x;
    const int w = tid >> 6, lane = tid & 63;
    const int quad = lane >> 4, l16 = lane & 15;
    const int n0 = blockIdx.x * 16;
    const int u = w * 16 + l16;                   // this lane's LSTM unit

    __shared__ __align__(16) u16 hT[3][2][16][72];   // [layer][hi/lo][node][unit(+pad)]
    {
        u16* hf = &hT[0][0][0][0];
        for (int p = tid; p < 3 * 2 * 16 * 72; p += NTHREADS) hf[p] = 0;
    }

    // weight B-fragments: fr[g][ks] = W[(g*64+u)][ks*32 + quad*8 + 0..7]
    short8_t fW[5][4][2];
    {
        const u16* Ws[5] = {whh0, wih1, whh1, wih2, whh2};
        #pragma unroll
        for (int m = 0; m < 5; ++m)
            #pragma unroll
            for (int g = 0; g < 4; ++g)
                #pragma unroll
                for (int ks = 0; ks < 2; ++ks)
                    fW[m][g][ks] = *(const short8_t*)(Ws[m] + (long)(g * 64 + u) * 64 + ks * 32 + quad * 8);
    }
    float bias[2][4];
    #pragma unroll
    for (int g = 0; g < 4; ++g) {
        bias[0][g] = bi1[g * 64 + u] + bh1[g * 64 + u];
        bias[1][g] = bi2[g * 64 + u] + bh2[g * 64 + u];
    }
    float cst[3][4] = {};   // c-state: [layer][row r] for node n0+quad*4+r, unit u
    __syncthreads();

    for (int t = 0; t < T_STEPS; ++t) {
        // ---------------- layer 0 ----------------
        short8_t ah[2], al[2];
        #pragma unroll
        for (int ks = 0; ks < 2; ++ks) {
            ah[ks] = *(const short8_t*)(&hT[0][0][l16][ks * 32 + quad * 8]);
            al[ks] = *(const short8_t*)(&hT[0][1][l16][ks * 32 + quad * 8]);
        }
        __syncthreads();                        // h0 reads done before overwrite
        float4_t acc[4];
        #pragma unroll
        for (int g = 0; g < 4; ++g) {
            float4_t v;
            #pragma unroll
            for (int r = 0; r < 4; ++r)
                v[r] = G0[((long)t * N + n0 + quad * 4 + r) * 256 + g * 64 + u];
            acc[g] = v;
        }
        #pragma unroll
        for (int ks = 0; ks < 2; ++ks)
            #pragma unroll
            for (int g = 0; g < 4; ++g) {
                acc[g] = __builtin_amdgcn_mfma_f32_16x16x32_bf16(ah[ks], fW[0][g][ks], acc[g], 0, 0, 0);
                acc[g] = __builtin_amdgcn_mfma_f32_16x16x32_bf16(al[ks], fW[0][g][ks], acc[g], 0, 0, 0);
            }
        #pragma unroll
        for (int r = 0; r < 4; ++r) {
            const float si = sigmoidf(acc[0][r]);
            const float sf = sigmoidf(acc[1][r]);
            const float gg = tanhf(acc[2][r]);
            const float so = sigmoidf(acc[3][r]);
            const float c = sf * cst[0][r] + si * gg;
            cst[0][r] = c;
            const float h = so * tanhf(c);
            const u16 hi = f2bf(h);
            hT[0][0][quad * 4 + r][u] = hi;
            hT[0][1][quad * 4 + r][u] = f2bf(h - bf2f(hi));
        }
        __syncthreads();                        // h0(t) visible

        // ---------------- layers 1, 2 ----------------
        #pragma unroll
        for (int l = 1; l < 3; ++l) {
            short8_t inh[2], inl[2], reh[2], rel[2];
            #pragma unroll
            for (int ks = 0; ks < 2; ++ks) {
                inh[ks] = *(const short8_t*)(&hT[l - 1][0][l16][ks * 32 + quad * 8]);
                inl[ks] = *(const short8_t*)(&hT[l - 1][1][l16][ks * 32 + quad * 8]);
                reh[ks] = *(const short8_t*)(&hT[l][0][l16][ks * 32 + quad * 8]);
                rel[ks] = *(const short8_t*)(&hT[l][1][l16][ks * 32 + quad * 8]);
            }
            __syncthreads();                    // h_l reads done before overwrite
            #pragma unroll
            for (int g = 0; g < 4; ++g) {
                const float b = bias[l - 1][g];
                acc[g] = (float4_t){b, b, b, b};
            }
            const int mi = 2 * l - 1, mr = 2 * l;   // fW indices: Wih_l, Whh_l
            #pragma unroll
            for (int ks = 0; ks < 2; ++ks)
                #pragma unroll
                for (int g = 0; g < 4; ++g) {
                    acc[g] = __builtin_amdgcn_mfma_f32_16x16x32_bf16(inh[ks], fW[mi][g][ks], acc[g], 0, 0, 0);
                    acc[g] = __builtin_amdgcn_mfma_f32_16x16x32_bf16(inl[ks], fW[mi][g][ks], acc[g], 0, 0, 0);
                    acc[g] = __builtin_amdgcn_mfma_f32_16x16x32_bf16(reh[ks], fW[mr][g][ks], acc[g], 0, 0, 0);
                    acc[g] = __builtin_amdgcn_mfma_f32_16x16x32_bf16(rel[ks], fW[mr][g][ks], acc[g], 0, 0, 0);
                }
            #pragma unroll
            for (int r = 0; r < 4; ++r) {
                const float si = sigmoidf(acc[0][r]);
                const float sf = sigmoidf(acc[1][r]);
                const float gg = tanhf(acc[2][r]);
                const float so = sigmoidf(acc[3][r]);
                const float c = sf * cst[l][r] + si * gg;
                cst[l][r] = c;
                const float h = so * tanhf(c);
                if (l == 2 && t == T_STEPS - 1)
                    out[(long)(n0 + quad * 4 + r) * 64 + u] = h;
                const u16 hi = f2bf(h);
                hT[l][0][quad * 4 + r][u] = hi;
                hT[l][1][quad * 4 + r][u] = f2bf(h - bf2f(hi));
            }
            __syncthreads();                    // h_l(t) visible
        }
    }
}

// ============================ launch ============================
extern "C" void kernel_launch(void* const* d_in, const int* in_sizes, int n_in,
                              void* d_out, int out_size, void* d_ws, size_t ws_size,
                              hipStream_t stream) {
    (void)n_in; (void)out_size; (void)ws_size;
    const float* x      = (const float*)d_in[0];
    const int*   ei     = (const int*)d_in[1];
    const float* w_gcn0 = (const float*)d_in[2];
    const float* b_gcn0 = (const float*)d_in[3];
    const float* w_gcn1 = (const float*)d_in[4];
    const float* b_gcn1 = (const float*)d_in[5];
    const float* w_gcn2 = (const float*)d_in[6];
    const float* b_gcn2 = (const float*)d_in[7];
    const float* bn_g0  = (const float*)d_in[8];
    const float* bn_b0  = (const float*)d_in[9];
    const float* bn_m0  = (const float*)d_in[10];
    const float* bn_v0  = (const float*)d_in[11];
    const float* bn_g1  = (const float*)d_in[12];
    const float* bn_b1  = (const float*)d_in[13];
    const float* bn_m1  = (const float*)d_in[14];
    const float* bn_v1  = (const float*)d_in[15];
    const float* w_ih_0 = (const float*)d_in[16];
    const float* w_hh_0 = (const float*)d_in[17];
    const float* b_ih_0 = (const float*)d_in[18];
    const float* b_hh_0 = (const float*)d_in[19];
    const float* w_ih_1 = (const float*)d_in[20];
    const float* w_hh_1 = (const float*)d_in[21];
    const float* b_ih_1 = (const float*)d_in[22];
    const float* b_hh_1 = (const float*)d_in[23];
    const float* w_ih_2 = (const float*)d_in[24];
    const float* w_hh_2 = (const float*)d_in[25];
    const float* b_ih_2 = (const float*)d_in[26];
    const float* b_hh_2 = (const float*)d_in[27];

    const int E = in_sizes[1] / 2;
    const int N = in_sizes[0] / (T_STEPS * F_INC);     // 10000
    const long M = (long)N * T_STEPS;                  // 80000

    // ---- workspace carve ----
    char* ws = (char*)d_ws;
    size_t off = 0;
    auto carve = [&](size_t bytes) -> void* {
        void* p = ws + off;
        off += (bytes + 255) & ~(size_t)255;
        return p;
    };
    float* dis     = (float*)carve((size_t)N * 4);
    float* selfw   = (float*)carve((size_t)N * 4);
    float* coefA   = (float*)carve((size_t)E * 4);
    int*   cnt     = (int*)carve((size_t)N * 4);
    int*   rowptr  = (int*)carve((size_t)(N + 1) * 4);
    int*   wp      = (int*)carve((size_t)N * 4);
    int*   csr_src = (int*)carve((size_t)E * 4);
    int*   bsum    = (int*)carve(64 * 4);
    int*   boff    = (int*)carve(64 * 4);
    u16*   hbuf    = (u16*)carve((size_t)M * H_DIM * 2);      // 20.5 MB, [t][n][128]
    u16*   wt0     = (u16*)carve((size_t)128 * 32 * 2);
    u16*   wt1     = (u16*)carve((size_t)128 * 128 * 2);
    u16*   wt2     = (u16*)carve((size_t)128 * 128 * 2);
    u16*   wtih0   = (u16*)carve((size_t)256 * 128 * 2);
    u16*   wtih1   = (u16*)carve((size_t)256 * 64 * 2);
    u16*   wtih2   = (u16*)carve((size_t)256 * 64 * 2);
    u16*   whh0b   = (u16*)carve((size_t)256 * 64 * 2);
    u16*   whh1b   = (u16*)carve((size_t)256 * 64 * 2);
    u16*   whh2b   = (u16*)carve((size_t)256 * 64 * 2);
    float* G       = (float*)carve((size_t)M * 256 * 4);      // 81.9 MB
    u16*   abuf    = (u16*)G;      // agg scratch aliases G (disjoint lifetimes)

    const dim3 b256(NTHREADS);
    const int gN = (N + NTHREADS - 1) / NTHREADS;      // 40
    const int gE = (E + NTHREADS - 1) / NTHREADS;

    // ---- CSR + normalization ----
    init_cnt_kernel<<<gN, b256, 0, stream>>>(cnt, N);
    count_kernel<<<gE, b256, 0, stream>>>(ei, cnt, E);
    scan_part1<<<gN, b256, 0, stream>>>(cnt, bsum, N);
    scan_part2<<<1, 64, 0, stream>>>(bsum, boff, gN);
    scan_part3<<<gN, b256, 0, stream>>>(cnt, boff, rowptr, wp, N);
    dis_kernel<<<gN, b256, 0, stream>>>(cnt, dis, selfw, N);
    fill_kernel<<<gE, b256, 0, stream>>>(ei, dis, wp, csr_src, coefA, E);

    // ---- weight prep (single launch) ----
    wprep_all_kernel<<<(151552 + 255) / 256, b256, 0, stream>>>(
        w_gcn0, w_gcn1, w_gcn2, w_ih_0, w_ih_1, w_ih_2, w_hh_0, w_hh_1, w_hh_2,
        wt0, wt1, wt2, wtih0, wtih1, wtih2, whh0b, whh1b, whh2b);

    // ---- GCN: aggregate-first (t-major, XCD-pinned), MFMA GEMM + fused epilogue ----
    const int gBlk = (int)(M / 128);   // 625
    agg32t_kernel<<<dim3(T_STEPS, (N + 31) / 32), b256, 0, stream>>>(
        x, rowptr, csr_src, coefA, selfw, abuf, N);
    mfma_gemm_kernel<32, 2, true><<<dim3(gBlk, 1), b256, 0, stream>>>(
        abuf, wt0, b_gcn0, nullptr, bn_g0, bn_b0, bn_m0, bn_v0, hbuf, 128);
    agg128t_kernel<<<dim3(T_STEPS, N / 8), b256, 0, stream>>>(
        hbuf, rowptr, csr_src, coefA, selfw, abuf, N);
    mfma_gemm_kernel<128, 2, true><<<dim3(gBlk, 1), b256, 0, stream>>>(
        abuf, wt1, b_gcn1, nullptr, bn_g1, bn_b1, bn_m1, bn_v1, hbuf, 128);
    agg128t_kernel<<<dim3(T_STEPS, N / 8), b256, 0, stream>>>(
        hbuf, rowptr, csr_src, coefA, selfw, abuf, N);
    mfma_gemm_kernel<128, 1, true><<<dim3(gBlk, 1), b256, 0, stream>>>(
        abuf, wt2, b_gcn2, nullptr, nullptr, nullptr, nullptr, nullptr, hbuf, 128);

    // ---- LSTM: one big input-GEMM (layer0 gates) + one fully-fused kernel ----
    mfma_gemm_kernel<128, 0, false><<<dim3(gBlk, 2), b256, 0, stream>>>(
        hbuf, wtih0, b_ih_0, b_hh_0, nullptr, nullptr, nullptr, nullptr, G, 256);
    lstm_fused_kernel<<<N / 16, b256, 0, stream>>>(
        G, whh0b, wtih1, whh1b, wtih2, whh2b,
        b_ih_1, b_hh_1, b_ih_2, b_hh_2, (float*)d_out, N);
}

// Round 4
// 426.498 us; speedup vs baseline: 2.7430x; 1.1027x over previous
//
#include <hip/hip_runtime.h>
#include <hip/hip_bf16.h>
#include <math.h>

#define NTHREADS 256
#define T_STEPS 8
#define F_INC 32
#define H_DIM 128
#define O_DIM 64

typedef unsigned short u16;
typedef __attribute__((ext_vector_type(8))) short short8_t;
typedef __attribute__((ext_vector_type(4))) float float4_t;

__device__ __forceinline__ float bf2f(u16 u) {
    return __uint_as_float(((unsigned)u) << 16);
}
__device__ __forceinline__ u16 f2bf(float f) {
    __hip_bfloat16 h = __float2bfloat16(f);   // RNE
    union { __hip_bfloat16 h; u16 s; } cv; cv.h = h; return cv.s;
}
__device__ __forceinline__ float4 ld_bf4(const u16* p) {
    uint2 u = *(const uint2*)p;
    return make_float4(__uint_as_float(u.x << 16), __uint_as_float(u.x & 0xffff0000u),
                       __uint_as_float(u.y << 16), __uint_as_float(u.y & 0xffff0000u));
}
__device__ __forceinline__ void st_bf4(u16* p, float4 v) {
    ushort4 s = make_ushort4(f2bf(v.x), f2bf(v.y), f2bf(v.z), f2bf(v.w));
    *(ushort4*)p = s;
}
// fast sigmoid/tanh: v_exp_f32 + v_rcp_f32 (~1ulp each, << bf16 noise)
__device__ __forceinline__ float fsig(float x) {
    float xc = fminf(fmaxf(x, -30.f), 30.f);
    float e = __builtin_amdgcn_exp2f(xc * -1.4426950408889634f);   // e^{-x}
    return __builtin_amdgcn_rcpf(1.0f + e);
}
__device__ __forceinline__ float ftanh(float x) {
    float xc = fminf(fmaxf(x, -15.f), 15.f);
    float e = __builtin_amdgcn_exp2f(xc * -2.8853900817779268f);   // e^{-2x}
    float r = __builtin_amdgcn_rcpf(1.0f + e);
    return fmaf(-2.0f * e, r, 1.0f);                               // (1-e)/(1+e)
}

// ============================ CSR build ============================
__global__ void init_cnt_kernel(int* __restrict__ cnt, int n) {
    int i = blockIdx.x * NTHREADS + threadIdx.x;
    if (i < n) cnt[i] = 0;
}

__global__ void count_kernel(const int* __restrict__ ei, int* __restrict__ cnt, int E) {
    int e = blockIdx.x * NTHREADS + threadIdx.x;
    if (e < E) atomicAdd(&cnt[ei[E + e]], 1);   // dst row of edge_index
}

__global__ void scan_part1(const int* __restrict__ cnt, int* __restrict__ bsum, int n) {
    __shared__ int sd[NTHREADS];
    const int i = blockIdx.x * NTHREADS + threadIdx.x;
    sd[threadIdx.x] = (i < n) ? cnt[i] : 0;
    __syncthreads();
    for (int off = 128; off > 0; off >>= 1) {
        if (threadIdx.x < off) sd[threadIdx.x] += sd[threadIdx.x + off];
        __syncthreads();
    }
    if (threadIdx.x == 0) bsum[blockIdx.x] = sd[0];
}
__global__ void scan_part2(const int* __restrict__ bsum, int* __restrict__ boff, int nb) {
    if (threadIdx.x == 0) {
        int s = 0;
        for (int b = 0; b < nb; ++b) { boff[b] = s; s += bsum[b]; }
    }
}
// + fused dis/selfw computation (saves one launch)
__global__ void scan_part3(const int* __restrict__ cnt, const int* __restrict__ boff,
                           int* __restrict__ rowptr, int* __restrict__ wp,
                           float* __restrict__ dis, float* __restrict__ selfw, int n) {
    __shared__ int sd[NTHREADS];
    const int i = blockIdx.x * NTHREADS + threadIdx.x;
    const int v = (i < n) ? cnt[i] : 0;
    sd[threadIdx.x] = v;
    __syncthreads();
    for (int off = 1; off < NTHREADS; off <<= 1) {
        const int tv = (threadIdx.x >= off) ? sd[threadIdx.x - off] : 0;
        __syncthreads();
        sd[threadIdx.x] += tv;
        __syncthreads();
    }
    const int excl = boff[blockIdx.x] + sd[threadIdx.x] - v;
    if (i < n) {
        rowptr[i] = excl; wp[i] = excl;
        if (i == n - 1) rowptr[n] = excl + v;
        const float d = 1.0f + (float)v;
        dis[i] = rsqrtf(d);
        selfw[i] = 1.0f / d;
    }
}

__global__ void fill_kernel(const int* __restrict__ ei, const float* __restrict__ dis,
                            int* __restrict__ wp, int* __restrict__ csr_src,
                            float* __restrict__ coefA, int E) {
    int e = blockIdx.x * NTHREADS + threadIdx.x;
    if (e < E) {
        int s = ei[e], d = ei[E + e];
        int p = atomicAdd(&wp[d], 1);
        csr_src[p] = s;
        coefA[p] = dis[s] * dis[d];
    }
}

// ============================ fused weight prep (one launch) ============================
__global__ void wprep_all_kernel(const float* g0, const float* g1, const float* g2,
                                 const float* i0, const float* i1, const float* i2,
                                 const float* h0, const float* h1, const float* h2,
                                 u16* o_g0, u16* o_g1, u16* o_g2,
                                 u16* o_i0, u16* o_i1, u16* o_i2,
                                 u16* o_h0, u16* o_h1, u16* o_h2) {
    const int i = blockIdx.x * NTHREADS + threadIdx.x;
    if (i < 4096)        { o_g0[i] = f2bf(g0[(i & 31) * 128 + (i >> 5)]); }
    else if (i < 20480)  { int j = i - 4096;   o_g1[j] = f2bf(g1[(j & 127) * 128 + (j >> 7)]); }
    else if (i < 36864)  { int j = i - 20480;  o_g2[j] = f2bf(g2[(j & 127) * 128 + (j >> 7)]); }
    else if (i < 69632)  { int j = i - 36864;  o_i0[j] = f2bf(i0[j]); }
    else if (i < 86016)  { int j = i - 69632;  o_i1[j] = f2bf(i1[j]); }
    else if (i < 102400) { int j = i - 86016;  o_i2[j] = f2bf(i2[j]); }
    else if (i < 118784) { int j = i - 102400; o_h0[j] = f2bf(h0[j]); }
    else if (i < 135168) { int j = i - 118784; o_h1[j] = f2bf(h1[j]); }
    else if (i < 151552) { int j = i - 135168; o_h2[j] = f2bf(h2[j]); }
}

// ============================ aggregation, t-major + XCD-pinned ============================
__global__ __launch_bounds__(NTHREADS)
void agg32t_kernel(const float* __restrict__ x, const int* __restrict__ rowptr,
                   const int* __restrict__ csrc, const float* __restrict__ coefA,
                   const float* __restrict__ selfw, u16* __restrict__ out, int N) {
    const int t = blockIdx.x;
    const int slot = threadIdx.x >> 3, lane = threadIdx.x & 7;
    const int n = blockIdx.y * 32 + slot;
    if (n >= N) return;
    const int c4 = lane * 4;
    const float* xb = x + (long)t * N * 32;
    const int e0 = rowptr[n], e1 = rowptr[n + 1];
    const float sw = selfw[n];
    const float4 sv = *(const float4*)(xb + (long)n * 32 + c4);
    float4 acc = make_float4(sw * sv.x, sw * sv.y, sw * sv.z, sw * sv.w);
    for (int e = e0; e < e1; ++e) {
        const float wgt = coefA[e];
        const int s = csrc[e];
        const float4 v = *(const float4*)(xb + (long)s * 32 + c4);
        acc.x = fmaf(wgt, v.x, acc.x);
        acc.y = fmaf(wgt, v.y, acc.y);
        acc.z = fmaf(wgt, v.z, acc.z);
        acc.w = fmaf(wgt, v.w, acc.w);
    }
    st_bf4(out + ((long)t * N + n) * 32 + c4, acc);
}

__global__ __launch_bounds__(NTHREADS)
void agg128t_kernel(const u16* __restrict__ h, const int* __restrict__ rowptr,
                    const int* __restrict__ csrc, const float* __restrict__ coefA,
                    const float* __restrict__ selfw, u16* __restrict__ out, int N) {
    const int t = blockIdx.x;
    const int slot = threadIdx.x >> 5, lane = threadIdx.x & 31;
    const int n = blockIdx.y * 8 + slot;
    const int c4 = lane * 4;
    const u16* hb = h + (long)t * N * 128;
    const int e0 = rowptr[n], e1 = rowptr[n + 1];
    const float sw = selfw[n];
    const float4 sv = ld_bf4(hb + (long)n * 128 + c4);
    float4 acc = make_float4(sw * sv.x, sw * sv.y, sw * sv.z, sw * sv.w);
    for (int e = e0; e < e1; ++e) {
        const float wgt = coefA[e];
        const int s = csrc[e];
        const float4 v = ld_bf4(hb + (long)s * 128 + c4);
        acc.x = fmaf(wgt, v.x, acc.x);
        acc.y = fmaf(wgt, v.y, acc.y);
        acc.z = fmaf(wgt, v.z, acc.z);
        acc.w = fmaf(wgt, v.w, acc.w);
    }
    st_bf4(out + ((long)t * N + n) * 128 + c4, acc);
}

// ============================ MFMA GEMM + fused epilogue ============================
// EPI: 1 = +bias0,ReLU, 2 = +bias0,ReLU,BN.
template<int K, int EPI, bool OUTBF>
__global__ __launch_bounds__(NTHREADS)
void mfma_gemm_kernel(const u16* __restrict__ A, const u16* __restrict__ Bt,
                      const float* __restrict__ bias0,
                      const float* __restrict__ bng, const float* __restrict__ bnb,
                      const float* __restrict__ bnm, const float* __restrict__ bnv,
                      void* __restrict__ Cout, int ldc) {
    constexpr int KC = (K < 64) ? K : 64;
    constexpr int KP = KC + 8;
    constexpr int KV = KC / 8;
    __shared__ __align__(16) u16 As[128 * KP];
    __shared__ __align__(16) u16 Bs[128 * KP];
    const int tid = threadIdx.x;
    const long row0 = (long)blockIdx.x * 128;
    const int col0 = blockIdx.y * 128;
    const int wid = tid >> 6, lane = tid & 63;
    const int quad = lane >> 4, l16 = lane & 15;

    float4_t acc[2][8];
    #pragma unroll
    for (int rt = 0; rt < 2; ++rt)
        #pragma unroll
        for (int ct = 0; ct < 8; ++ct)
            acc[rt][ct] = (float4_t){0.f, 0.f, 0.f, 0.f};

    const int arow = wid * 32 + l16;
    const int koff = quad * 8;
    for (int ch = 0; ch < K / KC; ++ch) {
        const int kbase = ch * KC;
        for (int p = tid; p < 128 * KV; p += NTHREADS) {
            const int r = p / KV, kv = p % KV;
            *(uint4*)(&As[r * KP + kv * 8]) =
                *(const uint4*)(A + (row0 + r) * K + kbase + kv * 8);
        }
        for (int p = tid; p < 128 * KV; p += NTHREADS) {
            const int r = p / KV, kv = p % KV;
            *(uint4*)(&Bs[r * KP + kv * 8]) =
                *(const uint4*)(Bt + (long)(col0 + r) * K + kbase + kv * 8);
        }
        __syncthreads();
        #pragma unroll
        for (int kc = 0; kc < KC / 32; ++kc) {
            const short8_t a0 = *(const short8_t*)(&As[arow * KP + kc * 32 + koff]);
            const short8_t a1 = *(const short8_t*)(&As[(arow + 16) * KP + kc * 32 + koff]);
            #pragma unroll
            for (int ct = 0; ct < 8; ++ct) {
                const short8_t b = *(const short8_t*)(&Bs[(ct * 16 + l16) * KP + kc * 32 + koff]);
                acc[0][ct] = __builtin_amdgcn_mfma_f32_16x16x32_bf16(a0, b, acc[0][ct], 0, 0, 0);
                acc[1][ct] = __builtin_amdgcn_mfma_f32_16x16x32_bf16(a1, b, acc[1][ct], 0, 0, 0);
            }
        }
        __syncthreads();
    }

    float e_add0[8], e_mul[8], e_add1[8];
    #pragma unroll
    for (int ct = 0; ct < 8; ++ct) {
        const int c = col0 + ct * 16 + l16;
        e_add0[ct] = bias0[c];
        if constexpr (EPI == 2) {
            const float s = bng[c] * rsqrtf(bnv[c] + 1e-5f);
            e_mul[ct] = s;
            e_add1[ct] = bnb[c] - bnm[c] * s;
        }
    }
    #pragma unroll
    for (int rt = 0; rt < 2; ++rt) {
        #pragma unroll
        for (int r = 0; r < 4; ++r) {
            const long row = row0 + wid * 32 + rt * 16 + quad * 4 + r;
            #pragma unroll
            for (int ct = 0; ct < 8; ++ct) {
                float v = fmaxf(acc[rt][ct][r] + e_add0[ct], 0.f);
                if constexpr (EPI == 2) v = fmaf(v, e_mul[ct], e_add1[ct]);
                const long idx = row * (long)ldc + col0 + ct * 16 + l16;
                if constexpr (OUTBF) ((u16*)Cout)[idx] = f2bf(v);
                else ((float*)Cout)[idx] = v;
            }
        }
    }
}

// ============================ per-layer fused LSTM ============================
// One block = 16 nodes, 4 waves; wave w owns gate units [w*16, w*16+16) so i/f/g/o of
// a unit live in the same lane (D-layout: node=quad*4+r, unit=l16). Per-layer split
// keeps weight fragments at 16-24 short8/wave (64-96 VGPR) -> 2-3 blocks/CU resident.
// Input h arrives as bf16 (KIN=128, plain) or split hi/lo bf16 planes (KIN=64).
// Recurrent h goes through LDS as hi/lo bf16 (~fp16+ precision), c-state fp32 regs.
template<int KIN, bool IN_SPLIT, bool LAST>
__global__ __launch_bounds__(NTHREADS, 2)
void lstm_layer_kernel(const u16* __restrict__ in_hi, const u16* __restrict__ in_lo,
                       const u16* __restrict__ wih, const u16* __restrict__ whh,
                       const float* __restrict__ bi, const float* __restrict__ bh,
                       u16* __restrict__ out_hi, u16* __restrict__ out_lo,
                       float* __restrict__ out_f, int N) {
    constexpr int NKS = KIN / 32;
    constexpr int HSTR = 76;          // hT row stride (u16): breaks write-bank overlap
    const int tid = threadIdx.x;
    const int w = tid >> 6, lane = tid & 63;
    const int quad = lane >> 4, l16 = lane & 15;
    const int n0 = blockIdx.x * 16;
    const int u = w * 16 + l16;       // this lane's LSTM unit

    __shared__ __align__(16) u16 hT[2][16][HSTR];    // [hi/lo][node][unit]
    for (int p = tid; p < 2 * 16 * HSTR; p += NTHREADS) (&hT[0][0][0])[p] = 0;

    // preload weights (held in regs across the whole t-loop)
    short8_t fI[4][NKS], fH[4][2];
    #pragma unroll
    for (int g = 0; g < 4; ++g) {
        #pragma unroll
        for (int ks = 0; ks < NKS; ++ks)
            fI[g][ks] = *(const short8_t*)(wih + (long)(g * 64 + u) * KIN + ks * 32 + quad * 8);
        #pragma unroll
        for (int ks = 0; ks < 2; ++ks)
            fH[g][ks] = *(const short8_t*)(whh + (long)(g * 64 + u) * 64 + ks * 32 + quad * 8);
    }
    float bias[4];
    #pragma unroll
    for (int g = 0; g < 4; ++g) bias[g] = bi[g * 64 + u] + bh[g * 64 + u];
    float cst[4] = {};
    __syncthreads();

    #pragma unroll 1
    for (int t = 0; t < T_STEPS; ++t) {
        // input-h A-fragments (global, streamed)
        short8_t ain[NKS], ainl[NKS];
        const long ibase = ((long)t * N + n0 + l16) * KIN + quad * 8;
        #pragma unroll
        for (int ks = 0; ks < NKS; ++ks) {
            ain[ks] = *(const short8_t*)(in_hi + ibase + ks * 32);
            if constexpr (IN_SPLIT) ainl[ks] = *(const short8_t*)(in_lo + ibase + ks * 32);
        }
        // recurrent-h A-fragments (LDS)
        short8_t ah[2], al[2];
        #pragma unroll
        for (int ks = 0; ks < 2; ++ks) {
            ah[ks] = *(const short8_t*)(&hT[0][l16][ks * 32 + quad * 8]);
            al[ks] = *(const short8_t*)(&hT[1][l16][ks * 32 + quad * 8]);
        }
        __syncthreads();              // reads done before this t's writes

        float4_t acc[4];
        #pragma unroll
        for (int g = 0; g < 4; ++g) acc[g] = (float4_t){bias[g], bias[g], bias[g], bias[g]};
        #pragma unroll
        for (int ks = 0; ks < NKS; ++ks)
            #pragma unroll
            for (int g = 0; g < 4; ++g) {
                acc[g] = __builtin_amdgcn_mfma_f32_16x16x32_bf16(ain[ks], fI[g][ks], acc[g], 0, 0, 0);
                if constexpr (IN_SPLIT)
                    acc[g] = __builtin_amdgcn_mfma_f32_16x16x32_bf16(ainl[ks], fI[g][ks], acc[g], 0, 0, 0);
            }
        #pragma unroll
        for (int ks = 0; ks < 2; ++ks)
            #pragma unroll
            for (int g = 0; g < 4; ++g) {
                acc[g] = __builtin_amdgcn_mfma_f32_16x16x32_bf16(ah[ks], fH[g][ks], acc[g], 0, 0, 0);
                acc[g] = __builtin_amdgcn_mfma_f32_16x16x32_bf16(al[ks], fH[g][ks], acc[g], 0, 0, 0);
            }

        #pragma unroll
        for (int r = 0; r < 4; ++r) {
            const float si = fsig(acc[0][r]);
            const float sf = fsig(acc[1][r]);
            const float gg = ftanh(acc[2][r]);
            const float so = fsig(acc[3][r]);
            const float c = sf * cst[r] + si * gg;
            cst[r] = c;
            const float h = so * ftanh(c);
            const int node = quad * 4 + r;
            const u16 hi = f2bf(h);
            const u16 lo = f2bf(h - bf2f(hi));
            hT[0][node][u] = hi;
            hT[1][node][u] = lo;
            if constexpr (LAST) {
                if (t == T_STEPS - 1) out_f[(long)(n0 + node) * 64 + u] = h;
            } else {
                const long o = ((long)t * N + n0 + node) * 64 + u;
                out_hi[o] = hi;
                out_lo[o] = lo;
            }
        }
        __syncthreads();              // h(t) visible for t+1
    }
}

// ============================ launch ============================
extern "C" void kernel_launch(void* const* d_in, const int* in_sizes, int n_in,
                              void* d_out, int out_size, void* d_ws, size_t ws_size,
                              hipStream_t stream) {
    (void)n_in; (void)out_size; (void)ws_size;
    const float* x      = (const float*)d_in[0];
    const int*   ei     = (const int*)d_in[1];
    const float* w_gcn0 = (const float*)d_in[2];
    const float* b_gcn0 = (const float*)d_in[3];
    const float* w_gcn1 = (const float*)d_in[4];
    const float* b_gcn1 = (const float*)d_in[5];
    const float* w_gcn2 = (const float*)d_in[6];
    const float* b_gcn2 = (const float*)d_in[7];
    const float* bn_g0  = (const float*)d_in[8];
    const float* bn_b0  = (const float*)d_in[9];
    const float* bn_m0  = (const float*)d_in[10];
    const float* bn_v0  = (const float*)d_in[11];
    const float* bn_g1  = (const float*)d_in[12];
    const float* bn_b1  = (const float*)d_in[13];
    const float* bn_m1  = (const float*)d_in[14];
    const float* bn_v1  = (const float*)d_in[15];
    const float* w_ih_0 = (const float*)d_in[16];
    const float* w_hh_0 = (const float*)d_in[17];
    const float* b_ih_0 = (const float*)d_in[18];
    const float* b_hh_0 = (const float*)d_in[19];
    const float* w_ih_1 = (const float*)d_in[20];
    const float* w_hh_1 = (const float*)d_in[21];
    const float* b_ih_1 = (const float*)d_in[22];
    const float* b_hh_1 = (const float*)d_in[23];
    const float* w_ih_2 = (const float*)d_in[24];
    const float* w_hh_2 = (const float*)d_in[25];
    const float* b_ih_2 = (const float*)d_in[26];
    const float* b_hh_2 = (const float*)d_in[27];

    const int E = in_sizes[1] / 2;
    const int N = in_sizes[0] / (T_STEPS * F_INC);     // 10000
    const long M = (long)N * T_STEPS;                  // 80000

    // ---- workspace carve ----
    char* ws = (char*)d_ws;
    size_t off = 0;
    auto carve = [&](size_t bytes) -> void* {
        void* p = ws + off;
        off += (bytes + 255) & ~(size_t)255;
        return p;
    };
    float* dis     = (float*)carve((size_t)N * 4);
    float* selfw   = (float*)carve((size_t)N * 4);
    float* coefA   = (float*)carve((size_t)E * 4);
    int*   cnt     = (int*)carve((size_t)N * 4);
    int*   rowptr  = (int*)carve((size_t)(N + 1) * 4);
    int*   wp      = (int*)carve((size_t)N * 4);
    int*   csr_src = (int*)carve((size_t)E * 4);
    int*   bsum    = (int*)carve(64 * 4);
    int*   boff    = (int*)carve(64 * 4);
    u16*   hbuf    = (u16*)carve((size_t)M * H_DIM * 2);      // 20.5 MB, [t][n][128]
    u16*   abuf    = (u16*)carve((size_t)M * H_DIM * 2);      // 20.5 MB agg scratch
    u16*   pA_hi   = (u16*)carve((size_t)M * O_DIM * 2);      // layer handoff planes
    u16*   pA_lo   = (u16*)carve((size_t)M * O_DIM * 2);
    u16*   pB_hi   = (u16*)carve((size_t)M * O_DIM * 2);
    u16*   pB_lo   = (u16*)carve((size_t)M * O_DIM * 2);
    u16*   wt0     = (u16*)carve((size_t)128 * 32 * 2);
    u16*   wt1     = (u16*)carve((size_t)128 * 128 * 2);
    u16*   wt2     = (u16*)carve((size_t)128 * 128 * 2);
    u16*   wtih0   = (u16*)carve((size_t)256 * 128 * 2);
    u16*   wtih1   = (u16*)carve((size_t)256 * 64 * 2);
    u16*   wtih2   = (u16*)carve((size_t)256 * 64 * 2);
    u16*   whh0b   = (u16*)carve((size_t)256 * 64 * 2);
    u16*   whh1b   = (u16*)carve((size_t)256 * 64 * 2);
    u16*   whh2b   = (u16*)carve((size_t)256 * 64 * 2);

    const dim3 b256(NTHREADS);
    const int gN = (N + NTHREADS - 1) / NTHREADS;      // 40
    const int gE = (E + NTHREADS - 1) / NTHREADS;

    // ---- CSR + normalization ----
    init_cnt_kernel<<<gN, b256, 0, stream>>>(cnt, N);
    count_kernel<<<gE, b256, 0, stream>>>(ei, cnt, E);
    scan_part1<<<gN, b256, 0, stream>>>(cnt, bsum, N);
    scan_part2<<<1, 64, 0, stream>>>(bsum, boff, gN);
    scan_part3<<<gN, b256, 0, stream>>>(cnt, boff, rowptr, wp, dis, selfw, N);
    fill_kernel<<<gE, b256, 0, stream>>>(ei, dis, wp, csr_src, coefA, E);

    // ---- weight prep (single launch) ----
    wprep_all_kernel<<<(151552 + 255) / 256, b256, 0, stream>>>(
        w_gcn0, w_gcn1, w_gcn2, w_ih_0, w_ih_1, w_ih_2, w_hh_0, w_hh_1, w_hh_2,
        wt0, wt1, wt2, wtih0, wtih1, wtih2, whh0b, whh1b, whh2b);

    // ---- GCN: aggregate-first (t-major, XCD-pinned), MFMA GEMM + fused epilogue ----
    const int gBlk = (int)(M / 128);   // 625
    agg32t_kernel<<<dim3(T_STEPS, (N + 31) / 32), b256, 0, stream>>>(
        x, rowptr, csr_src, coefA, selfw, abuf, N);
    mfma_gemm_kernel<32, 2, true><<<dim3(gBlk, 1), b256, 0, stream>>>(
        abuf, wt0, b_gcn0, bn_g0, bn_b0, bn_m0, bn_v0, hbuf, 128);
    agg128t_kernel<<<dim3(T_STEPS, N / 8), b256, 0, stream>>>(
        hbuf, rowptr, csr_src, coefA, selfw, abuf, N);
    mfma_gemm_kernel<128, 2, true><<<dim3(gBlk, 1), b256, 0, stream>>>(
        abuf, wt1, b_gcn1, bn_g1, bn_b1, bn_m1, bn_v1, hbuf, 128);
    agg128t_kernel<<<dim3(T_STEPS, N / 8), b256, 0, stream>>>(
        hbuf, rowptr, csr_src, coefA, selfw, abuf, N);
    mfma_gemm_kernel<128, 1, true><<<dim3(gBlk, 1), b256, 0, stream>>>(
        abuf, wt2, b_gcn2, nullptr, nullptr, nullptr, nullptr, hbuf, 128);

    // ---- LSTM: three per-layer fused kernels (weights in regs, h hi/lo handoff) ----
    const int gL = N / 16;             // 625
    lstm_layer_kernel<128, false, false><<<gL, b256, 0, stream>>>(
        hbuf, nullptr, wtih0, whh0b, b_ih_0, b_hh_0, pA_hi, pA_lo, nullptr, N);
    lstm_layer_kernel<64, true, false><<<gL, b256, 0, stream>>>(
        pA_hi, pA_lo, wtih1, whh1b, b_ih_1, b_hh_1, pB_hi, pB_lo, nullptr, N);
    lstm_layer_kernel<64, true, true><<<gL, b256, 0, stream>>>(
        pB_hi, pB_lo, wtih2, whh2b, b_ih_2, b_hh_2, nullptr, nullptr, (float*)d_out, N);
}

// Round 5
// 377.636 us; speedup vs baseline: 3.0979x; 1.1294x over previous
//
#include <hip/hip_runtime.h>
#include <hip/hip_bf16.h>
#include <math.h>

#define NTHREADS 256
#define T_STEPS 8
#define F_INC 32
#define H_DIM 128
#define O_DIM 64

typedef unsigned short u16;
typedef __attribute__((ext_vector_type(8))) short short8_t;
typedef __attribute__((ext_vector_type(4))) float float4_t;

__device__ __forceinline__ float bf2f(u16 u) {
    return __uint_as_float(((unsigned)u) << 16);
}
__device__ __forceinline__ u16 f2bf(float f) {
    __hip_bfloat16 h = __float2bfloat16(f);   // RNE
    union { __hip_bfloat16 h; u16 s; } cv; cv.h = h; return cv.s;
}
__device__ __forceinline__ float4 ld_bf4(const u16* p) {
    uint2 u = *(const uint2*)p;
    return make_float4(__uint_as_float(u.x << 16), __uint_as_float(u.x & 0xffff0000u),
                       __uint_as_float(u.y << 16), __uint_as_float(u.y & 0xffff0000u));
}
__device__ __forceinline__ void st_bf4(u16* p, float4 v) {
    ushort4 s = make_ushort4(f2bf(v.x), f2bf(v.y), f2bf(v.z), f2bf(v.w));
    *(ushort4*)p = s;
}
__device__ __forceinline__ void bf8_unpack(uint4 u, float* f) {
    f[0] = __uint_as_float(u.x << 16); f[1] = __uint_as_float(u.x & 0xffff0000u);
    f[2] = __uint_as_float(u.y << 16); f[3] = __uint_as_float(u.y & 0xffff0000u);
    f[4] = __uint_as_float(u.z << 16); f[5] = __uint_as_float(u.z & 0xffff0000u);
    f[6] = __uint_as_float(u.w << 16); f[7] = __uint_as_float(u.w & 0xffff0000u);
}
// fast sigmoid/tanh: v_exp_f32 + v_rcp_f32 (~1ulp each, << bf16 noise)
__device__ __forceinline__ float fsig(float x) {
    float xc = fminf(fmaxf(x, -30.f), 30.f);
    float e = __builtin_amdgcn_exp2f(xc * -1.4426950408889634f);   // e^{-x}
    return __builtin_amdgcn_rcpf(1.0f + e);
}
__device__ __forceinline__ float ftanh(float x) {
    float xc = fminf(fmaxf(x, -15.f), 15.f);
    float e = __builtin_amdgcn_exp2f(xc * -2.8853900817779268f);   // e^{-2x}
    float r = __builtin_amdgcn_rcpf(1.0f + e);
    return fmaf(-2.0f * e, r, 1.0f);                               // (1-e)/(1+e)
}

// ============================ CSR build ============================
__global__ void init_cnt_kernel(int* __restrict__ cnt, int n) {
    int i = blockIdx.x * NTHREADS + threadIdx.x;
    if (i < n) cnt[i] = 0;
}

__global__ void count_kernel(const int* __restrict__ ei, int* __restrict__ cnt, int E) {
    int e = blockIdx.x * NTHREADS + threadIdx.x;
    if (e < E) atomicAdd(&cnt[ei[E + e]], 1);   // dst row of edge_index
}

__global__ void scan_part1(const int* __restrict__ cnt, int* __restrict__ bsum, int n) {
    __shared__ int sd[NTHREADS];
    const int i = blockIdx.x * NTHREADS + threadIdx.x;
    sd[threadIdx.x] = (i < n) ? cnt[i] : 0;
    __syncthreads();
    for (int off = 128; off > 0; off >>= 1) {
        if (threadIdx.x < off) sd[threadIdx.x] += sd[threadIdx.x + off];
        __syncthreads();
    }
    if (threadIdx.x == 0) bsum[blockIdx.x] = sd[0];
}
__global__ void scan_part2(const int* __restrict__ bsum, int* __restrict__ boff, int nb) {
    if (threadIdx.x == 0) {
        int s = 0;
        for (int b = 0; b < nb; ++b) { boff[b] = s; s += bsum[b]; }
    }
}
// + fused dis/selfw computation
__global__ void scan_part3(const int* __restrict__ cnt, const int* __restrict__ boff,
                           int* __restrict__ rowptr, int* __restrict__ wp,
                           float* __restrict__ dis, float* __restrict__ selfw, int n) {
    __shared__ int sd[NTHREADS];
    const int i = blockIdx.x * NTHREADS + threadIdx.x;
    const int v = (i < n) ? cnt[i] : 0;
    sd[threadIdx.x] = v;
    __syncthreads();
    for (int off = 1; off < NTHREADS; off <<= 1) {
        const int tv = (threadIdx.x >= off) ? sd[threadIdx.x - off] : 0;
        __syncthreads();
        sd[threadIdx.x] += tv;
        __syncthreads();
    }
    const int excl = boff[blockIdx.x] + sd[threadIdx.x] - v;
    if (i < n) {
        rowptr[i] = excl; wp[i] = excl;
        if (i == n - 1) rowptr[n] = excl + v;
        const float d = 1.0f + (float)v;
        dis[i] = rsqrtf(d);
        selfw[i] = 1.0f / d;
    }
}

__global__ void fill_kernel(const int* __restrict__ ei, const float* __restrict__ dis,
                            int* __restrict__ wp, int* __restrict__ csr_src,
                            float* __restrict__ coefA, int E) {
    int e = blockIdx.x * NTHREADS + threadIdx.x;
    if (e < E) {
        int s = ei[e], d = ei[E + e];
        int p = atomicAdd(&wp[d], 1);
        csr_src[p] = s;
        coefA[p] = dis[s] * dis[d];
    }
}

// ============================ fused weight prep (one launch) ============================
__global__ void wprep_all_kernel(const float* g0, const float* g1, const float* g2,
                                 const float* i0, const float* i1, const float* i2,
                                 const float* h0, const float* h1, const float* h2,
                                 u16* o_g0, u16* o_g1, u16* o_g2,
                                 u16* o_i0, u16* o_i1, u16* o_i2,
                                 u16* o_h0, u16* o_h1, u16* o_h2) {
    const int i = blockIdx.x * NTHREADS + threadIdx.x;
    if (i < 4096)        { o_g0[i] = f2bf(g0[(i & 31) * 128 + (i >> 5)]); }
    else if (i < 20480)  { int j = i - 4096;   o_g1[j] = f2bf(g1[(j & 127) * 128 + (j >> 7)]); }
    else if (i < 36864)  { int j = i - 20480;  o_g2[j] = f2bf(g2[(j & 127) * 128 + (j >> 7)]); }
    else if (i < 69632)  { int j = i - 36864;  o_i0[j] = f2bf(i0[j]); }
    else if (i < 86016)  { int j = i - 69632;  o_i1[j] = f2bf(i1[j]); }
    else if (i < 102400) { int j = i - 86016;  o_i2[j] = f2bf(i2[j]); }
    else if (i < 118784) { int j = i - 102400; o_h0[j] = f2bf(h0[j]); }
    else if (i < 135168) { int j = i - 118784; o_h1[j] = f2bf(h1[j]); }
    else if (i < 151552) { int j = i - 135168; o_h2[j] = f2bf(h2[j]); }
}

// ============================ aggregation, t-major + XCD-pinned ============================
// Latency-chain fix: one full wave per node; lane-groups split the edge list
// (serial depth deg/splits), combined by __shfl_xor at the end. unroll 2 -> MLP.
// layer0: fp32 x [t][n][32]; 8 lanes x float4 cover 32 ch; 8 splits.
__global__ __launch_bounds__(NTHREADS)
void agg32t_kernel(const float* __restrict__ x, const int* __restrict__ rowptr,
                   const int* __restrict__ csrc, const float* __restrict__ coefA,
                   const float* __restrict__ selfw, u16* __restrict__ out, int N) {
    const int t = blockIdx.x;
    const int n = blockIdx.y * 4 + (threadIdx.x >> 6);
    const int lane = threadIdx.x & 63;
    const int split = lane >> 3;              // 0..7, edge stride 8
    const int c4 = (lane & 7) * 4;
    const float* xb = x + (long)t * N * 32;
    const int e0 = rowptr[n], e1 = rowptr[n + 1];
    float a[4] = {};
    #pragma unroll 2
    for (int e = e0 + split; e < e1; e += 8) {
        const float wgt = coefA[e];
        const int s = csrc[e];
        const float4 v = *(const float4*)(xb + (long)s * 32 + c4);
        a[0] = fmaf(wgt, v.x, a[0]);
        a[1] = fmaf(wgt, v.y, a[1]);
        a[2] = fmaf(wgt, v.z, a[2]);
        a[3] = fmaf(wgt, v.w, a[3]);
    }
    #pragma unroll
    for (int j = 0; j < 4; ++j) {
        a[j] += __shfl_xor(a[j], 8);
        a[j] += __shfl_xor(a[j], 16);
        a[j] += __shfl_xor(a[j], 32);
    }
    if (split == 0) {
        const float sw = selfw[n];
        const float4 sv = *(const float4*)(xb + (long)n * 32 + c4);
        float4 r = make_float4(fmaf(sw, sv.x, a[0]), fmaf(sw, sv.y, a[1]),
                               fmaf(sw, sv.z, a[2]), fmaf(sw, sv.w, a[3]));
        st_bf4(out + ((long)t * N + n) * 32 + c4, r);
    }
}

// 128-ch: bf16 h [t][n][128]; 16 lanes x uint4 (8 bf16) cover 128 ch; 4 splits.
__global__ __launch_bounds__(NTHREADS)
void agg128t_kernel(const u16* __restrict__ h, const int* __restrict__ rowptr,
                    const int* __restrict__ csrc, const float* __restrict__ coefA,
                    const float* __restrict__ selfw, u16* __restrict__ out, int N) {
    const int t = blockIdx.x;
    const int n = blockIdx.y * 4 + (threadIdx.x >> 6);
    const int lane = threadIdx.x & 63;
    const int split = lane >> 4;              // 0..3, edge stride 4
    const int c8 = (lane & 15) * 8;
    const u16* hb = h + (long)t * N * 128;
    const int e0 = rowptr[n], e1 = rowptr[n + 1];
    float a[8] = {};
    #pragma unroll 2
    for (int e = e0 + split; e < e1; e += 4) {
        const float wgt = coefA[e];
        const int s = csrc[e];
        const uint4 v = *(const uint4*)(hb + (long)s * 128 + c8);
        float f[8];
        bf8_unpack(v, f);
        #pragma unroll
        for (int j = 0; j < 8; ++j) a[j] = fmaf(wgt, f[j], a[j]);
    }
    #pragma unroll
    for (int j = 0; j < 8; ++j) {
        a[j] += __shfl_xor(a[j], 16);
        a[j] += __shfl_xor(a[j], 32);
    }
    if (split == 0) {
        const float sw = selfw[n];
        const uint4 sv = *(const uint4*)(hb + (long)n * 128 + c8);
        float f[8];
        bf8_unpack(sv, f);
        ushort4 o0, o1;
        o0.x = f2bf(fmaf(sw, f[0], a[0])); o0.y = f2bf(fmaf(sw, f[1], a[1]));
        o0.z = f2bf(fmaf(sw, f[2], a[2])); o0.w = f2bf(fmaf(sw, f[3], a[3]));
        o1.x = f2bf(fmaf(sw, f[4], a[4])); o1.y = f2bf(fmaf(sw, f[5], a[5]));
        o1.z = f2bf(fmaf(sw, f[6], a[6])); o1.w = f2bf(fmaf(sw, f[7], a[7]));
        u16* op = out + ((long)t * N + n) * 128 + c8;
        *(ushort4*)op = o0;
        *(ushort4*)(op + 4) = o1;
    }
}

// ============================ MFMA GEMM + fused epilogue ============================
// EPI: 1 = +bias0,ReLU, 2 = +bias0,ReLU,BN.
template<int K, int EPI, bool OUTBF>
__global__ __launch_bounds__(NTHREADS)
void mfma_gemm_kernel(const u16* __restrict__ A, const u16* __restrict__ Bt,
                      const float* __restrict__ bias0,
                      const float* __restrict__ bng, const float* __restrict__ bnb,
                      const float* __restrict__ bnm, const float* __restrict__ bnv,
                      void* __restrict__ Cout, int ldc) {
    constexpr int KC = (K < 64) ? K : 64;
    constexpr int KP = KC + 8;
    constexpr int KV = KC / 8;
    __shared__ __align__(16) u16 As[128 * KP];
    __shared__ __align__(16) u16 Bs[128 * KP];
    const int tid = threadIdx.x;
    const long row0 = (long)blockIdx.x * 128;
    const int col0 = blockIdx.y * 128;
    const int wid = tid >> 6, lane = tid & 63;
    const int quad = lane >> 4, l16 = lane & 15;

    float4_t acc[2][8];
    #pragma unroll
    for (int rt = 0; rt < 2; ++rt)
        #pragma unroll
        for (int ct = 0; ct < 8; ++ct)
            acc[rt][ct] = (float4_t){0.f, 0.f, 0.f, 0.f};

    const int arow = wid * 32 + l16;
    const int koff = quad * 8;
    for (int ch = 0; ch < K / KC; ++ch) {
        const int kbase = ch * KC;
        for (int p = tid; p < 128 * KV; p += NTHREADS) {
            const int r = p / KV, kv = p % KV;
            *(uint4*)(&As[r * KP + kv * 8]) =
                *(const uint4*)(A + (row0 + r) * K + kbase + kv * 8);
        }
        for (int p = tid; p < 128 * KV; p += NTHREADS) {
            const int r = p / KV, kv = p % KV;
            *(uint4*)(&Bs[r * KP + kv * 8]) =
                *(const uint4*)(Bt + (long)(col0 + r) * K + kbase + kv * 8);
        }
        __syncthreads();
        #pragma unroll
        for (int kc = 0; kc < KC / 32; ++kc) {
            const short8_t a0 = *(const short8_t*)(&As[arow * KP + kc * 32 + koff]);
            const short8_t a1 = *(const short8_t*)(&As[(arow + 16) * KP + kc * 32 + koff]);
            #pragma unroll
            for (int ct = 0; ct < 8; ++ct) {
                const short8_t b = *(const short8_t*)(&Bs[(ct * 16 + l16) * KP + kc * 32 + koff]);
                acc[0][ct] = __builtin_amdgcn_mfma_f32_16x16x32_bf16(a0, b, acc[0][ct], 0, 0, 0);
                acc[1][ct] = __builtin_amdgcn_mfma_f32_16x16x32_bf16(a1, b, acc[1][ct], 0, 0, 0);
            }
        }
        __syncthreads();
    }

    float e_add0[8], e_mul[8], e_add1[8];
    #pragma unroll
    for (int ct = 0; ct < 8; ++ct) {
        const int c = col0 + ct * 16 + l16;
        e_add0[ct] = bias0[c];
        if constexpr (EPI == 2) {
            const float s = bng[c] * rsqrtf(bnv[c] + 1e-5f);
            e_mul[ct] = s;
            e_add1[ct] = bnb[c] - bnm[c] * s;
        }
    }
    #pragma unroll
    for (int rt = 0; rt < 2; ++rt) {
        #pragma unroll
        for (int r = 0; r < 4; ++r) {
            const long row = row0 + wid * 32 + rt * 16 + quad * 4 + r;
            #pragma unroll
            for (int ct = 0; ct < 8; ++ct) {
                float v = fmaxf(acc[rt][ct][r] + e_add0[ct], 0.f);
                if constexpr (EPI == 2) v = fmaf(v, e_mul[ct], e_add1[ct]);
                const long idx = row * (long)ldc + col0 + ct * 16 + l16;
                if constexpr (OUTBF) ((u16*)Cout)[idx] = f2bf(v);
                else ((float*)Cout)[idx] = v;
            }
        }
    }
}

// ============================ per-layer fused LSTM ============================
template<int KIN, bool IN_SPLIT, bool LAST>
__global__ __launch_bounds__(NTHREADS, 2)
void lstm_layer_kernel(const u16* __restrict__ in_hi, const u16* __restrict__ in_lo,
                       const u16* __restrict__ wih, const u16* __restrict__ whh,
                       const float* __restrict__ bi, const float* __restrict__ bh,
                       u16* __restrict__ out_hi, u16* __restrict__ out_lo,
                       float* __restrict__ out_f, int N) {
    constexpr int NKS = KIN / 32;
    constexpr int HSTR = 76;
    const int tid = threadIdx.x;
    const int w = tid >> 6, lane = tid & 63;
    const int quad = lane >> 4, l16 = lane & 15;
    const int n0 = blockIdx.x * 16;
    const int u = w * 16 + l16;

    __shared__ __align__(16) u16 hT[2][16][HSTR];
    for (int p = tid; p < 2 * 16 * HSTR; p += NTHREADS) (&hT[0][0][0])[p] = 0;

    short8_t fI[4][NKS], fH[4][2];
    #pragma unroll
    for (int g = 0; g < 4; ++g) {
        #pragma unroll
        for (int ks = 0; ks < NKS; ++ks)
            fI[g][ks] = *(const short8_t*)(wih + (long)(g * 64 + u) * KIN + ks * 32 + quad * 8);
        #pragma unroll
        for (int ks = 0; ks < 2; ++ks)
            fH[g][ks] = *(const short8_t*)(whh + (long)(g * 64 + u) * 64 + ks * 32 + quad * 8);
    }
    float bias[4];
    #pragma unroll
    for (int g = 0; g < 4; ++g) bias[g] = bi[g * 64 + u] + bh[g * 64 + u];
    float cst[4] = {};
    __syncthreads();

    #pragma unroll 1
    for (int t = 0; t < T_STEPS; ++t) {
        short8_t ain[NKS], ainl[NKS];
        const long ibase = ((long)t * N + n0 + l16) * KIN + quad * 8;
        #pragma unroll
        for (int ks = 0; ks < NKS; ++ks) {
            ain[ks] = *(const short8_t*)(in_hi + ibase + ks * 32);
            if constexpr (IN_SPLIT) ainl[ks] = *(const short8_t*)(in_lo + ibase + ks * 32);
        }
        short8_t ah[2], al[2];
        #pragma unroll
        for (int ks = 0; ks < 2; ++ks) {
            ah[ks] = *(const short8_t*)(&hT[0][l16][ks * 32 + quad * 8]);
            al[ks] = *(const short8_t*)(&hT[1][l16][ks * 32 + quad * 8]);
        }
        __syncthreads();

        float4_t acc[4];
        #pragma unroll
        for (int g = 0; g < 4; ++g) acc[g] = (float4_t){bias[g], bias[g], bias[g], bias[g]};
        #pragma unroll
        for (int ks = 0; ks < NKS; ++ks)
            #pragma unroll
            for (int g = 0; g < 4; ++g) {
                acc[g] = __builtin_amdgcn_mfma_f32_16x16x32_bf16(ain[ks], fI[g][ks], acc[g], 0, 0, 0);
                if constexpr (IN_SPLIT)
                    acc[g] = __builtin_amdgcn_mfma_f32_16x16x32_bf16(ainl[ks], fI[g][ks], acc[g], 0, 0, 0);
            }
        #pragma unroll
        for (int ks = 0; ks < 2; ++ks)
            #pragma unroll
            for (int g = 0; g < 4; ++g) {
                acc[g] = __builtin_amdgcn_mfma_f32_16x16x32_bf16(ah[ks], fH[g][ks], acc[g], 0, 0, 0);
                acc[g] = __builtin_amdgcn_mfma_f32_16x16x32_bf16(al[ks], fH[g][ks], acc[g], 0, 0, 0);
            }

        #pragma unroll
        for (int r = 0; r < 4; ++r) {
            const float si = fsig(acc[0][r]);
            const float sf = fsig(acc[1][r]);
            const float gg = ftanh(acc[2][r]);
            const float so = fsig(acc[3][r]);
            const float c = sf * cst[r] + si * gg;
            cst[r] = c;
            const float h = so * ftanh(c);
            const int node = quad * 4 + r;
            const u16 hi = f2bf(h);
            const u16 lo = f2bf(h - bf2f(hi));
            hT[0][node][u] = hi;
            hT[1][node][u] = lo;
            if constexpr (LAST) {
                if (t == T_STEPS - 1) out_f[(long)(n0 + node) * 64 + u] = h;
            } else {
                const long o = ((long)t * N + n0 + node) * 64 + u;
                out_hi[o] = hi;
                out_lo[o] = lo;
            }
        }
        __syncthreads();
    }
}

// ============================ launch ============================
extern "C" void kernel_launch(void* const* d_in, const int* in_sizes, int n_in,
                              void* d_out, int out_size, void* d_ws, size_t ws_size,
                              hipStream_t stream) {
    (void)n_in; (void)out_size; (void)ws_size;
    const float* x      = (const float*)d_in[0];
    const int*   ei     = (const int*)d_in[1];
    const float* w_gcn0 = (const float*)d_in[2];
    const float* b_gcn0 = (const float*)d_in[3];
    const float* w_gcn1 = (const float*)d_in[4];
    const float* b_gcn1 = (const float*)d_in[5];
    const float* w_gcn2 = (const float*)d_in[6];
    const float* b_gcn2 = (const float*)d_in[7];
    const float* bn_g0  = (const float*)d_in[8];
    const float* bn_b0  = (const float*)d_in[9];
    const float* bn_m0  = (const float*)d_in[10];
    const float* bn_v0  = (const float*)d_in[11];
    const float* bn_g1  = (const float*)d_in[12];
    const float* bn_b1  = (const float*)d_in[13];
    const float* bn_m1  = (const float*)d_in[14];
    const float* bn_v1  = (const float*)d_in[15];
    const float* w_ih_0 = (const float*)d_in[16];
    const float* w_hh_0 = (const float*)d_in[17];
    const float* b_ih_0 = (const float*)d_in[18];
    const float* b_hh_0 = (const float*)d_in[19];
    const float* w_ih_1 = (const float*)d_in[20];
    const float* w_hh_1 = (const float*)d_in[21];
    const float* b_ih_1 = (const float*)d_in[22];
    const float* b_hh_1 = (const float*)d_in[23];
    const float* w_ih_2 = (const float*)d_in[24];
    const float* w_hh_2 = (const float*)d_in[25];
    const float* b_ih_2 = (const float*)d_in[26];
    const float* b_hh_2 = (const float*)d_in[27];

    const int E = in_sizes[1] / 2;
    const int N = in_sizes[0] / (T_STEPS * F_INC);     // 10000
    const long M = (long)N * T_STEPS;                  // 80000

    char* ws = (char*)d_ws;
    size_t off = 0;
    auto carve = [&](size_t bytes) -> void* {
        void* p = ws + off;
        off += (bytes + 255) & ~(size_t)255;
        return p;
    };
    float* dis     = (float*)carve((size_t)N * 4);
    float* selfw   = (float*)carve((size_t)N * 4);
    float* coefA   = (float*)carve((size_t)E * 4);
    int*   cnt     = (int*)carve((size_t)N * 4);
    int*   rowptr  = (int*)carve((size_t)(N + 1) * 4);
    int*   wp      = (int*)carve((size_t)N * 4);
    int*   csr_src = (int*)carve((size_t)E * 4);
    int*   bsum    = (int*)carve(64 * 4);
    int*   boff    = (int*)carve(64 * 4);
    u16*   hbuf    = (u16*)carve((size_t)M * H_DIM * 2);      // 20.5 MB, [t][n][128]
    u16*   abuf    = (u16*)carve((size_t)M * H_DIM * 2);      // 20.5 MB agg scratch
    u16*   pA_hi   = (u16*)carve((size_t)M * O_DIM * 2);
    u16*   pA_lo   = (u16*)carve((size_t)M * O_DIM * 2);
    u16*   pB_hi   = (u16*)carve((size_t)M * O_DIM * 2);
    u16*   pB_lo   = (u16*)carve((size_t)M * O_DIM * 2);
    u16*   wt0     = (u16*)carve((size_t)128 * 32 * 2);
    u16*   wt1     = (u16*)carve((size_t)128 * 128 * 2);
    u16*   wt2     = (u16*)carve((size_t)128 * 128 * 2);
    u16*   wtih0   = (u16*)carve((size_t)256 * 128 * 2);
    u16*   wtih1   = (u16*)carve((size_t)256 * 64 * 2);
    u16*   wtih2   = (u16*)carve((size_t)256 * 64 * 2);
    u16*   whh0b   = (u16*)carve((size_t)256 * 64 * 2);
    u16*   whh1b   = (u16*)carve((size_t)256 * 64 * 2);
    u16*   whh2b   = (u16*)carve((size_t)256 * 64 * 2);

    const dim3 b256(NTHREADS);
    const int gN = (N + NTHREADS - 1) / NTHREADS;      // 40
    const int gE = (E + NTHREADS - 1) / NTHREADS;

    // ---- CSR + normalization ----
    init_cnt_kernel<<<gN, b256, 0, stream>>>(cnt, N);
    count_kernel<<<gE, b256, 0, stream>>>(ei, cnt, E);
    scan_part1<<<gN, b256, 0, stream>>>(cnt, bsum, N);
    scan_part2<<<1, 64, 0, stream>>>(bsum, boff, gN);
    scan_part3<<<gN, b256, 0, stream>>>(cnt, boff, rowptr, wp, dis, selfw, N);
    fill_kernel<<<gE, b256, 0, stream>>>(ei, dis, wp, csr_src, coefA, E);

    // ---- weight prep ----
    wprep_all_kernel<<<(151552 + 255) / 256, b256, 0, stream>>>(
        w_gcn0, w_gcn1, w_gcn2, w_ih_0, w_ih_1, w_ih_2, w_hh_0, w_hh_1, w_hh_2,
        wt0, wt1, wt2, wtih0, wtih1, wtih2, whh0b, whh1b, whh2b);

    // ---- GCN: aggregate-first (t-major, XCD-pinned, wave-per-node agg) ----
    const int gBlk = (int)(M / 128);   // 625
    agg32t_kernel<<<dim3(T_STEPS, N / 4), b256, 0, stream>>>(
        x, rowptr, csr_src, coefA, selfw, abuf, N);
    mfma_gemm_kernel<32, 2, true><<<dim3(gBlk, 1), b256, 0, stream>>>(
        abuf, wt0, b_gcn0, bn_g0, bn_b0, bn_m0, bn_v0, hbuf, 128);
    agg128t_kernel<<<dim3(T_STEPS, N / 4), b256, 0, stream>>>(
        hbuf, rowptr, csr_src, coefA, selfw, abuf, N);
    mfma_gemm_kernel<128, 2, true><<<dim3(gBlk, 1), b256, 0, stream>>>(
        abuf, wt1, b_gcn1, bn_g1, bn_b1, bn_m1, bn_v1, hbuf, 128);
    agg128t_kernel<<<dim3(T_STEPS, N / 4), b256, 0, stream>>>(
        hbuf, rowptr, csr_src, coefA, selfw, abuf, N);
    mfma_gemm_kernel<128, 1, true><<<dim3(gBlk, 1), b256, 0, stream>>>(
        abuf, wt2, b_gcn2, nullptr, nullptr, nullptr, nullptr, hbuf, 128);

    // ---- LSTM: three per-layer fused kernels ----
    const int gL = N / 16;             // 625
    lstm_layer_kernel<128, false, false><<<gL, b256, 0, stream>>>(
        hbuf, nullptr, wtih0, whh0b, b_ih_0, b_hh_0, pA_hi, pA_lo, nullptr, N);
    lstm_layer_kernel<64, true, false><<<gL, b256, 0, stream>>>(
        pA_hi, pA_lo, wtih1, whh1b, b_ih_1, b_hh_1, pB_hi, pB_lo, nullptr, N);
    lstm_layer_kernel<64, true, true><<<gL, b256, 0, stream>>>(
        pB_hi, pB_lo, wtih2, whh2b, b_ih_2, b_hh_2, nullptr, nullptr, (float*)d_out, N);
}

// Round 6
// 370.395 us; speedup vs baseline: 3.1585x; 1.0195x over previous
//
#include <hip/hip_runtime.h>
#include <hip/hip_bf16.h>
#include <math.h>

#define NTHREADS 256
#define T_STEPS 8
#define F_INC 32
#define H_DIM 128
#define O_DIM 64

typedef unsigned short u16;
typedef __attribute__((ext_vector_type(8))) short short8_t;
typedef __attribute__((ext_vector_type(4))) float float4_t;

__device__ __forceinline__ float bf2f(u16 u) {
    return __uint_as_float(((unsigned)u) << 16);
}
__device__ __forceinline__ u16 f2bf(float f) {
    __hip_bfloat16 h = __float2bfloat16(f);   // RNE
    union { __hip_bfloat16 h; u16 s; } cv; cv.h = h; return cv.s;
}
__device__ __forceinline__ void bf8_unpack(uint4 u, float* f) {
    f[0] = __uint_as_float(u.x << 16); f[1] = __uint_as_float(u.x & 0xffff0000u);
    f[2] = __uint_as_float(u.y << 16); f[3] = __uint_as_float(u.y & 0xffff0000u);
    f[4] = __uint_as_float(u.z << 16); f[5] = __uint_as_float(u.z & 0xffff0000u);
    f[6] = __uint_as_float(u.w << 16); f[7] = __uint_as_float(u.w & 0xffff0000u);
}
// fast sigmoid/tanh via v_exp_f32 (~1ulp, << bf16 noise)
__device__ __forceinline__ float fsig(float x) {
    float xc = fminf(fmaxf(x, -30.f), 30.f);
    float e = __builtin_amdgcn_exp2f(xc * -1.4426950408889634f);
    return __builtin_amdgcn_rcpf(1.0f + e);
}
__device__ __forceinline__ float ftanh(float x) {
    float xc = fminf(fmaxf(x, -15.f), 15.f);
    float e = __builtin_amdgcn_exp2f(xc * -2.8853900817779268f);
    float r = __builtin_amdgcn_rcpf(1.0f + e);
    return fmaf(-2.0f * e, r, 1.0f);
}

// ============================ CSR build ============================
__global__ void count_kernel(const int* __restrict__ ei, int* __restrict__ cnt, int E) {
    int e = blockIdx.x * NTHREADS + threadIdx.x;
    if (e < E) atomicAdd(&cnt[ei[E + e]], 1);   // dst row of edge_index
}

__global__ void scan_part1(const int* __restrict__ cnt, int* __restrict__ bsum, int n) {
    __shared__ int sd[NTHREADS];
    const int i = blockIdx.x * NTHREADS + threadIdx.x;
    sd[threadIdx.x] = (i < n) ? cnt[i] : 0;
    __syncthreads();
    for (int off = 128; off > 0; off >>= 1) {
        if (threadIdx.x < off) sd[threadIdx.x] += sd[threadIdx.x + off];
        __syncthreads();
    }
    if (threadIdx.x == 0) bsum[blockIdx.x] = sd[0];
}

// inlined block-offset (wave shuffle over bsum) + scan + dis/selfw
__global__ void scan_part3(const int* __restrict__ cnt, const int* __restrict__ bsum,
                           int* __restrict__ rowptr, int* __restrict__ wp,
                           float* __restrict__ dis, float* __restrict__ selfw, int n) {
    __shared__ int sd[NTHREADS];
    __shared__ int sbase;
    const int tid = threadIdx.x;
    if (tid < 64) {
        int v0 = (tid < blockIdx.x) ? bsum[tid] : 0;   // nb <= 64
        #pragma unroll
        for (int off = 1; off < 64; off <<= 1) v0 += __shfl_xor(v0, off);
        if (tid == 0) sbase = v0;
    }
    const int i = blockIdx.x * NTHREADS + tid;
    const int v = (i < n) ? cnt[i] : 0;
    sd[tid] = v;
    __syncthreads();
    for (int off = 1; off < NTHREADS; off <<= 1) {
        const int tv = (tid >= off) ? sd[tid - off] : 0;
        __syncthreads();
        sd[tid] += tv;
        __syncthreads();
    }
    const int excl = sbase + sd[tid] - v;
    if (i < n) {
        rowptr[i] = excl; wp[i] = excl;
        if (i == n - 1) rowptr[n] = excl + v;
        const float d = 1.0f + (float)v;
        dis[i] = rsqrtf(d);
        selfw[i] = 1.0f / d;
    }
}

__global__ void fill_kernel(const int* __restrict__ ei, const float* __restrict__ dis,
                            int* __restrict__ wp, int* __restrict__ csr_src,
                            float* __restrict__ coefA, int E) {
    int e = blockIdx.x * NTHREADS + threadIdx.x;
    if (e < E) {
        int s = ei[e], d = ei[E + e];
        int p = atomicAdd(&wp[d], 1);
        csr_src[p] = s;
        coefA[p] = dis[s] * dis[d];
    }
}

// ============================ fused weight prep (one launch) ============================
__global__ void wprep_all_kernel(const float* g0, const float* g1, const float* g2,
                                 const float* i0, const float* i1, const float* i2,
                                 const float* h0, const float* h1, const float* h2,
                                 u16* o_g0, u16* o_g1, u16* o_g2,
                                 u16* o_i0, u16* o_i1, u16* o_i2,
                                 u16* o_h0, u16* o_h1, u16* o_h2) {
    const int i = blockIdx.x * NTHREADS + threadIdx.x;
    if (i < 4096)        { o_g0[i] = f2bf(g0[(i & 31) * 128 + (i >> 5)]); }
    else if (i < 20480)  { int j = i - 4096;   o_g1[j] = f2bf(g1[(j & 127) * 128 + (j >> 7)]); }
    else if (i < 36864)  { int j = i - 20480;  o_g2[j] = f2bf(g2[(j & 127) * 128 + (j >> 7)]); }
    else if (i < 69632)  { int j = i - 36864;  o_i0[j] = f2bf(i0[j]); }
    else if (i < 86016)  { int j = i - 69632;  o_i1[j] = f2bf(i1[j]); }
    else if (i < 102400) { int j = i - 86016;  o_i2[j] = f2bf(i2[j]); }
    else if (i < 118784) { int j = i - 102400; o_h0[j] = f2bf(h0[j]); }
    else if (i < 135168) { int j = i - 118784; o_h1[j] = f2bf(h1[j]); }
    else if (i < 151552) { int j = i - 135168; o_h2[j] = f2bf(h2[j]); }
}

// ============================ fused GCN layer 0: agg(x fp32) + W0 GEMM + BN ============================
// Block = 16 nodes x 1 t. Phase A: wave-per-node aggregation (8 splits x 8 lanes x 4ch)
// into LDS bf16 tile. Phase B: 16x128 GEMM vs W0t [128col][32k] with register B-frags.
__global__ __launch_bounds__(NTHREADS)
void gcn32_kernel(const float* __restrict__ x, const int* __restrict__ rowptr,
                  const int* __restrict__ csrc, const float* __restrict__ coefA,
                  const float* __restrict__ selfw, const u16* __restrict__ Wt,
                  const float* __restrict__ bias,
                  const float* __restrict__ bng, const float* __restrict__ bnb,
                  const float* __restrict__ bnm, const float* __restrict__ bnv,
                  u16* __restrict__ out, int N) {
    constexpr int ASTR = 40;                      // u16 stride: 20 dwords -> 2-way banks (free)
    __shared__ __align__(16) u16 aT[16][ASTR];
    const int t = blockIdx.x;
    const int n0 = blockIdx.y * 16;
    const int tid = threadIdx.x;
    const int wid = tid >> 6, lane = tid & 63;
    const int quad = lane >> 4, l16 = lane & 15;
    const float* xb = x + (long)t * N * 32;

    // ---- phase A: aggregate 4 nodes per wave ----
    const int split = lane >> 3;                  // 0..7
    const int c4 = (lane & 7) * 4;
    for (int i = 0; i < 4; ++i) {
        const int n = n0 + wid * 4 + i;
        const int e0 = rowptr[n], e1 = rowptr[n + 1];
        float a[4] = {};
        #pragma unroll 2
        for (int e = e0 + split; e < e1; e += 8) {
            const float wgt = coefA[e];
            const int s = csrc[e];
            const float4 v = *(const float4*)(xb + (long)s * 32 + c4);
            a[0] = fmaf(wgt, v.x, a[0]);
            a[1] = fmaf(wgt, v.y, a[1]);
            a[2] = fmaf(wgt, v.z, a[2]);
            a[3] = fmaf(wgt, v.w, a[3]);
        }
        #pragma unroll
        for (int j = 0; j < 4; ++j) {
            a[j] += __shfl_xor(a[j], 8);
            a[j] += __shfl_xor(a[j], 16);
            a[j] += __shfl_xor(a[j], 32);
        }
        if (split == 0) {
            const float sw = selfw[n];
            const float4 sv = *(const float4*)(xb + (long)n * 32 + c4);
            ushort4 o;
            o.x = f2bf(fmaf(sw, sv.x, a[0]));
            o.y = f2bf(fmaf(sw, sv.y, a[1]));
            o.z = f2bf(fmaf(sw, sv.z, a[2]));
            o.w = f2bf(fmaf(sw, sv.w, a[3]));
            *(ushort4*)(&aT[wid * 4 + i][c4]) = o;
        }
    }
    __syncthreads();

    // ---- phase B: [16 nodes] x [32k] @ Wt^T -> [16][128], wave owns 32 cols ----
    const short8_t fA = *(const short8_t*)(&aT[l16][quad * 8]);
    float4_t acc[2];
    short8_t fB[2];
    #pragma unroll
    for (int ct = 0; ct < 2; ++ct) {
        const int col = wid * 32 + ct * 16 + l16;
        fB[ct] = *(const short8_t*)(Wt + (long)col * 32 + quad * 8);
        acc[ct] = (float4_t){0.f, 0.f, 0.f, 0.f};
    }
    #pragma unroll
    for (int ct = 0; ct < 2; ++ct)
        acc[ct] = __builtin_amdgcn_mfma_f32_16x16x32_bf16(fA, fB[ct], acc[ct], 0, 0, 0);

    #pragma unroll
    for (int ct = 0; ct < 2; ++ct) {
        const int c = wid * 32 + ct * 16 + l16;
        const float s = bng[c] * rsqrtf(bnv[c] + 1e-5f);
        const float a1 = bnb[c] - bnm[c] * s;
        const float a0 = bias[c];
        #pragma unroll
        for (int r = 0; r < 4; ++r) {
            const int node = quad * 4 + r;
            float v = fmaf(fmaxf(acc[ct][r] + a0, 0.f), s, a1);
            out[((long)t * N + n0 + node) * 128 + c] = f2bf(v);
        }
    }
}

// ============================ fused GCN layers 1/2: agg(h bf16) + W GEMM + epi ============================
// EPI: 1 = bias,ReLU ; 2 = bias,ReLU,BN.  Wt is [128col][128k] bf16.
template<int EPI>
__global__ __launch_bounds__(NTHREADS)
void gcn128_kernel(const u16* __restrict__ h, const int* __restrict__ rowptr,
                   const int* __restrict__ csrc, const float* __restrict__ coefA,
                   const float* __restrict__ selfw, const u16* __restrict__ Wt,
                   const float* __restrict__ bias,
                   const float* __restrict__ bng, const float* __restrict__ bnb,
                   const float* __restrict__ bnm, const float* __restrict__ bnv,
                   u16* __restrict__ out, int N) {
    constexpr int ASTR = 136;                     // u16 stride: 68 dwords -> 2-way banks (free)
    __shared__ __align__(16) u16 aT[16][ASTR];
    const int t = blockIdx.x;
    const int n0 = blockIdx.y * 16;
    const int tid = threadIdx.x;
    const int wid = tid >> 6, lane = tid & 63;
    const int quad = lane >> 4, l16 = lane & 15;
    const u16* hb = h + (long)t * N * 128;

    // ---- phase A: aggregate 4 nodes per wave (4 splits x 16 lanes x 8ch) ----
    const int split = lane >> 4;                  // 0..3
    const int c8 = l16 * 8;
    for (int i = 0; i < 4; ++i) {
        const int n = n0 + wid * 4 + i;
        const int e0 = rowptr[n], e1 = rowptr[n + 1];
        float a[8] = {};
        #pragma unroll 2
        for (int e = e0 + split; e < e1; e += 4) {
            const float wgt = coefA[e];
            const int s = csrc[e];
            const uint4 v = *(const uint4*)(hb + (long)s * 128 + c8);
            float f[8];
            bf8_unpack(v, f);
            #pragma unroll
            for (int j = 0; j < 8; ++j) a[j] = fmaf(wgt, f[j], a[j]);
        }
        #pragma unroll
        for (int j = 0; j < 8; ++j) {
            a[j] += __shfl_xor(a[j], 16);
            a[j] += __shfl_xor(a[j], 32);
        }
        if (split == 0) {
            const float sw = selfw[n];
            const uint4 sv = *(const uint4*)(hb + (long)n * 128 + c8);
            float f[8];
            bf8_unpack(sv, f);
            ushort4 o0, o1;
            o0.x = f2bf(fmaf(sw, f[0], a[0])); o0.y = f2bf(fmaf(sw, f[1], a[1]));
            o0.z = f2bf(fmaf(sw, f[2], a[2])); o0.w = f2bf(fmaf(sw, f[3], a[3]));
            o1.x = f2bf(fmaf(sw, f[4], a[4])); o1.y = f2bf(fmaf(sw, f[5], a[5]));
            o1.z = f2bf(fmaf(sw, f[6], a[6])); o1.w = f2bf(fmaf(sw, f[7], a[7]));
            *(ushort4*)(&aT[wid * 4 + i][c8]) = o0;
            *(ushort4*)(&aT[wid * 4 + i][c8 + 4]) = o1;
        }
    }
    __syncthreads();

    // ---- phase B: [16][128] @ Wt^T -> [16][128]; wave owns 32 cols, K=128 ----
    short8_t fA[4];
    #pragma unroll
    for (int ks = 0; ks < 4; ++ks)
        fA[ks] = *(const short8_t*)(&aT[l16][ks * 32 + quad * 8]);
    float4_t acc[2];
    #pragma unroll
    for (int ct = 0; ct < 2; ++ct) acc[ct] = (float4_t){0.f, 0.f, 0.f, 0.f};
    #pragma unroll
    for (int ct = 0; ct < 2; ++ct) {
        const int col = wid * 32 + ct * 16 + l16;
        #pragma unroll
        for (int ks = 0; ks < 4; ++ks) {
            const short8_t fB = *(const short8_t*)(Wt + (long)col * 128 + ks * 32 + quad * 8);
            acc[ct] = __builtin_amdgcn_mfma_f32_16x16x32_bf16(fA[ks], fB, acc[ct], 0, 0, 0);
        }
    }

    #pragma unroll
    for (int ct = 0; ct < 2; ++ct) {
        const int c = wid * 32 + ct * 16 + l16;
        const float a0 = bias[c];
        float s = 0.f, a1 = 0.f;
        if constexpr (EPI == 2) {
            s = bng[c] * rsqrtf(bnv[c] + 1e-5f);
            a1 = bnb[c] - bnm[c] * s;
        }
        #pragma unroll
        for (int r = 0; r < 4; ++r) {
            const int node = quad * 4 + r;
            float v = fmaxf(acc[ct][r] + a0, 0.f);
            if constexpr (EPI == 2) v = fmaf(v, s, a1);
            out[((long)t * N + n0 + node) * 128 + c] = f2bf(v);
        }
    }
}

// ============================ per-layer fused LSTM ============================
template<int KIN, bool IN_SPLIT, bool LAST>
__global__ __launch_bounds__(NTHREADS, 2)
void lstm_layer_kernel(const u16* __restrict__ in_hi, const u16* __restrict__ in_lo,
                       const u16* __restrict__ wih, const u16* __restrict__ whh,
                       const float* __restrict__ bi, const float* __restrict__ bh,
                       u16* __restrict__ out_hi, u16* __restrict__ out_lo,
                       float* __restrict__ out_f, int N) {
    constexpr int NKS = KIN / 32;
    constexpr int HSTR = 76;
    const int tid = threadIdx.x;
    const int w = tid >> 6, lane = tid & 63;
    const int quad = lane >> 4, l16 = lane & 15;
    const int n0 = blockIdx.x * 16;
    const int u = w * 16 + l16;

    __shared__ __align__(16) u16 hT[2][16][HSTR];
    for (int p = tid; p < 2 * 16 * HSTR; p += NTHREADS) (&hT[0][0][0])[p] = 0;

    short8_t fI[4][NKS], fH[4][2];
    #pragma unroll
    for (int g = 0; g < 4; ++g) {
        #pragma unroll
        for (int ks = 0; ks < NKS; ++ks)
            fI[g][ks] = *(const short8_t*)(wih + (long)(g * 64 + u) * KIN + ks * 32 + quad * 8);
        #pragma unroll
        for (int ks = 0; ks < 2; ++ks)
            fH[g][ks] = *(const short8_t*)(whh + (long)(g * 64 + u) * 64 + ks * 32 + quad * 8);
    }
    float bias[4];
    #pragma unroll
    for (int g = 0; g < 4; ++g) bias[g] = bi[g * 64 + u] + bh[g * 64 + u];
    float cst[4] = {};
    __syncthreads();

    #pragma unroll 1
    for (int t = 0; t < T_STEPS; ++t) {
        short8_t ain[NKS], ainl[NKS];
        const long ibase = ((long)t * N + n0 + l16) * KIN + quad * 8;
        #pragma unroll
        for (int ks = 0; ks < NKS; ++ks) {
            ain[ks] = *(const short8_t*)(in_hi + ibase + ks * 32);
            if constexpr (IN_SPLIT) ainl[ks] = *(const short8_t*)(in_lo + ibase + ks * 32);
        }
        short8_t ah[2], al[2];
        #pragma unroll
        for (int ks = 0; ks < 2; ++ks) {
            ah[ks] = *(const short8_t*)(&hT[0][l16][ks * 32 + quad * 8]);
            al[ks] = *(const short8_t*)(&hT[1][l16][ks * 32 + quad * 8]);
        }
        __syncthreads();

        float4_t acc[4];
        #pragma unroll
        for (int g = 0; g < 4; ++g) acc[g] = (float4_t){bias[g], bias[g], bias[g], bias[g]};
        #pragma unroll
        for (int ks = 0; ks < NKS; ++ks)
            #pragma unroll
            for (int g = 0; g < 4; ++g) {
                acc[g] = __builtin_amdgcn_mfma_f32_16x16x32_bf16(ain[ks], fI[g][ks], acc[g], 0, 0, 0);
                if constexpr (IN_SPLIT)
                    acc[g] = __builtin_amdgcn_mfma_f32_16x16x32_bf16(ainl[ks], fI[g][ks], acc[g], 0, 0, 0);
            }
        #pragma unroll
        for (int ks = 0; ks < 2; ++ks)
            #pragma unroll
            for (int g = 0; g < 4; ++g) {
                acc[g] = __builtin_amdgcn_mfma_f32_16x16x32_bf16(ah[ks], fH[g][ks], acc[g], 0, 0, 0);
                acc[g] = __builtin_amdgcn_mfma_f32_16x16x32_bf16(al[ks], fH[g][ks], acc[g], 0, 0, 0);
            }

        #pragma unroll
        for (int r = 0; r < 4; ++r) {
            const float si = fsig(acc[0][r]);
            const float sf = fsig(acc[1][r]);
            const float gg = ftanh(acc[2][r]);
            const float so = fsig(acc[3][r]);
            const float c = sf * cst[r] + si * gg;
            cst[r] = c;
            const float h = so * ftanh(c);
            const int node = quad * 4 + r;
            const u16 hi = f2bf(h);
            const u16 lo = f2bf(h - bf2f(hi));
            hT[0][node][u] = hi;
            hT[1][node][u] = lo;
            if constexpr (LAST) {
                if (t == T_STEPS - 1) out_f[(long)(n0 + node) * 64 + u] = h;
            } else {
                const long o = ((long)t * N + n0 + node) * 64 + u;
                out_hi[o] = hi;
                out_lo[o] = lo;
            }
        }
        __syncthreads();
    }
}

// ============================ launch ============================
extern "C" void kernel_launch(void* const* d_in, const int* in_sizes, int n_in,
                              void* d_out, int out_size, void* d_ws, size_t ws_size,
                              hipStream_t stream) {
    (void)n_in; (void)out_size; (void)ws_size;
    const float* x      = (const float*)d_in[0];
    const int*   ei     = (const int*)d_in[1];
    const float* w_gcn0 = (const float*)d_in[2];
    const float* b_gcn0 = (const float*)d_in[3];
    const float* w_gcn1 = (const float*)d_in[4];
    const float* b_gcn1 = (const float*)d_in[5];
    const float* w_gcn2 = (const float*)d_in[6];
    const float* b_gcn2 = (const float*)d_in[7];
    const float* bn_g0  = (const float*)d_in[8];
    const float* bn_b0  = (const float*)d_in[9];
    const float* bn_m0  = (const float*)d_in[10];
    const float* bn_v0  = (const float*)d_in[11];
    const float* bn_g1  = (const float*)d_in[12];
    const float* bn_b1  = (const float*)d_in[13];
    const float* bn_m1  = (const float*)d_in[14];
    const float* bn_v1  = (const float*)d_in[15];
    const float* w_ih_0 = (const float*)d_in[16];
    const float* w_hh_0 = (const float*)d_in[17];
    const float* b_ih_0 = (const float*)d_in[18];
    const float* b_hh_0 = (const float*)d_in[19];
    const float* w_ih_1 = (const float*)d_in[20];
    const float* w_hh_1 = (const float*)d_in[21];
    const float* b_ih_1 = (const float*)d_in[22];
    const float* b_hh_1 = (const float*)d_in[23];
    const float* w_ih_2 = (const float*)d_in[24];
    const float* w_hh_2 = (const float*)d_in[25];
    const float* b_ih_2 = (const float*)d_in[26];
    const float* b_hh_2 = (const float*)d_in[27];

    const int E = in_sizes[1] / 2;
    const int N = in_sizes[0] / (T_STEPS * F_INC);     // 10000
    const long M = (long)N * T_STEPS;                  // 80000

    char* ws = (char*)d_ws;
    size_t off = 0;
    auto carve = [&](size_t bytes) -> void* {
        void* p = ws + off;
        off += (bytes + 255) & ~(size_t)255;
        return p;
    };
    float* dis     = (float*)carve((size_t)N * 4);
    float* selfw   = (float*)carve((size_t)N * 4);
    float* coefA   = (float*)carve((size_t)E * 4);
    int*   cnt     = (int*)carve((size_t)N * 4);
    int*   rowptr  = (int*)carve((size_t)(N + 1) * 4);
    int*   wp      = (int*)carve((size_t)N * 4);
    int*   csr_src = (int*)carve((size_t)E * 4);
    int*   bsum    = (int*)carve(64 * 4);
    u16*   hbuf    = (u16*)carve((size_t)M * H_DIM * 2);      // 20.5 MB, [t][n][128]
    u16*   hbuf2   = (u16*)carve((size_t)M * H_DIM * 2);      // 20.5 MB ping-pong
    u16*   pA_hi   = (u16*)carve((size_t)M * O_DIM * 2);
    u16*   pA_lo   = (u16*)carve((size_t)M * O_DIM * 2);
    u16*   pB_hi   = (u16*)carve((size_t)M * O_DIM * 2);
    u16*   pB_lo   = (u16*)carve((size_t)M * O_DIM * 2);
    u16*   wt0     = (u16*)carve((size_t)128 * 32 * 2);
    u16*   wt1     = (u16*)carve((size_t)128 * 128 * 2);
    u16*   wt2     = (u16*)carve((size_t)128 * 128 * 2);
    u16*   wtih0   = (u16*)carve((size_t)256 * 128 * 2);
    u16*   wtih1   = (u16*)carve((size_t)256 * 64 * 2);
    u16*   wtih2   = (u16*)carve((size_t)256 * 64 * 2);
    u16*   whh0b   = (u16*)carve((size_t)256 * 64 * 2);
    u16*   whh1b   = (u16*)carve((size_t)256 * 64 * 2);
    u16*   whh2b   = (u16*)carve((size_t)256 * 64 * 2);

    const dim3 b256(NTHREADS);
    const int gN = (N + NTHREADS - 1) / NTHREADS;      // 40
    const int gE = (E + NTHREADS - 1) / NTHREADS;

    // ---- CSR + normalization (4 kernels + 1 async memset) ----
    hipMemsetAsync(cnt, 0, (size_t)N * 4, stream);
    count_kernel<<<gE, b256, 0, stream>>>(ei, cnt, E);
    scan_part1<<<gN, b256, 0, stream>>>(cnt, bsum, N);
    scan_part3<<<gN, b256, 0, stream>>>(cnt, bsum, rowptr, wp, dis, selfw, N);
    fill_kernel<<<gE, b256, 0, stream>>>(ei, dis, wp, csr_src, coefA, E);

    // ---- weight prep ----
    wprep_all_kernel<<<(151552 + 255) / 256, b256, 0, stream>>>(
        w_gcn0, w_gcn1, w_gcn2, w_ih_0, w_ih_1, w_ih_2, w_hh_0, w_hh_1, w_hh_2,
        wt0, wt1, wt2, wtih0, wtih1, wtih2, whh0b, whh1b, whh2b);

    // ---- GCN: fused agg+GEMM per layer (t-major, XCD-pinned) ----
    const dim3 gG(T_STEPS, N / 16);                     // (8, 625)
    gcn32_kernel<<<gG, b256, 0, stream>>>(
        x, rowptr, csr_src, coefA, selfw, wt0, b_gcn0,
        bn_g0, bn_b0, bn_m0, bn_v0, hbuf, N);
    gcn128_kernel<2><<<gG, b256, 0, stream>>>(
        hbuf, rowptr, csr_src, coefA, selfw, wt1, b_gcn1,
        bn_g1, bn_b1, bn_m1, bn_v1, hbuf2, N);
    gcn128_kernel<1><<<gG, b256, 0, stream>>>(
        hbuf2, rowptr, csr_src, coefA, selfw, wt2, b_gcn2,
        nullptr, nullptr, nullptr, nullptr, hbuf, N);

    // ---- LSTM: three per-layer fused kernels ----
    const int gL = N / 16;             // 625
    lstm_layer_kernel<128, false, false><<<gL, b256, 0, stream>>>(
        hbuf, nullptr, wtih0, whh0b, b_ih_0, b_hh_0, pA_hi, pA_lo, nullptr, N);
    lstm_layer_kernel<64, true, false><<<gL, b256, 0, stream>>>(
        pA_hi, pA_lo, wtih1, whh1b, b_ih_1, b_hh_1, pB_hi, pB_lo, nullptr, N);
    lstm_layer_kernel<64, true, true><<<gL, b256, 0, stream>>>(
        pB_hi, pB_lo, wtih2, whh2b, b_ih_2, b_hh_2, nullptr, nullptr, (float*)d_out, N);
}

// Round 7
// 361.032 us; speedup vs baseline: 3.2404x; 1.0259x over previous
//
#include <hip/hip_runtime.h>
#include <hip/hip_bf16.h>
#include <math.h>

#define NTHREADS 256
#define T_STEPS 8
#define F_INC 32
#define H_DIM 128
#define O_DIM 64

typedef unsigned short u16;
typedef __attribute__((ext_vector_type(8))) short short8_t;
typedef __attribute__((ext_vector_type(4))) float float4_t;

__device__ __forceinline__ float bf2f(u16 u) {
    return __uint_as_float(((unsigned)u) << 16);
}
__device__ __forceinline__ u16 f2bf(float f) {
    __hip_bfloat16 h = __float2bfloat16(f);   // RNE
    union { __hip_bfloat16 h; u16 s; } cv; cv.h = h; return cv.s;
}
__device__ __forceinline__ void bf8_unpack(uint4 u, float* f) {
    f[0] = __uint_as_float(u.x << 16); f[1] = __uint_as_float(u.x & 0xffff0000u);
    f[2] = __uint_as_float(u.y << 16); f[3] = __uint_as_float(u.y & 0xffff0000u);
    f[4] = __uint_as_float(u.z << 16); f[5] = __uint_as_float(u.z & 0xffff0000u);
    f[6] = __uint_as_float(u.w << 16); f[7] = __uint_as_float(u.w & 0xffff0000u);
}
// fast sigmoid/tanh via v_exp_f32 (~1ulp, << bf16 noise)
__device__ __forceinline__ float fsig(float x) {
    float xc = fminf(fmaxf(x, -30.f), 30.f);
    float e = __builtin_amdgcn_exp2f(xc * -1.4426950408889634f);
    return __builtin_amdgcn_rcpf(1.0f + e);
}
__device__ __forceinline__ float ftanh(float x) {
    float xc = fminf(fmaxf(x, -15.f), 15.f);
    float e = __builtin_amdgcn_exp2f(xc * -2.8853900817779268f);
    float r = __builtin_amdgcn_rcpf(1.0f + e);
    return fmaf(-2.0f * e, r, 1.0f);
}

// ============================ CSR build ============================
__global__ void count_kernel(const int* __restrict__ ei, int* __restrict__ cnt, int E) {
    int e = blockIdx.x * NTHREADS + threadIdx.x;
    if (e < E) atomicAdd(&cnt[ei[E + e]], 1);   // dst row of edge_index
}

__global__ void scan_part1(const int* __restrict__ cnt, int* __restrict__ bsum, int n) {
    __shared__ int sd[NTHREADS];
    const int i = blockIdx.x * NTHREADS + threadIdx.x;
    sd[threadIdx.x] = (i < n) ? cnt[i] : 0;
    __syncthreads();
    for (int off = 128; off > 0; off >>= 1) {
        if (threadIdx.x < off) sd[threadIdx.x] += sd[threadIdx.x + off];
        __syncthreads();
    }
    if (threadIdx.x == 0) bsum[blockIdx.x] = sd[0];
}

// inlined block-offset (wave shuffle over bsum) + scan + dis/selfw
__global__ void scan_part3(const int* __restrict__ cnt, const int* __restrict__ bsum,
                           int* __restrict__ rowptr, int* __restrict__ wp,
                           float* __restrict__ dis, float* __restrict__ selfw, int n) {
    __shared__ int sd[NTHREADS];
    __shared__ int sbase;
    const int tid = threadIdx.x;
    if (tid < 64) {
        int v0 = (tid < blockIdx.x) ? bsum[tid] : 0;   // nb <= 64
        #pragma unroll
        for (int off = 1; off < 64; off <<= 1) v0 += __shfl_xor(v0, off);
        if (tid == 0) sbase = v0;
    }
    const int i = blockIdx.x * NTHREADS + tid;
    const int v = (i < n) ? cnt[i] : 0;
    sd[tid] = v;
    __syncthreads();
    for (int off = 1; off < NTHREADS; off <<= 1) {
        const int tv = (tid >= off) ? sd[tid - off] : 0;
        __syncthreads();
        sd[tid] += tv;
        __syncthreads();
    }
    const int excl = sbase + sd[tid] - v;
    if (i < n) {
        rowptr[i] = excl; wp[i] = excl;
        if (i == n - 1) rowptr[n] = excl + v;
        const float d = 1.0f + (float)v;
        dis[i] = rsqrtf(d);
        selfw[i] = 1.0f / d;
    }
}

// packed edge metadata: epk[p] = (src, coef) -> one 8B load per edge
__global__ void fill_kernel(const int* __restrict__ ei, const float* __restrict__ dis,
                            int* __restrict__ wp, int2* __restrict__ epk, int E) {
    int e = blockIdx.x * NTHREADS + threadIdx.x;
    if (e < E) {
        int s = ei[e], d = ei[E + e];
        int p = atomicAdd(&wp[d], 1);
        epk[p] = make_int2(s, __float_as_int(dis[s] * dis[d]));
    }
}

// ============================ fused weight prep (one launch) ============================
__global__ void wprep_all_kernel(const float* g0, const float* g1, const float* g2,
                                 const float* i0, const float* i1, const float* i2,
                                 const float* h0, const float* h1, const float* h2,
                                 u16* o_g0, u16* o_g1, u16* o_g2,
                                 u16* o_i0, u16* o_i1, u16* o_i2,
                                 u16* o_h0, u16* o_h1, u16* o_h2) {
    const int i = blockIdx.x * NTHREADS + threadIdx.x;
    if (i < 4096)        { o_g0[i] = f2bf(g0[(i & 31) * 128 + (i >> 5)]); }
    else if (i < 20480)  { int j = i - 4096;   o_g1[j] = f2bf(g1[(j & 127) * 128 + (j >> 7)]); }
    else if (i < 36864)  { int j = i - 20480;  o_g2[j] = f2bf(g2[(j & 127) * 128 + (j >> 7)]); }
    else if (i < 69632)  { int j = i - 36864;  o_i0[j] = f2bf(i0[j]); }
    else if (i < 86016)  { int j = i - 69632;  o_i1[j] = f2bf(i1[j]); }
    else if (i < 102400) { int j = i - 86016;  o_i2[j] = f2bf(i2[j]); }
    else if (i < 118784) { int j = i - 102400; o_h0[j] = f2bf(h0[j]); }
    else if (i < 135168) { int j = i - 118784; o_h1[j] = f2bf(h1[j]); }
    else if (i < 151552) { int j = i - 135168; o_h2[j] = f2bf(h2[j]); }
}

// ============================ fused GCN layer 0: agg(x fp32) + W0 GEMM + BN ============================
// Block = 16 nodes x 1 t; edge window [rowptr[n0], rowptr[n0+16]) is contiguous (CSR
// dst-sorted) -> staged to LDS once; edge loops read int2 meta via ds_read_b64 and
// unroll 4 for gather MLP. Phase B: 16x128 GEMM vs W0t with register B-frags.
__global__ __launch_bounds__(NTHREADS)
void gcn32_kernel(const float* __restrict__ x, const int* __restrict__ rowptr,
                  const int2* __restrict__ epk,
                  const float* __restrict__ selfw, const u16* __restrict__ Wt,
                  const float* __restrict__ bias,
                  const float* __restrict__ bng, const float* __restrict__ bnb,
                  const float* __restrict__ bnm, const float* __restrict__ bnv,
                  u16* __restrict__ out, int N) {
    constexpr int ASTR = 40;
    constexpr int ECAP = 1024;
    __shared__ __align__(16) u16 aT[16][ASTR];
    __shared__ int2 sM[ECAP];
    const int t = blockIdx.x;
    const int n0 = blockIdx.y * 16;
    const int tid = threadIdx.x;
    const int wid = tid >> 6, lane = tid & 63;
    const int quad = lane >> 4, l16 = lane & 15;
    const float* xb = x + (long)t * N * 32;

    const int eb0 = rowptr[n0];
    const int ecnt = min(rowptr[n0 + 16] - eb0, ECAP);
    for (int p = tid; p < ecnt; p += NTHREADS) sM[p] = epk[eb0 + p];
    __syncthreads();

    // ---- phase A: aggregate 4 nodes per wave (8 splits x 8 lanes x 4ch) ----
    const int split = lane >> 3;                  // 0..7
    const int c4 = (lane & 7) * 4;
    for (int i = 0; i < 4; ++i) {
        const int n = n0 + wid * 4 + i;
        const int l0 = rowptr[n] - eb0;
        const int l1 = rowptr[n + 1] - eb0;
        const int eL = min(l1, ecnt);
        const int start = l0 + split;
        float a[4] = {};
        #pragma unroll 4
        for (int e = start; e < eL; e += 8) {
            const int2 m = sM[e];
            const float wgt = __int_as_float(m.y);
            const float4 v = *(const float4*)(xb + (long)m.x * 32 + c4);
            a[0] = fmaf(wgt, v.x, a[0]);
            a[1] = fmaf(wgt, v.y, a[1]);
            a[2] = fmaf(wgt, v.z, a[2]);
            a[3] = fmaf(wgt, v.w, a[3]);
        }
        // overflow tail (statistically never taken)
        const int kL = (eL > start) ? (eL - start + 7) >> 3 : 0;
        for (int e = start + kL * 8; e < l1; e += 8) {
            const int2 m = epk[eb0 + e];
            const float wgt = __int_as_float(m.y);
            const float4 v = *(const float4*)(xb + (long)m.x * 32 + c4);
            a[0] = fmaf(wgt, v.x, a[0]);
            a[1] = fmaf(wgt, v.y, a[1]);
            a[2] = fmaf(wgt, v.z, a[2]);
            a[3] = fmaf(wgt, v.w, a[3]);
        }
        #pragma unroll
        for (int j = 0; j < 4; ++j) {
            a[j] += __shfl_xor(a[j], 8);
            a[j] += __shfl_xor(a[j], 16);
            a[j] += __shfl_xor(a[j], 32);
        }
        if (split == 0) {
            const float sw = selfw[n];
            const float4 sv = *(const float4*)(xb + (long)n * 32 + c4);
            ushort4 o;
            o.x = f2bf(fmaf(sw, sv.x, a[0]));
            o.y = f2bf(fmaf(sw, sv.y, a[1]));
            o.z = f2bf(fmaf(sw, sv.z, a[2]));
            o.w = f2bf(fmaf(sw, sv.w, a[3]));
            *(ushort4*)(&aT[wid * 4 + i][c4]) = o;
        }
    }
    __syncthreads();

    // ---- phase B: [16 nodes] x [32k] @ Wt^T -> [16][128], wave owns 32 cols ----
    const short8_t fA = *(const short8_t*)(&aT[l16][quad * 8]);
    float4_t acc[2];
    short8_t fB[2];
    #pragma unroll
    for (int ct = 0; ct < 2; ++ct) {
        const int col = wid * 32 + ct * 16 + l16;
        fB[ct] = *(const short8_t*)(Wt + (long)col * 32 + quad * 8);
        acc[ct] = (float4_t){0.f, 0.f, 0.f, 0.f};
    }
    #pragma unroll
    for (int ct = 0; ct < 2; ++ct)
        acc[ct] = __builtin_amdgcn_mfma_f32_16x16x32_bf16(fA, fB[ct], acc[ct], 0, 0, 0);

    #pragma unroll
    for (int ct = 0; ct < 2; ++ct) {
        const int c = wid * 32 + ct * 16 + l16;
        const float s = bng[c] * rsqrtf(bnv[c] + 1e-5f);
        const float a1 = bnb[c] - bnm[c] * s;
        const float a0 = bias[c];
        #pragma unroll
        for (int r = 0; r < 4; ++r) {
            const int node = quad * 4 + r;
            float v = fmaf(fmaxf(acc[ct][r] + a0, 0.f), s, a1);
            out[((long)t * N + n0 + node) * 128 + c] = f2bf(v);
        }
    }
}

// ============================ fused GCN layers 1/2: agg(h bf16) + W GEMM + epi ============================
// EPI: 1 = bias,ReLU ; 2 = bias,ReLU,BN.  Wt is [128col][128k] bf16.
template<int EPI>
__global__ __launch_bounds__(NTHREADS)
void gcn128_kernel(const u16* __restrict__ h, const int* __restrict__ rowptr,
                   const int2* __restrict__ epk,
                   const float* __restrict__ selfw, const u16* __restrict__ Wt,
                   const float* __restrict__ bias,
                   const float* __restrict__ bng, const float* __restrict__ bnb,
                   const float* __restrict__ bnm, const float* __restrict__ bnv,
                   u16* __restrict__ out, int N) {
    constexpr int ASTR = 136;
    constexpr int ECAP = 1024;
    __shared__ __align__(16) u16 aT[16][ASTR];
    __shared__ int2 sM[ECAP];
    const int t = blockIdx.x;
    const int n0 = blockIdx.y * 16;
    const int tid = threadIdx.x;
    const int wid = tid >> 6, lane = tid & 63;
    const int quad = lane >> 4, l16 = lane & 15;
    const u16* hb = h + (long)t * N * 128;

    const int eb0 = rowptr[n0];
    const int ecnt = min(rowptr[n0 + 16] - eb0, ECAP);
    for (int p = tid; p < ecnt; p += NTHREADS) sM[p] = epk[eb0 + p];
    __syncthreads();

    // ---- phase A: aggregate 4 nodes per wave (4 splits x 16 lanes x 8ch) ----
    const int split = lane >> 4;                  // 0..3
    const int c8 = l16 * 8;
    for (int i = 0; i < 4; ++i) {
        const int n = n0 + wid * 4 + i;
        const int l0 = rowptr[n] - eb0;
        const int l1 = rowptr[n + 1] - eb0;
        const int eL = min(l1, ecnt);
        const int start = l0 + split;
        float a[8] = {};
        #pragma unroll 4
        for (int e = start; e < eL; e += 4) {
            const int2 m = sM[e];
            const float wgt = __int_as_float(m.y);
            const uint4 v = *(const uint4*)(hb + (long)m.x * 128 + c8);
            float f[8];
            bf8_unpack(v, f);
            #pragma unroll
            for (int j = 0; j < 8; ++j) a[j] = fmaf(wgt, f[j], a[j]);
        }
        // overflow tail (statistically never taken)
        const int kL = (eL > start) ? (eL - start + 3) >> 2 : 0;
        for (int e = start + kL * 4; e < l1; e += 4) {
            const int2 m = epk[eb0 + e];
            const float wgt = __int_as_float(m.y);
            const uint4 v = *(const uint4*)(hb + (long)m.x * 128 + c8);
            float f[8];
            bf8_unpack(v, f);
            #pragma unroll
            for (int j = 0; j < 8; ++j) a[j] = fmaf(wgt, f[j], a[j]);
        }
        #pragma unroll
        for (int j = 0; j < 8; ++j) {
            a[j] += __shfl_xor(a[j], 16);
            a[j] += __shfl_xor(a[j], 32);
        }
        if (split == 0) {
            const float sw = selfw[n];
            const uint4 sv = *(const uint4*)(hb + (long)n * 128 + c8);
            float f[8];
            bf8_unpack(sv, f);
            ushort4 o0, o1;
            o0.x = f2bf(fmaf(sw, f[0], a[0])); o0.y = f2bf(fmaf(sw, f[1], a[1]));
            o0.z = f2bf(fmaf(sw, f[2], a[2])); o0.w = f2bf(fmaf(sw, f[3], a[3]));
            o1.x = f2bf(fmaf(sw, f[4], a[4])); o1.y = f2bf(fmaf(sw, f[5], a[5]));
            o1.z = f2bf(fmaf(sw, f[6], a[6])); o1.w = f2bf(fmaf(sw, f[7], a[7]));
            *(ushort4*)(&aT[wid * 4 + i][c8]) = o0;
            *(ushort4*)(&aT[wid * 4 + i][c8 + 4]) = o1;
        }
    }
    __syncthreads();

    // ---- phase B: [16][128] @ Wt^T -> [16][128]; wave owns 32 cols, K=128 ----
    short8_t fA[4];
    #pragma unroll
    for (int ks = 0; ks < 4; ++ks)
        fA[ks] = *(const short8_t*)(&aT[l16][ks * 32 + quad * 8]);
    float4_t acc[2];
    #pragma unroll
    for (int ct = 0; ct < 2; ++ct) acc[ct] = (float4_t){0.f, 0.f, 0.f, 0.f};
    #pragma unroll
    for (int ct = 0; ct < 2; ++ct) {
        const int col = wid * 32 + ct * 16 + l16;
        #pragma unroll
        for (int ks = 0; ks < 4; ++ks) {
            const short8_t fB = *(const short8_t*)(Wt + (long)col * 128 + ks * 32 + quad * 8);
            acc[ct] = __builtin_amdgcn_mfma_f32_16x16x32_bf16(fA[ks], fB, acc[ct], 0, 0, 0);
        }
    }

    #pragma unroll
    for (int ct = 0; ct < 2; ++ct) {
        const int c = wid * 32 + ct * 16 + l16;
        const float a0 = bias[c];
        float s = 0.f, a1 = 0.f;
        if constexpr (EPI == 2) {
            s = bng[c] * rsqrtf(bnv[c] + 1e-5f);
            a1 = bnb[c] - bnm[c] * s;
        }
        #pragma unroll
        for (int r = 0; r < 4; ++r) {
            const int node = quad * 4 + r;
            float v = fmaxf(acc[ct][r] + a0, 0.f);
            if constexpr (EPI == 2) v = fmaf(v, s, a1);
            out[((long)t * N + n0 + node) * 128 + c] = f2bf(v);
        }
    }
}

// ============================ per-layer fused LSTM ============================
template<int KIN, bool IN_SPLIT, bool LAST>
__global__ __launch_bounds__(NTHREADS, 2)
void lstm_layer_kernel(const u16* __restrict__ in_hi, const u16* __restrict__ in_lo,
                       const u16* __restrict__ wih, const u16* __restrict__ whh,
                       const float* __restrict__ bi, const float* __restrict__ bh,
                       u16* __restrict__ out_hi, u16* __restrict__ out_lo,
                       float* __restrict__ out_f, int N) {
    constexpr int NKS = KIN / 32;
    constexpr int HSTR = 76;
    const int tid = threadIdx.x;
    const int w = tid >> 6, lane = tid & 63;
    const int quad = lane >> 4, l16 = lane & 15;
    const int n0 = blockIdx.x * 16;
    const int u = w * 16 + l16;

    __shared__ __align__(16) u16 hT[2][16][HSTR];
    for (int p = tid; p < 2 * 16 * HSTR; p += NTHREADS) (&hT[0][0][0])[p] = 0;

    short8_t fI[4][NKS], fH[4][2];
    #pragma unroll
    for (int g = 0; g < 4; ++g) {
        #pragma unroll
        for (int ks = 0; ks < NKS; ++ks)
            fI[g][ks] = *(const short8_t*)(wih + (long)(g * 64 + u) * KIN + ks * 32 + quad * 8);
        #pragma unroll
        for (int ks = 0; ks < 2; ++ks)
            fH[g][ks] = *(const short8_t*)(whh + (long)(g * 64 + u) * 64 + ks * 32 + quad * 8);
    }
    float bias[4];
    #pragma unroll
    for (int g = 0; g < 4; ++g) bias[g] = bi[g * 64 + u] + bh[g * 64 + u];
    float cst[4] = {};
    __syncthreads();

    #pragma unroll 1
    for (int t = 0; t < T_STEPS; ++t) {
        short8_t ain[NKS], ainl[NKS];
        const long ibase = ((long)t * N + n0 + l16) * KIN + quad * 8;
        #pragma unroll
        for (int ks = 0; ks < NKS; ++ks) {
            ain[ks] = *(const short8_t*)(in_hi + ibase + ks * 32);
            if constexpr (IN_SPLIT) ainl[ks] = *(const short8_t*)(in_lo + ibase + ks * 32);
        }
        short8_t ah[2], al[2];
        #pragma unroll
        for (int ks = 0; ks < 2; ++ks) {
            ah[ks] = *(const short8_t*)(&hT[0][l16][ks * 32 + quad * 8]);
            al[ks] = *(const short8_t*)(&hT[1][l16][ks * 32 + quad * 8]);
        }
        __syncthreads();

        float4_t acc[4];
        #pragma unroll
        for (int g = 0; g < 4; ++g) acc[g] = (float4_t){bias[g], bias[g], bias[g], bias[g]};
        #pragma unroll
        for (int ks = 0; ks < NKS; ++ks)
            #pragma unroll
            for (int g = 0; g < 4; ++g) {
                acc[g] = __builtin_amdgcn_mfma_f32_16x16x32_bf16(ain[ks], fI[g][ks], acc[g], 0, 0, 0);
                if constexpr (IN_SPLIT)
                    acc[g] = __builtin_amdgcn_mfma_f32_16x16x32_bf16(ainl[ks], fI[g][ks], acc[g], 0, 0, 0);
            }
        #pragma unroll
        for (int ks = 0; ks < 2; ++ks)
            #pragma unroll
            for (int g = 0; g < 4; ++g) {
                acc[g] = __builtin_amdgcn_mfma_f32_16x16x32_bf16(ah[ks], fH[g][ks], acc[g], 0, 0, 0);
                acc[g] = __builtin_amdgcn_mfma_f32_16x16x32_bf16(al[ks], fH[g][ks], acc[g], 0, 0, 0);
            }

        #pragma unroll
        for (int r = 0; r < 4; ++r) {
            const float si = fsig(acc[0][r]);
            const float sf = fsig(acc[1][r]);
            const float gg = ftanh(acc[2][r]);
            const float so = fsig(acc[3][r]);
            const float c = sf * cst[r] + si * gg;
            cst[r] = c;
            const float h = so * ftanh(c);
            const int node = quad * 4 + r;
            const u16 hi = f2bf(h);
            const u16 lo = f2bf(h - bf2f(hi));
            hT[0][node][u] = hi;
            hT[1][node][u] = lo;
            if constexpr (LAST) {
                if (t == T_STEPS - 1) out_f[(long)(n0 + node) * 64 + u] = h;
            } else {
                const long o = ((long)t * N + n0 + node) * 64 + u;
                out_hi[o] = hi;
                out_lo[o] = lo;
            }
        }
        __syncthreads();
    }
}

// ============================ launch ============================
extern "C" void kernel_launch(void* const* d_in, const int* in_sizes, int n_in,
                              void* d_out, int out_size, void* d_ws, size_t ws_size,
                              hipStream_t stream) {
    (void)n_in; (void)out_size; (void)ws_size;
    const float* x      = (const float*)d_in[0];
    const int*   ei     = (const int*)d_in[1];
    const float* w_gcn0 = (const float*)d_in[2];
    const float* b_gcn0 = (const float*)d_in[3];
    const float* w_gcn1 = (const float*)d_in[4];
    const float* b_gcn1 = (const float*)d_in[5];
    const float* w_gcn2 = (const float*)d_in[6];
    const float* b_gcn2 = (const float*)d_in[7];
    const float* bn_g0  = (const float*)d_in[8];
    const float* bn_b0  = (const float*)d_in[9];
    const float* bn_m0  = (const float*)d_in[10];
    const float* bn_v0  = (const float*)d_in[11];
    const float* bn_g1  = (const float*)d_in[12];
    const float* bn_b1  = (const float*)d_in[13];
    const float* bn_m1  = (const float*)d_in[14];
    const float* bn_v1  = (const float*)d_in[15];
    const float* w_ih_0 = (const float*)d_in[16];
    const float* w_hh_0 = (const float*)d_in[17];
    const float* b_ih_0 = (const float*)d_in[18];
    const float* b_hh_0 = (const float*)d_in[19];
    const float* w_ih_1 = (const float*)d_in[20];
    const float* w_hh_1 = (const float*)d_in[21];
    const float* b_ih_1 = (const float*)d_in[22];
    const float* b_hh_1 = (const float*)d_in[23];
    const float* w_ih_2 = (const float*)d_in[24];
    const float* w_hh_2 = (const float*)d_in[25];
    const float* b_ih_2 = (const float*)d_in[26];
    const float* b_hh_2 = (const float*)d_in[27];

    const int E = in_sizes[1] / 2;
    const int N = in_sizes[0] / (T_STEPS * F_INC);     // 10000
    const long M = (long)N * T_STEPS;                  // 80000

    char* ws = (char*)d_ws;
    size_t off = 0;
    auto carve = [&](size_t bytes) -> void* {
        void* p = ws + off;
        off += (bytes + 255) & ~(size_t)255;
        return p;
    };
    float* dis     = (float*)carve((size_t)N * 4);
    float* selfw   = (float*)carve((size_t)N * 4);
    int*   cnt     = (int*)carve((size_t)N * 4);
    int*   rowptr  = (int*)carve((size_t)(N + 1) * 4);
    int*   wp      = (int*)carve((size_t)N * 4);
    int2*  epk     = (int2*)carve((size_t)E * 8);
    int*   bsum    = (int*)carve(64 * 4);
    u16*   hbuf    = (u16*)carve((size_t)M * H_DIM * 2);      // 20.5 MB, [t][n][128]
    u16*   hbuf2   = (u16*)carve((size_t)M * H_DIM * 2);      // 20.5 MB ping-pong
    u16*   pA_hi   = (u16*)carve((size_t)M * O_DIM * 2);
    u16*   pA_lo   = (u16*)carve((size_t)M * O_DIM * 2);
    u16*   pB_hi   = (u16*)carve((size_t)M * O_DIM * 2);
    u16*   pB_lo   = (u16*)carve((size_t)M * O_DIM * 2);
    u16*   wt0     = (u16*)carve((size_t)128 * 32 * 2);
    u16*   wt1     = (u16*)carve((size_t)128 * 128 * 2);
    u16*   wt2     = (u16*)carve((size_t)128 * 128 * 2);
    u16*   wtih0   = (u16*)carve((size_t)256 * 128 * 2);
    u16*   wtih1   = (u16*)carve((size_t)256 * 64 * 2);
    u16*   wtih2   = (u16*)carve((size_t)256 * 64 * 2);
    u16*   whh0b   = (u16*)carve((size_t)256 * 64 * 2);
    u16*   whh1b   = (u16*)carve((size_t)256 * 64 * 2);
    u16*   whh2b   = (u16*)carve((size_t)256 * 64 * 2);

    const dim3 b256(NTHREADS);
    const int gN = (N + NTHREADS - 1) / NTHREADS;      // 40
    const int gE = (E + NTHREADS - 1) / NTHREADS;

    // ---- CSR + normalization ----
    hipMemsetAsync(cnt, 0, (size_t)N * 4, stream);
    count_kernel<<<gE, b256, 0, stream>>>(ei, cnt, E);
    scan_part1<<<gN, b256, 0, stream>>>(cnt, bsum, N);
    scan_part3<<<gN, b256, 0, stream>>>(cnt, bsum, rowptr, wp, dis, selfw, N);
    fill_kernel<<<gE, b256, 0, stream>>>(ei, dis, wp, epk, E);

    // ---- weight prep ----
    wprep_all_kernel<<<(151552 + 255) / 256, b256, 0, stream>>>(
        w_gcn0, w_gcn1, w_gcn2, w_ih_0, w_ih_1, w_ih_2, w_hh_0, w_hh_1, w_hh_2,
        wt0, wt1, wt2, wtih0, wtih1, wtih2, whh0b, whh1b, whh2b);

    // ---- GCN: fused agg+GEMM per layer (t-major, XCD-pinned, LDS edge staging) ----
    const dim3 gG(T_STEPS, N / 16);                     // (8, 625)
    gcn32_kernel<<<gG, b256, 0, stream>>>(
        x, rowptr, epk, selfw, wt0, b_gcn0,
        bn_g0, bn_b0, bn_m0, bn_v0, hbuf, N);
    gcn128_kernel<2><<<gG, b256, 0, stream>>>(
        hbuf, rowptr, epk, selfw, wt1, b_gcn1,
        bn_g1, bn_b1, bn_m1, bn_v1, hbuf2, N);
    gcn128_kernel<1><<<gG, b256, 0, stream>>>(
        hbuf2, rowptr, epk, selfw, wt2, b_gcn2,
        nullptr, nullptr, nullptr, nullptr, hbuf, N);

    // ---- LSTM: three per-layer fused kernels ----
    const int gL = N / 16;             // 625
    lstm_layer_kernel<128, false, false><<<gL, b256, 0, stream>>>(
        hbuf, nullptr, wtih0, whh0b, b_ih_0, b_hh_0, pA_hi, pA_lo, nullptr, N);
    lstm_layer_kernel<64, true, false><<<gL, b256, 0, stream>>>(
        pA_hi, pA_lo, wtih1, whh1b, b_ih_1, b_hh_1, pB_hi, pB_lo, nullptr, N);
    lstm_layer_kernel<64, true, true><<<gL, b256, 0, stream>>>(
        pB_hi, pB_lo, wtih2, whh2b, b_ih_2, b_hh_2, nullptr, nullptr, (float*)d_out, N);
}

// Round 8
// 356.610 us; speedup vs baseline: 3.2806x; 1.0124x over previous
//
#include <hip/hip_runtime.h>
#include <hip/hip_bf16.h>
#include <math.h>

#define NTHREADS 256
#define T_STEPS 8
#define F_INC 32
#define H_DIM 128
#define O_DIM 64

typedef unsigned short u16;
typedef __attribute__((ext_vector_type(8))) short short8_t;
typedef __attribute__((ext_vector_type(4))) float float4_t;
typedef __attribute__((ext_vector_type(2))) float float2_t;

__device__ __forceinline__ float bf2f(u16 u) {
    return __uint_as_float(((unsigned)u) << 16);
}
__device__ __forceinline__ u16 f2bf(float f) {
    __hip_bfloat16 h = __float2bfloat16(f);   // RNE
    union { __hip_bfloat16 h; u16 s; } cv; cv.h = h; return cv.s;
}
// one dword (2 bf16) -> float2 {lo, hi}
__device__ __forceinline__ float2_t bfpair(unsigned u) {
    union { unsigned w[2]; float2_t f; } c;
    c.w[0] = u << 16;
    c.w[1] = u & 0xffff0000u;
    return c.f;
}
__device__ __forceinline__ void bf8_unpack(uint4 u, float* f) {
    f[0] = __uint_as_float(u.x << 16); f[1] = __uint_as_float(u.x & 0xffff0000u);
    f[2] = __uint_as_float(u.y << 16); f[3] = __uint_as_float(u.y & 0xffff0000u);
    f[4] = __uint_as_float(u.z << 16); f[5] = __uint_as_float(u.z & 0xffff0000u);
    f[6] = __uint_as_float(u.w << 16); f[7] = __uint_as_float(u.w & 0xffff0000u);
}
// fast sigmoid/tanh via v_exp_f32 (~1ulp, << bf16 noise)
__device__ __forceinline__ float fsig(float x) {
    float xc = fminf(fmaxf(x, -30.f), 30.f);
    float e = __builtin_amdgcn_exp2f(xc * -1.4426950408889634f);
    return __builtin_amdgcn_rcpf(1.0f + e);
}
__device__ __forceinline__ float ftanh(float x) {
    float xc = fminf(fmaxf(x, -15.f), 15.f);
    float e = __builtin_amdgcn_exp2f(xc * -2.8853900817779268f);
    float r = __builtin_amdgcn_rcpf(1.0f + e);
    return fmaf(-2.0f * e, r, 1.0f);
}

// ============================ CSR build ============================
__global__ void count_kernel(const int* __restrict__ ei, int* __restrict__ cnt, int E) {
    int e = blockIdx.x * NTHREADS + threadIdx.x;
    if (e < E) atomicAdd(&cnt[ei[E + e]], 1);   // dst row of edge_index
}

__global__ void scan_part1(const int* __restrict__ cnt, int* __restrict__ bsum, int n) {
    __shared__ int sd[NTHREADS];
    const int i = blockIdx.x * NTHREADS + threadIdx.x;
    sd[threadIdx.x] = (i < n) ? cnt[i] : 0;
    __syncthreads();
    for (int off = 128; off > 0; off >>= 1) {
        if (threadIdx.x < off) sd[threadIdx.x] += sd[threadIdx.x + off];
        __syncthreads();
    }
    if (threadIdx.x == 0) bsum[blockIdx.x] = sd[0];
}

// inlined block-offset (wave shuffle over bsum) + scan + dis/selfw
__global__ void scan_part3(const int* __restrict__ cnt, const int* __restrict__ bsum,
                           int* __restrict__ rowptr, int* __restrict__ wp,
                           float* __restrict__ dis, float* __restrict__ selfw, int n) {
    __shared__ int sd[NTHREADS];
    __shared__ int sbase;
    const int tid = threadIdx.x;
    if (tid < 64) {
        int v0 = (tid < blockIdx.x) ? bsum[tid] : 0;   // nb <= 64
        #pragma unroll
        for (int off = 1; off < 64; off <<= 1) v0 += __shfl_xor(v0, off);
        if (tid == 0) sbase = v0;
    }
    const int i = blockIdx.x * NTHREADS + tid;
    const int v = (i < n) ? cnt[i] : 0;
    sd[tid] = v;
    __syncthreads();
    for (int off = 1; off < NTHREADS; off <<= 1) {
        const int tv = (tid >= off) ? sd[tid - off] : 0;
        __syncthreads();
        sd[tid] += tv;
        __syncthreads();
    }
    const int excl = sbase + sd[tid] - v;
    if (i < n) {
        rowptr[i] = excl; wp[i] = excl;
        if (i == n - 1) rowptr[n] = excl + v;
        const float d = 1.0f + (float)v;
        dis[i] = rsqrtf(d);
        selfw[i] = 1.0f / d;
    }
}

// packed edge metadata: epk[p] = (src, coef) -> one 8B load per edge
__global__ void fill_kernel(const int* __restrict__ ei, const float* __restrict__ dis,
                            int* __restrict__ wp, int2* __restrict__ epk, int E) {
    int e = blockIdx.x * NTHREADS + threadIdx.x;
    if (e < E) {
        int s = ei[e], d = ei[E + e];
        int p = atomicAdd(&wp[d], 1);
        epk[p] = make_int2(s, __float_as_int(dis[s] * dis[d]));
    }
}

// ============================ fused weight prep (one launch) ============================
__global__ void wprep_all_kernel(const float* g0, const float* g1, const float* g2,
                                 const float* i0, const float* i1, const float* i2,
                                 const float* h0, const float* h1, const float* h2,
                                 u16* o_g0, u16* o_g1, u16* o_g2,
                                 u16* o_i0, u16* o_i1, u16* o_i2,
                                 u16* o_h0, u16* o_h1, u16* o_h2) {
    const int i = blockIdx.x * NTHREADS + threadIdx.x;
    if (i < 4096)        { o_g0[i] = f2bf(g0[(i & 31) * 128 + (i >> 5)]); }
    else if (i < 20480)  { int j = i - 4096;   o_g1[j] = f2bf(g1[(j & 127) * 128 + (j >> 7)]); }
    else if (i < 36864)  { int j = i - 20480;  o_g2[j] = f2bf(g2[(j & 127) * 128 + (j >> 7)]); }
    else if (i < 69632)  { int j = i - 36864;  o_i0[j] = f2bf(i0[j]); }
    else if (i < 86016)  { int j = i - 69632;  o_i1[j] = f2bf(i1[j]); }
    else if (i < 102400) { int j = i - 86016;  o_i2[j] = f2bf(i2[j]); }
    else if (i < 118784) { int j = i - 102400; o_h0[j] = f2bf(h0[j]); }
    else if (i < 135168) { int j = i - 118784; o_h1[j] = f2bf(h1[j]); }
    else if (i < 151552) { int j = i - 135168; o_h2[j] = f2bf(h2[j]); }
}

// ============================ fused GCN layer 0: agg(x fp32) + W0 GEMM + BN ============================
// t-PAIRED: block = 16 nodes x 2 t-slices (edge metadata, staging, addresses shared).
// Paired x working set 2.56 MB fits one XCD L2. pk_fma float2 accumulation.
__global__ __launch_bounds__(NTHREADS)
void gcn32_kernel(const float* __restrict__ x, const int* __restrict__ rowptr,
                  const int2* __restrict__ epk,
                  const float* __restrict__ selfw, const u16* __restrict__ Wt,
                  const float* __restrict__ bias,
                  const float* __restrict__ bng, const float* __restrict__ bnb,
                  const float* __restrict__ bnm, const float* __restrict__ bnv,
                  u16* __restrict__ out, int N) {
    constexpr int ASTR = 40;
    constexpr int ECAP = 1024;
    __shared__ __align__(16) u16 aT[2][16][ASTR];
    __shared__ int2 sM[ECAP];
    const int t0 = blockIdx.x * 2;
    const int n0 = blockIdx.y * 16;
    const int tid = threadIdx.x;
    const int wid = tid >> 6, lane = tid & 63;
    const int quad = lane >> 4, l16 = lane & 15;
    const float* xb0 = x + (long)t0 * N * 32;
    const float* xb1 = xb0 + (long)N * 32;

    const int eb0 = rowptr[n0];
    const int ecnt = min(rowptr[n0 + 16] - eb0, ECAP);
    for (int p = tid; p < ecnt; p += NTHREADS) sM[p] = epk[eb0 + p];
    __syncthreads();

    // ---- phase A: aggregate 4 nodes per wave (8 splits x 8 lanes x 4ch x 2t) ----
    const int split = lane >> 3;                  // 0..7
    const int c4 = (lane & 7) * 4;
    for (int i = 0; i < 4; ++i) {
        const int n = n0 + wid * 4 + i;
        const int l0 = rowptr[n] - eb0;
        const int l1 = rowptr[n + 1] - eb0;
        const int eL = min(l1, ecnt);
        const int start = l0 + split;
        float2_t a0[2] = {(float2_t){0.f, 0.f}, (float2_t){0.f, 0.f}};
        float2_t a1[2] = {(float2_t){0.f, 0.f}, (float2_t){0.f, 0.f}};
        #pragma unroll 2
        for (int e = start; e < eL; e += 8) {
            const int2 m = sM[e];
            const float w = __int_as_float(m.y);
            const float2_t w2 = {w, w};
            const long o = (long)m.x * 32 + c4;
            const float4 v0 = *(const float4*)(xb0 + o);
            const float4 v1 = *(const float4*)(xb1 + o);
            a0[0] = __builtin_elementwise_fma((float2_t){v0.x, v0.y}, w2, a0[0]);
            a0[1] = __builtin_elementwise_fma((float2_t){v0.z, v0.w}, w2, a0[1]);
            a1[0] = __builtin_elementwise_fma((float2_t){v1.x, v1.y}, w2, a1[0]);
            a1[1] = __builtin_elementwise_fma((float2_t){v1.z, v1.w}, w2, a1[1]);
        }
        // overflow tail (statistically never taken)
        const int kL = (eL > start) ? (eL - start + 7) >> 3 : 0;
        for (int e = start + kL * 8; e < l1; e += 8) {
            const int2 m = epk[eb0 + e];
            const float w = __int_as_float(m.y);
            const float2_t w2 = {w, w};
            const long o = (long)m.x * 32 + c4;
            const float4 v0 = *(const float4*)(xb0 + o);
            const float4 v1 = *(const float4*)(xb1 + o);
            a0[0] = __builtin_elementwise_fma((float2_t){v0.x, v0.y}, w2, a0[0]);
            a0[1] = __builtin_elementwise_fma((float2_t){v0.z, v0.w}, w2, a0[1]);
            a1[0] = __builtin_elementwise_fma((float2_t){v1.x, v1.y}, w2, a1[0]);
            a1[1] = __builtin_elementwise_fma((float2_t){v1.z, v1.w}, w2, a1[1]);
        }
        float r[8] = {a0[0][0], a0[0][1], a0[1][0], a0[1][1],
                      a1[0][0], a1[0][1], a1[1][0], a1[1][1]};
        #pragma unroll
        for (int j = 0; j < 8; ++j) {
            r[j] += __shfl_xor(r[j], 8);
            r[j] += __shfl_xor(r[j], 16);
            r[j] += __shfl_xor(r[j], 32);
        }
        if (split == 0) {
            const float sw = selfw[n];
            const float4 s0 = *(const float4*)(xb0 + (long)n * 32 + c4);
            const float4 s1 = *(const float4*)(xb1 + (long)n * 32 + c4);
            ushort4 o0, o1;
            o0.x = f2bf(fmaf(sw, s0.x, r[0])); o0.y = f2bf(fmaf(sw, s0.y, r[1]));
            o0.z = f2bf(fmaf(sw, s0.z, r[2])); o0.w = f2bf(fmaf(sw, s0.w, r[3]));
            o1.x = f2bf(fmaf(sw, s1.x, r[4])); o1.y = f2bf(fmaf(sw, s1.y, r[5]));
            o1.z = f2bf(fmaf(sw, s1.z, r[6])); o1.w = f2bf(fmaf(sw, s1.w, r[7]));
            *(ushort4*)(&aT[0][wid * 4 + i][c4]) = o0;
            *(ushort4*)(&aT[1][wid * 4 + i][c4]) = o1;
        }
    }
    __syncthreads();

    // ---- phase B: two 16x128 GEMMs vs W0t; wave owns 32 cols ----
    const short8_t fA0 = *(const short8_t*)(&aT[0][l16][quad * 8]);
    const short8_t fA1 = *(const short8_t*)(&aT[1][l16][quad * 8]);
    float4_t acc[2][2];
    short8_t fB[2];
    #pragma unroll
    for (int ct = 0; ct < 2; ++ct) {
        const int col = wid * 32 + ct * 16 + l16;
        fB[ct] = *(const short8_t*)(Wt + (long)col * 32 + quad * 8);
        acc[0][ct] = (float4_t){0.f, 0.f, 0.f, 0.f};
        acc[1][ct] = (float4_t){0.f, 0.f, 0.f, 0.f};
    }
    #pragma unroll
    for (int ct = 0; ct < 2; ++ct) {
        acc[0][ct] = __builtin_amdgcn_mfma_f32_16x16x32_bf16(fA0, fB[ct], acc[0][ct], 0, 0, 0);
        acc[1][ct] = __builtin_amdgcn_mfma_f32_16x16x32_bf16(fA1, fB[ct], acc[1][ct], 0, 0, 0);
    }

    #pragma unroll
    for (int ct = 0; ct < 2; ++ct) {
        const int c = wid * 32 + ct * 16 + l16;
        const float s = bng[c] * rsqrtf(bnv[c] + 1e-5f);
        const float a1 = bnb[c] - bnm[c] * s;
        const float a0 = bias[c];
        #pragma unroll
        for (int tt = 0; tt < 2; ++tt) {
            #pragma unroll
            for (int r = 0; r < 4; ++r) {
                const int node = quad * 4 + r;
                float v = fmaf(fmaxf(acc[tt][ct][r] + a0, 0.f), s, a1);
                out[((long)(t0 + tt) * N + n0 + node) * 128 + c] = f2bf(v);
            }
        }
    }
}

// ============================ fused GCN layers 1/2: agg(h bf16) + W GEMM + epi ============================
// EPI: 1 = bias,ReLU ; 2 = bias,ReLU,BN.  Wt is [128col][128k] bf16. pk_fma float2.
template<int EPI>
__global__ __launch_bounds__(NTHREADS)
void gcn128_kernel(const u16* __restrict__ h, const int* __restrict__ rowptr,
                   const int2* __restrict__ epk,
                   const float* __restrict__ selfw, const u16* __restrict__ Wt,
                   const float* __restrict__ bias,
                   const float* __restrict__ bng, const float* __restrict__ bnb,
                   const float* __restrict__ bnm, const float* __restrict__ bnv,
                   u16* __restrict__ out, int N) {
    constexpr int ASTR = 136;
    constexpr int ECAP = 1024;
    __shared__ __align__(16) u16 aT[16][ASTR];
    __shared__ int2 sM[ECAP];
    const int t = blockIdx.x;
    const int n0 = blockIdx.y * 16;
    const int tid = threadIdx.x;
    const int wid = tid >> 6, lane = tid & 63;
    const int quad = lane >> 4, l16 = lane & 15;
    const u16* hb = h + (long)t * N * 128;

    const int eb0 = rowptr[n0];
    const int ecnt = min(rowptr[n0 + 16] - eb0, ECAP);
    for (int p = tid; p < ecnt; p += NTHREADS) sM[p] = epk[eb0 + p];
    __syncthreads();

    // ---- phase A: aggregate 4 nodes per wave (4 splits x 16 lanes x 8ch) ----
    const int split = lane >> 4;                  // 0..3
    const int c8 = l16 * 8;
    for (int i = 0; i < 4; ++i) {
        const int n = n0 + wid * 4 + i;
        const int l0 = rowptr[n] - eb0;
        const int l1 = rowptr[n + 1] - eb0;
        const int eL = min(l1, ecnt);
        const int start = l0 + split;
        float2_t a2[4] = {(float2_t){0.f, 0.f}, (float2_t){0.f, 0.f},
                          (float2_t){0.f, 0.f}, (float2_t){0.f, 0.f}};
        #pragma unroll 4
        for (int e = start; e < eL; e += 4) {
            const int2 m = sM[e];
            const float w = __int_as_float(m.y);
            const float2_t w2 = {w, w};
            const uint4 v = *(const uint4*)(hb + (long)m.x * 128 + c8);
            a2[0] = __builtin_elementwise_fma(bfpair(v.x), w2, a2[0]);
            a2[1] = __builtin_elementwise_fma(bfpair(v.y), w2, a2[1]);
            a2[2] = __builtin_elementwise_fma(bfpair(v.z), w2, a2[2]);
            a2[3] = __builtin_elementwise_fma(bfpair(v.w), w2, a2[3]);
        }
        // overflow tail (statistically never taken)
        const int kL = (eL > start) ? (eL - start + 3) >> 2 : 0;
        for (int e = start + kL * 4; e < l1; e += 4) {
            const int2 m = epk[eb0 + e];
            const float w = __int_as_float(m.y);
            const float2_t w2 = {w, w};
            const uint4 v = *(const uint4*)(hb + (long)m.x * 128 + c8);
            a2[0] = __builtin_elementwise_fma(bfpair(v.x), w2, a2[0]);
            a2[1] = __builtin_elementwise_fma(bfpair(v.y), w2, a2[1]);
            a2[2] = __builtin_elementwise_fma(bfpair(v.z), w2, a2[2]);
            a2[3] = __builtin_elementwise_fma(bfpair(v.w), w2, a2[3]);
        }
        float a[8] = {a2[0][0], a2[0][1], a2[1][0], a2[1][1],
                      a2[2][0], a2[2][1], a2[3][0], a2[3][1]};
        #pragma unroll
        for (int j = 0; j < 8; ++j) {
            a[j] += __shfl_xor(a[j], 16);
            a[j] += __shfl_xor(a[j], 32);
        }
        if (split == 0) {
            const float sw = selfw[n];
            const uint4 sv = *(const uint4*)(hb + (long)n * 128 + c8);
            float f[8];
            bf8_unpack(sv, f);
            ushort4 o0, o1;
            o0.x = f2bf(fmaf(sw, f[0], a[0])); o0.y = f2bf(fmaf(sw, f[1], a[1]));
            o0.z = f2bf(fmaf(sw, f[2], a[2])); o0.w = f2bf(fmaf(sw, f[3], a[3]));
            o1.x = f2bf(fmaf(sw, f[4], a[4])); o1.y = f2bf(fmaf(sw, f[5], a[5]));
            o1.z = f2bf(fmaf(sw, f[6], a[6])); o1.w = f2bf(fmaf(sw, f[7], a[7]));
            *(ushort4*)(&aT[wid * 4 + i][c8]) = o0;
            *(ushort4*)(&aT[wid * 4 + i][c8 + 4]) = o1;
        }
    }
    __syncthreads();

    // ---- phase B: [16][128] @ Wt^T -> [16][128]; wave owns 32 cols, K=128 ----
    short8_t fA[4];
    #pragma unroll
    for (int ks = 0; ks < 4; ++ks)
        fA[ks] = *(const short8_t*)(&aT[l16][ks * 32 + quad * 8]);
    float4_t acc[2];
    #pragma unroll
    for (int ct = 0; ct < 2; ++ct) acc[ct] = (float4_t){0.f, 0.f, 0.f, 0.f};
    #pragma unroll
    for (int ct = 0; ct < 2; ++ct) {
        const int col = wid * 32 + ct * 16 + l16;
        #pragma unroll
        for (int ks = 0; ks < 4; ++ks) {
            const short8_t fB = *(const short8_t*)(Wt + (long)col * 128 + ks * 32 + quad * 8);
            acc[ct] = __builtin_amdgcn_mfma_f32_16x16x32_bf16(fA[ks], fB, acc[ct], 0, 0, 0);
        }
    }

    #pragma unroll
    for (int ct = 0; ct < 2; ++ct) {
        const int c = wid * 32 + ct * 16 + l16;
        const float a0 = bias[c];
        float s = 0.f, a1 = 0.f;
        if constexpr (EPI == 2) {
            s = bng[c] * rsqrtf(bnv[c] + 1e-5f);
            a1 = bnb[c] - bnm[c] * s;
        }
        #pragma unroll
        for (int r = 0; r < 4; ++r) {
            const int node = quad * 4 + r;
            float v = fmaxf(acc[ct][r] + a0, 0.f);
            if constexpr (EPI == 2) v = fmaf(v, s, a1);
            out[((long)t * N + n0 + node) * 128 + c] = f2bf(v);
        }
    }
}

// ============================ per-layer fused LSTM ============================
template<int KIN, bool IN_SPLIT, bool LAST>
__global__ __launch_bounds__(NTHREADS, 2)
void lstm_layer_kernel(const u16* __restrict__ in_hi, const u16* __restrict__ in_lo,
                       const u16* __restrict__ wih, const u16* __restrict__ whh,
                       const float* __restrict__ bi, const float* __restrict__ bh,
                       u16* __restrict__ out_hi, u16* __restrict__ out_lo,
                       float* __restrict__ out_f, int N) {
    constexpr int NKS = KIN / 32;
    constexpr int HSTR = 76;
    const int tid = threadIdx.x;
    const int w = tid >> 6, lane = tid & 63;
    const int quad = lane >> 4, l16 = lane & 15;
    const int n0 = blockIdx.x * 16;
    const int u = w * 16 + l16;

    __shared__ __align__(16) u16 hT[2][16][HSTR];
    for (int p = tid; p < 2 * 16 * HSTR; p += NTHREADS) (&hT[0][0][0])[p] = 0;

    short8_t fI[4][NKS], fH[4][2];
    #pragma unroll
    for (int g = 0; g < 4; ++g) {
        #pragma unroll
        for (int ks = 0; ks < NKS; ++ks)
            fI[g][ks] = *(const short8_t*)(wih + (long)(g * 64 + u) * KIN + ks * 32 + quad * 8);
        #pragma unroll
        for (int ks = 0; ks < 2; ++ks)
            fH[g][ks] = *(const short8_t*)(whh + (long)(g * 64 + u) * 64 + ks * 32 + quad * 8);
    }
    float bias[4];
    #pragma unroll
    for (int g = 0; g < 4; ++g) bias[g] = bi[g * 64 + u] + bh[g * 64 + u];
    float cst[4] = {};
    __syncthreads();

    #pragma unroll 1
    for (int t = 0; t < T_STEPS; ++t) {
        short8_t ain[NKS], ainl[NKS];
        const long ibase = ((long)t * N + n0 + l16) * KIN + quad * 8;
        #pragma unroll
        for (int ks = 0; ks < NKS; ++ks) {
            ain[ks] = *(const short8_t*)(in_hi + ibase + ks * 32);
            if constexpr (IN_SPLIT) ainl[ks] = *(const short8_t*)(in_lo + ibase + ks * 32);
        }
        short8_t ah[2], al[2];
        #pragma unroll
        for (int ks = 0; ks < 2; ++ks) {
            ah[ks] = *(const short8_t*)(&hT[0][l16][ks * 32 + quad * 8]);
            al[ks] = *(const short8_t*)(&hT[1][l16][ks * 32 + quad * 8]);
        }
        __syncthreads();

        float4_t acc[4];
        #pragma unroll
        for (int g = 0; g < 4; ++g) acc[g] = (float4_t){bias[g], bias[g], bias[g], bias[g]};
        #pragma unroll
        for (int ks = 0; ks < NKS; ++ks)
            #pragma unroll
            for (int g = 0; g < 4; ++g) {
                acc[g] = __builtin_amdgcn_mfma_f32_16x16x32_bf16(ain[ks], fI[g][ks], acc[g], 0, 0, 0);
                if constexpr (IN_SPLIT)
                    acc[g] = __builtin_amdgcn_mfma_f32_16x16x32_bf16(ainl[ks], fI[g][ks], acc[g], 0, 0, 0);
            }
        #pragma unroll
        for (int ks = 0; ks < 2; ++ks)
            #pragma unroll
            for (int g = 0; g < 4; ++g) {
                acc[g] = __builtin_amdgcn_mfma_f32_16x16x32_bf16(ah[ks], fH[g][ks], acc[g], 0, 0, 0);
                acc[g] = __builtin_amdgcn_mfma_f32_16x16x32_bf16(al[ks], fH[g][ks], acc[g], 0, 0, 0);
            }

        #pragma unroll
        for (int r = 0; r < 4; ++r) {
            const float si = fsig(acc[0][r]);
            const float sf = fsig(acc[1][r]);
            const float gg = ftanh(acc[2][r]);
            const float so = fsig(acc[3][r]);
            const float c = sf * cst[r] + si * gg;
            cst[r] = c;
            const float h = so * ftanh(c);
            const int node = quad * 4 + r;
            const u16 hi = f2bf(h);
            const u16 lo = f2bf(h - bf2f(hi));
            hT[0][node][u] = hi;
            hT[1][node][u] = lo;
            if constexpr (LAST) {
                if (t == T_STEPS - 1) out_f[(long)(n0 + node) * 64 + u] = h;
            } else {
                const long o = ((long)t * N + n0 + node) * 64 + u;
                out_hi[o] = hi;
                out_lo[o] = lo;
            }
        }
        __syncthreads();
    }
}

// ============================ launch ============================
extern "C" void kernel_launch(void* const* d_in, const int* in_sizes, int n_in,
                              void* d_out, int out_size, void* d_ws, size_t ws_size,
                              hipStream_t stream) {
    (void)n_in; (void)out_size; (void)ws_size;
    const float* x      = (const float*)d_in[0];
    const int*   ei     = (const int*)d_in[1];
    const float* w_gcn0 = (const float*)d_in[2];
    const float* b_gcn0 = (const float*)d_in[3];
    const float* w_gcn1 = (const float*)d_in[4];
    const float* b_gcn1 = (const float*)d_in[5];
    const float* w_gcn2 = (const float*)d_in[6];
    const float* b_gcn2 = (const float*)d_in[7];
    const float* bn_g0  = (const float*)d_in[8];
    const float* bn_b0  = (const float*)d_in[9];
    const float* bn_m0  = (const float*)d_in[10];
    const float* bn_v0  = (const float*)d_in[11];
    const float* bn_g1  = (const float*)d_in[12];
    const float* bn_b1  = (const float*)d_in[13];
    const float* bn_m1  = (const float*)d_in[14];
    const float* bn_v1  = (const float*)d_in[15];
    const float* w_ih_0 = (const float*)d_in[16];
    const float* w_hh_0 = (const float*)d_in[17];
    const float* b_ih_0 = (const float*)d_in[18];
    const float* b_hh_0 = (const float*)d_in[19];
    const float* w_ih_1 = (const float*)d_in[20];
    const float* w_hh_1 = (const float*)d_in[21];
    const float* b_ih_1 = (const float*)d_in[22];
    const float* b_hh_1 = (const float*)d_in[23];
    const float* w_ih_2 = (const float*)d_in[24];
    const float* w_hh_2 = (const float*)d_in[25];
    const float* b_ih_2 = (const float*)d_in[26];
    const float* b_hh_2 = (const float*)d_in[27];

    const int E = in_sizes[1] / 2;
    const int N = in_sizes[0] / (T_STEPS * F_INC);     // 10000
    const long M = (long)N * T_STEPS;                  // 80000

    char* ws = (char*)d_ws;
    size_t off = 0;
    auto carve = [&](size_t bytes) -> void* {
        void* p = ws + off;
        off += (bytes + 255) & ~(size_t)255;
        return p;
    };
    float* dis     = (float*)carve((size_t)N * 4);
    float* selfw   = (float*)carve((size_t)N * 4);
    int*   cnt     = (int*)carve((size_t)N * 4);
    int*   rowptr  = (int*)carve((size_t)(N + 1) * 4);
    int*   wp      = (int*)carve((size_t)N * 4);
    int2*  epk     = (int2*)carve((size_t)E * 8);
    int*   bsum    = (int*)carve(64 * 4);
    u16*   hbuf    = (u16*)carve((size_t)M * H_DIM * 2);      // 20.5 MB, [t][n][128]
    u16*   hbuf2   = (u16*)carve((size_t)M * H_DIM * 2);      // 20.5 MB ping-pong
    u16*   pA_hi   = (u16*)carve((size_t)M * O_DIM * 2);
    u16*   pA_lo   = (u16*)carve((size_t)M * O_DIM * 2);
    u16*   pB_hi   = (u16*)carve((size_t)M * O_DIM * 2);
    u16*   pB_lo   = (u16*)carve((size_t)M * O_DIM * 2);
    u16*   wt0     = (u16*)carve((size_t)128 * 32 * 2);
    u16*   wt1     = (u16*)carve((size_t)128 * 128 * 2);
    u16*   wt2     = (u16*)carve((size_t)128 * 128 * 2);
    u16*   wtih0   = (u16*)carve((size_t)256 * 128 * 2);
    u16*   wtih1   = (u16*)carve((size_t)256 * 64 * 2);
    u16*   wtih2   = (u16*)carve((size_t)256 * 64 * 2);
    u16*   whh0b   = (u16*)carve((size_t)256 * 64 * 2);
    u16*   whh1b   = (u16*)carve((size_t)256 * 64 * 2);
    u16*   whh2b   = (u16*)carve((size_t)256 * 64 * 2);

    const dim3 b256(NTHREADS);
    const int gN = (N + NTHREADS - 1) / NTHREADS;      // 40
    const int gE = (E + NTHREADS - 1) / NTHREADS;

    // ---- CSR + normalization ----
    hipMemsetAsync(cnt, 0, (size_t)N * 4, stream);
    count_kernel<<<gE, b256, 0, stream>>>(ei, cnt, E);
    scan_part1<<<gN, b256, 0, stream>>>(cnt, bsum, N);
    scan_part3<<<gN, b256, 0, stream>>>(cnt, bsum, rowptr, wp, dis, selfw, N);
    fill_kernel<<<gE, b256, 0, stream>>>(ei, dis, wp, epk, E);

    // ---- weight prep ----
    wprep_all_kernel<<<(151552 + 255) / 256, b256, 0, stream>>>(
        w_gcn0, w_gcn1, w_gcn2, w_ih_0, w_ih_1, w_ih_2, w_hh_0, w_hh_1, w_hh_2,
        wt0, wt1, wt2, wtih0, wtih1, wtih2, whh0b, whh1b, whh2b);

    // ---- GCN: fused agg+GEMM per layer (t-major, XCD-pinned, LDS edge staging) ----
    gcn32_kernel<<<dim3(T_STEPS / 2, N / 16), b256, 0, stream>>>(
        x, rowptr, epk, selfw, wt0, b_gcn0,
        bn_g0, bn_b0, bn_m0, bn_v0, hbuf, N);
    const dim3 gG(T_STEPS, N / 16);                     // (8, 625)
    gcn128_kernel<2><<<gG, b256, 0, stream>>>(
        hbuf, rowptr, epk, selfw, wt1, b_gcn1,
        bn_g1, bn_b1, bn_m1, bn_v1, hbuf2, N);
    gcn128_kernel<1><<<gG, b256, 0, stream>>>(
        hbuf2, rowptr, epk, selfw, wt2, b_gcn2,
        nullptr, nullptr, nullptr, nullptr, hbuf, N);

    // ---- LSTM: three per-layer fused kernels ----
    const int gL = N / 16;             // 625
    lstm_layer_kernel<128, false, false><<<gL, b256, 0, stream>>>(
        hbuf, nullptr, wtih0, whh0b, b_ih_0, b_hh_0, pA_hi, pA_lo, nullptr, N);
    lstm_layer_kernel<64, true, false><<<gL, b256, 0, stream>>>(
        pA_hi, pA_lo, wtih1, whh1b, b_ih_1, b_hh_1, pB_hi, pB_lo, nullptr, N);
    lstm_layer_kernel<64, true, true><<<gL, b256, 0, stream>>>(
        pB_hi, pB_lo, wtih2, whh2b, b_ih_2, b_hh_2, nullptr, nullptr, (float*)d_out, N);
}